// Round 9
// baseline (874.717 us; speedup 1.0000x reference)
//
#include <hip/hip_runtime.h>

typedef unsigned short u16;
typedef u16 u16x8 __attribute__((ext_vector_type(8)));
typedef __bf16 bf16x8 __attribute__((ext_vector_type(8)));
typedef float f32x4 __attribute__((ext_vector_type(4)));

__device__ __forceinline__ float bf2f(u16 v) {
  unsigned u = ((unsigned)v) << 16;
  return __builtin_bit_cast(float, u);
}
__device__ __forceinline__ u16 f2bf(float f) {
  unsigned u = __builtin_bit_cast(unsigned, f);
  u += 0x7FFFu + ((u >> 16) & 1u);
  return (u16)(u >> 16);
}
__device__ __forceinline__ float hsw(float v) {
  return v * fminf(fmaxf(v + 3.f, 0.f), 6.f) * (1.f / 6.f);
}
__device__ __forceinline__ f32x4 mfma16(u16x8 a, u16x8 b, f32x4 c) {
  return __builtin_amdgcn_mfma_f32_16x16x32_bf16(
      __builtin_bit_cast(bf16x8, a), __builtin_bit_cast(bf16x8, b), c, 0, 0, 0);
}

#define LR 40  // padded LDS row stride in u16 (80 B)

// ---------------------------------------------------------------------------
// K0: feature NCHW fp32 -> NHWC bf16 (single plane)
// ---------------------------------------------------------------------------
__global__ __launch_bounds__(256) void k_tobf(const float* __restrict__ f,
                                              u16* __restrict__ fbh) {
  __shared__ float tl[64 * 65];
  const int t = threadIdx.x;
  const int bid = blockIdx.x;
  const int ict = bid & 7, xt = (bid >> 3) & 1, y = (bid >> 4) & 127, n = bid >> 11;
  const int x0 = xt * 64, ic0 = ict * 64;
#pragma unroll
  for (int i = 0; i < 16; ++i) {
    const int e = t + i * 256;
    const int icl = e >> 6, xl = e & 63;
    tl[icl * 65 + xl] = f[((n * 512 + ic0 + icl) * 128 + y) * 128 + x0 + xl];
  }
  __syncthreads();
#pragma unroll
  for (int i = 0; i < 16; ++i) {
    const int e = t + i * 256;
    const int xl = e >> 6, icl = e & 63;
    const size_t idx = ((size_t)((n * 128 + y) * 128 + x0 + xl) << 9) + ic0 + icl;
    fbh[idx] = f2bf(tl[icl * 65 + xl]);
  }
}

// ---------------------------------------------------------------------------
// Weight prepacks: [tap][icc][oc][ic32] bf16
// ---------------------------------------------------------------------------
__global__ __launch_bounds__(256) void k_pack1(const float* __restrict__ w,
                                               u16* __restrict__ bph) {
  const int e = blockIdx.x * 256 + threadIdx.x;  // < 9*16*192*32
  const int ici = e & 31;
  const int rest = e >> 5;
  const int oc = rest % 192;
  const int kc = rest / 192;
  const int icc = kc & 15, tap = kc >> 4;
  const int ic = icc * 32 + ici;
  bph[e] = f2bf(w[(oc * 512 + ic) * 9 + tap]);
}

__global__ __launch_bounds__(256) void k_pack2(const float* __restrict__ w,
                                               u16* __restrict__ bph) {
  const int e = blockIdx.x * 256 + threadIdx.x;  // < 9*6*192*32
  const int ici = e & 31;
  const int rest = e >> 5;
  const int oc = rest % 192;
  const int kc = rest / 192;
  const int icc = kc % 6, tap = kc / 6;
  const int ic = icc * 32 + ici;
  bph[e] = f2bf(w[(oc * 192 + ic) * 9 + tap]);
}

__global__ __launch_bounds__(256) void k_pack5(const float* __restrict__ rgw,
                                               const float* __restrict__ hmw,
                                               u16* __restrict__ bph) {
  const int e = blockIdx.x * 256 + threadIdx.x;  // < 9*16*48*32
  const int ici = e & 31;
  const int rest = e >> 5;
  const int oc = rest % 48;
  const int sic = rest / 48;
  const int icc = sic & 15, slot = sic >> 4;
  const int ic = icc * 32 + ici;
  const int kytab[9] = {1, 1, 1, 2, 0, 2, 2, 0, 0};
  const int kxtab[9] = {1, 2, 0, 1, 1, 2, 0, 2, 0};
  const int ky = kytab[slot], kx = kxtab[slot];
  float v = 0.f;
  if (oc < 32)
    v = rgw[((ic * 32 + oc) * 3 + ky) * 3 + kx];
  else if (oc < 40)
    v = hmw[((ic * 8 + (oc - 32)) * 3 + ky) * 3 + kx];
  bph[e] = f2bf(v);
}

// ---------------------------------------------------------------------------
// K1 v2: conv1 3x3 s2 p1, 512->192. Block = (n, oy, ocg 48-oc slice).
// K-loop over 16 ic-chunks; all 9 taps = shifted reads of 3 staged input
// rows. 27 MFMA per wave per barrier pair. y1 bf16 NHWC.
// ---------------------------------------------------------------------------
__global__ __launch_bounds__(256) void k_conv1(const u16* __restrict__ fbh,
                                               const u16* __restrict__ bph,
                                               const float* __restrict__ bias,
                                               u16* __restrict__ y1) {
  __shared__ u16 AL[3 * 130 * LR];   // 31.2 KB: [ry][p=ix+1 (0..129)][32ch]
  __shared__ u16 BH[9 * 48 * LR];    // 34.6 KB: [tap][oco][32ch]
  const int t = threadIdx.x;
  const int bid = blockIdx.x;
  const int ocg = bid & 3, oy = (bid >> 2) & 63, n = bid >> 8;
  const int lane = t & 63, wv = t >> 6;
  const int row = lane & 15, g = lane >> 4;

  float bias3[3];
#pragma unroll
  for (int nf = 0; nf < 3; ++nf) bias3[nf] = bias[ocg * 48 + nf * 16 + row];

  const f32x4 z4 = {0.f, 0.f, 0.f, 0.f};
  f32x4 acc[3];
#pragma unroll
  for (int j = 0; j < 3; ++j) acc[j] = z4;

  // A: 1560 u16x8 chunks (3*130*4); B: 1728 chunks (9*48*4)
#define C1_LOAD_A(ICC, DST)                                                    \
  _Pragma("unroll") for (int i = 0; i < 7; ++i) {                              \
    const int e = t + i * 256;                                                 \
    u16x8 v = {0, 0, 0, 0, 0, 0, 0, 0};                                        \
    if (e < 1560) {                                                            \
      const int icq = e & 3, q = e >> 2;                                       \
      const int ry = q / 130, p = q - ry * 130;                                \
      const int iy = 2 * oy - 1 + ry, ix = p - 1;                              \
      if (iy >= 0 && (unsigned)ix < 128u)                                      \
        v = *(const u16x8*)&fbh[((size_t)((n * 128 + iy) * 128 + ix) << 9) +   \
                                (ICC)*32 + icq * 8];                           \
    }                                                                          \
    DST[i] = v;                                                                \
  }

#define C1_LOAD_B(ICC, DST)                                                    \
  _Pragma("unroll") for (int i = 0; i < 7; ++i) {                              \
    const int e = t + i * 256;                                                 \
    u16x8 v = {0, 0, 0, 0, 0, 0, 0, 0};                                        \
    if (e < 1728) {                                                            \
      const int icq = e & 3, q = e >> 2;                                       \
      const int tap = q / 48, oco = q - tap * 48;                              \
      v = *(const u16x8*)&bph[((size_t)((tap * 16 + (ICC)) * 192 + ocg * 48 +  \
                                        oco)                                   \
                              << 5) +                                          \
                              icq * 8];                                        \
    }                                                                          \
    DST[i] = v;                                                                \
  }

  u16x8 aA[7], bA[7], aB[7], bB[7];
  C1_LOAD_A(0, aA);
  C1_LOAD_B(0, bA);

  for (int icc = 0; icc < 16; ++icc) {
    __syncthreads();
#pragma unroll
    for (int i = 0; i < 7; ++i) {
      const int e = t + i * 256;
      if (e < 1560) {
        const int icq = e & 3, q = e >> 2;
        *(u16x8*)&AL[q * LR + icq * 8] = aA[i];
      }
    }
#pragma unroll
    for (int i = 0; i < 7; ++i) {
      const int e = t + i * 256;
      if (e < 1728) {
        const int icq = e & 3, q = e >> 2;
        *(u16x8*)&BH[q * LR + icq * 8] = bA[i];
      }
    }
    __syncthreads();

    if (icc < 15) {
      C1_LOAD_A(icc + 1, aB);
      C1_LOAD_B(icc + 1, bB);
    }

#pragma unroll
    for (int tap = 0; tap < 9; ++tap) {
      const int ry = tap / 3, kx = tap - ry * 3;
      const int p = 2 * (wv * 16 + row) + kx;  // = ix+1
      const u16x8 af = *(const u16x8*)&AL[(ry * 130 + p) * LR + g * 8];
      const u16x8 bf0 = *(const u16x8*)&BH[(tap * 48 + row) * LR + g * 8];
      const u16x8 bf1 = *(const u16x8*)&BH[(tap * 48 + 16 + row) * LR + g * 8];
      const u16x8 bf2 = *(const u16x8*)&BH[(tap * 48 + 32 + row) * LR + g * 8];
      acc[0] = mfma16(af, bf0, acc[0]);
      acc[1] = mfma16(af, bf1, acc[1]);
      acc[2] = mfma16(af, bf2, acc[2]);
    }

#pragma unroll
    for (int i = 0; i < 7; ++i) {
      aA[i] = aB[i];
      bA[i] = bB[i];
    }
  }
#undef C1_LOAD_A
#undef C1_LOAD_B

#pragma unroll
  for (int nf = 0; nf < 3; ++nf)
#pragma unroll
    for (int r = 0; r < 4; ++r) {
      const int m = wv * 16 + g * 4 + r;
      const int oc = ocg * 48 + nf * 16 + row;
      y1[((n * 64 + oy) * 64 + m) * 192 + oc] = f2bf(acc[nf][r] + bias3[nf]);
    }
}

// ---------------------------------------------------------------------------
// K2: conv2 3x3 s2 p1, 192->192 on bn1(y1 bf16), prefetch. y2 fp32 NHWC.
// ---------------------------------------------------------------------------
__global__ __launch_bounds__(256) void k_conv2(const u16* __restrict__ y1,
                                               const u16* __restrict__ bph,
                                               const float* __restrict__ bias,
                                               const float* __restrict__ sc,
                                               const float* __restrict__ sh,
                                               float* __restrict__ y2) {
  __shared__ u16 Al[64 * LR];
  __shared__ u16 Bl[192 * LR];
  __shared__ float bl[192], scl[192], shl[192];
  const int t = threadIdx.x;
  const int n = blockIdx.x >> 4, oyp = blockIdx.x & 15;
  if (t < 192) {
    bl[t] = bias[t];
    scl[t] = sc[t];
    shl[t] = sh[t];
  }
  __syncthreads();
  const int lane = t & 63, wv = t >> 6;
  const int row = lane & 15, g = lane >> 4;
  const int ms = t >> 2, icq = t & 3;
  const int ryr = ms >> 5, oxs = ms & 31;
  const f32x4 z4 = {0.f, 0.f, 0.f, 0.f};
  f32x4 acc[4][3];
#pragma unroll
  for (int i = 0; i < 4; ++i)
#pragma unroll
    for (int j = 0; j < 3; ++j) acc[i][j] = z4;

#define C2_LOAD(KC, RAW, OK, BV)                                               \
  {                                                                            \
    const int tap_ = (KC) / 6, icc_ = (KC)-tap_ * 6;                           \
    const int ky_ = tap_ / 3, kx_ = tap_ - ky_ * 3;                            \
    const int iy_ = 2 * (oyp * 2 + ryr) - 1 + ky_;                             \
    const int ix_ = 2 * oxs - 1 + kx_;                                         \
    OK = ((unsigned)iy_ < 64u) && ((unsigned)ix_ < 64u);                       \
    u16x8 v_ = {0, 0, 0, 0, 0, 0, 0, 0};                                       \
    if (OK)                                                                    \
      v_ = *(const u16x8*)&y1[((n * 64 + iy_) * 64 + ix_) * 192 + icc_ * 32 +  \
                              icq * 8];                                        \
    RAW = v_;                                                                  \
    const size_t bbase_ = (size_t)(tap_ * 6 + icc_) * (192 * 32);              \
    _Pragma("unroll") for (int i_ = 0; i_ < 3; ++i_) {                         \
      const int e_ = t + i_ * 256;                                             \
      BV[i_] = *(const u16x8*)&bph[bbase_ + (e_ >> 2) * 32 + (e_ & 3) * 8];    \
    }                                                                          \
  }

  u16x8 rawA, bvA[3], rawB, bvB[3];
  bool okA, okB;
  C2_LOAD(0, rawA, okA, bvA);

  for (int kc = 0; kc < 54; ++kc) {
    const int tap = kc / 6, icc = kc - tap * 6;
    const int icb = icc * 32 + icq * 8;
    u16x8 av = {0, 0, 0, 0, 0, 0, 0, 0};
    if (okA) {
#pragma unroll
      for (int j = 0; j < 8; ++j)
        av[j] = f2bf(bf2f(rawA[j]) * scl[icb + j] + shl[icb + j]);
    }
    __syncthreads();
    *(u16x8*)&Al[ms * LR + icq * 8] = av;
#pragma unroll
    for (int i = 0; i < 3; ++i) {
      const int e = t + i * 256;
      *(u16x8*)&Bl[(e >> 2) * LR + (e & 3) * 8] = bvA[i];
    }
    __syncthreads();
    if (kc < 53) C2_LOAD(kc + 1, rawB, okB, bvB);
    u16x8 af[4], bf[3];
#pragma unroll
    for (int mf = 0; mf < 4; ++mf)
      af[mf] = *(const u16x8*)&Al[(mf * 16 + row) * LR + g * 8];
#pragma unroll
    for (int nf = 0; nf < 3; ++nf)
      bf[nf] = *(const u16x8*)&Bl[(wv * 48 + nf * 16 + row) * LR + g * 8];
#pragma unroll
    for (int mf = 0; mf < 4; ++mf)
#pragma unroll
      for (int nf = 0; nf < 3; ++nf) acc[mf][nf] = mfma16(af[mf], bf[nf], acc[mf][nf]);
    rawA = rawB;
    okA = okB;
#pragma unroll
    for (int i = 0; i < 3; ++i) bvA[i] = bvB[i];
  }
#undef C2_LOAD
#pragma unroll
  for (int mf = 0; mf < 4; ++mf)
#pragma unroll
    for (int nf = 0; nf < 3; ++nf)
#pragma unroll
      for (int r = 0; r < 4; ++r) {
        const int m = mf * 16 + g * 4 + r;
        const int oy = oyp * 2 + (m >> 5), ox = m & 31;
        const int oc = wv * 48 + nf * 16 + row;
        y2[((n * 32 + oy) * 32 + ox) * 192 + oc] = acc[mf][nf][r] + bl[oc];
      }
}

// ---------------------------------------------------------------------------
// K5 (R7 revert, measured 156 us): fused ConvT single-bf16, pipelined
// staging, pad-40 LDS, chunked XCD swizzle.
// ---------------------------------------------------------------------------
#define AST 40           // px stride in u16 (80 B)
#define ARS (130 * 40)   // per-row plane stride in u16
#define BST 40           // oc stride in u16
__global__ __launch_bounds__(256) void k_convt(const u16* __restrict__ fbh,
                                               const u16* __restrict__ bph,
                                               const float* __restrict__ rgb,
                                               const float* __restrict__ hmb,
                                               u16* __restrict__ rr,
                                               float* __restrict__ hm) {
  __shared__ u16 AH[2 * ARS];       // 20.8 KB
  __shared__ u16 BH[9 * 48 * BST];  // 34.6 KB
  const int t = threadIdx.x;
  const int bid = (blockIdx.x & 7) * 128 + (blockIdx.x >> 3);
  const int n = bid >> 7, iyb = bid & 127;
  const int lane = t & 63, wv = t >> 6;
  const int row = lane & 15, g = lane >> 4;

  if (t < 8) {
    const int r = t >> 2, j = t & 3;
    const u16x8 z = {0, 0, 0, 0, 0, 0, 0, 0};
    *(u16x8*)&AH[r * ARS + 128 * AST + j * 8] = z;
  }

  float bias3[3];
#pragma unroll
  for (int nf = 0; nf < 3; ++nf) {
    const int oc = nf * 16 + row;
    bias3[nf] = (oc < 32) ? rgb[oc] : ((oc < 40) ? hmb[oc - 32] : 0.f);
  }

  const int SCt[9] = {0, 1, 1, 2, 2, 3, 3, 3, 3};
  const int SDt[9] = {0, 0, 0, 0, 1, 0, 0, 1, 1};
  const int SXt[9] = {0, 0, 1, 0, 0, 0, 1, 0, 1};

  int rr_[4], px_[4], iq_[4];
#pragma unroll
  for (int i = 0; i < 4; ++i) {
    const int u = t + i * 256;
    rr_[i] = u >> 9;
    px_[i] = (u >> 2) & 127;
    iq_[i] = u & 3;
  }

  const f32x4 z4 = {0.f, 0.f, 0.f, 0.f};
  f32x4 acc[4][2][3];
#pragma unroll
  for (int c = 0; c < 4; ++c)
#pragma unroll
    for (int m = 0; m < 2; ++m)
#pragma unroll
      for (int j = 0; j < 3; ++j) acc[c][m][j] = z4;

#define LOAD_A(ICC, DST)                                                       \
  _Pragma("unroll") for (int i = 0; i < 4; ++i) {                              \
    const int iy = iyb + rr_[i];                                               \
    u16x8 v = {0, 0, 0, 0, 0, 0, 0, 0};                                        \
    if (iy < 128)                                                              \
      v = *(const u16x8*)&fbh[((size_t)((n * 128 + iy) * 128 + px_[i]) << 9) + \
                              (ICC)*32 + iq_[i] * 8];                          \
    DST[i] = v;                                                                \
  }

#define LOAD_B(ICC, DST)                                                       \
  _Pragma("unroll") for (int i = 0; i < 7; ++i) {                              \
    const int e = t + i * 256;                                                 \
    u16x8 v = {0, 0, 0, 0, 0, 0, 0, 0};                                        \
    if (e < 1728) {                                                            \
      const int slot = e / 192, rem = e % 192;                                 \
      const int oc = rem >> 2, icq = rem & 3;                                  \
      v = *(const u16x8*)&bph[((size_t)((slot * 16 + (ICC)) * 48 + oc) << 5) + \
                              icq * 8];                                        \
    }                                                                          \
    DST[i] = v;                                                                \
  }

  u16x8 ahA[4], bhA[7], ahB[4], bhB[7];
  LOAD_A(0, ahA);
  LOAD_B(0, bhA);

  for (int icc = 0; icc < 16; ++icc) {
    __syncthreads();
#pragma unroll
    for (int i = 0; i < 4; ++i)
      *(u16x8*)&AH[rr_[i] * ARS + px_[i] * AST + iq_[i] * 8] = ahA[i];
#pragma unroll
    for (int i = 0; i < 7; ++i) {
      const int e = t + i * 256;
      if (e < 1728) {
        const int slot = e / 192, rem = e % 192;
        const int oc = rem >> 2, icq = rem & 3;
        *(u16x8*)&BH[(slot * 48 + oc) * BST + icq * 8] = bhA[i];
      }
    }
    __syncthreads();

    if (icc < 15) {
      LOAD_A(icc + 1, ahB);
      LOAD_B(icc + 1, bhB);
    }

#pragma unroll
    for (int slot = 0; slot < 9; ++slot) {
      const int cls = SCt[slot], diy = SDt[slot], dix = SXt[slot];
      const u16x8 bf0 = *(const u16x8*)&BH[(slot * 48 + row) * BST + g * 8];
      const u16x8 bf1 = *(const u16x8*)&BH[(slot * 48 + 16 + row) * BST + g * 8];
      const u16x8 bf2 = *(const u16x8*)&BH[(slot * 48 + 32 + row) * BST + g * 8];
#pragma unroll
      for (int mfl = 0; mfl < 2; ++mfl) {
        const int mf = wv * 2 + mfl;
        const u16x8 af =
            *(const u16x8*)&AH[diy * ARS + (mf * 16 + row + dix) * AST + g * 8];
        acc[cls][mfl][0] = mfma16(af, bf0, acc[cls][mfl][0]);
        acc[cls][mfl][1] = mfma16(af, bf1, acc[cls][mfl][1]);
        acc[cls][mfl][2] = mfma16(af, bf2, acc[cls][mfl][2]);
      }
    }

#pragma unroll
    for (int i = 0; i < 4; ++i) ahA[i] = ahB[i];
#pragma unroll
    for (int i = 0; i < 7; ++i) bhA[i] = bhB[i];
  }
#undef LOAD_A
#undef LOAD_B

#pragma unroll
  for (int cls = 0; cls < 4; ++cls) {
    const int oy = 2 * iyb + (cls >> 1);
    const int xp = cls & 1;
#pragma unroll
    for (int mfl = 0; mfl < 2; ++mfl)
#pragma unroll
      for (int nf = 0; nf < 3; ++nf)
#pragma unroll
        for (int r = 0; r < 4; ++r) {
          const int m = (wv * 2 + mfl) * 16 + g * 4 + r;
          const int ox = 2 * m + xp;
          const int oc = nf * 16 + row;
          const float v = acc[cls][mfl][nf][r] + bias3[nf];
          if (oc < 32)
            rr[((size_t)((n * 256 + oy) * 256 + ox)) * 32 + oc] = f2bf(v);
          else if (oc < 40)
            hm[(size_t)(n * 8 + (oc - 32)) * 65536 + oy * 256 + ox] = v;
        }
  }
}

// ---------------------------------------------------------------------------
// Generic per-channel sum/sumsq over [M][C] (C = CG*32)
// ---------------------------------------------------------------------------
template <int CG, bool BF16>
__global__ __launch_bounds__(256) void k_stats(const void* __restrict__ in_, int M,
                                               int PB, float* __restrict__ gsum,
                                               float* __restrict__ gsq) {
  const int C = CG * 32;
  __shared__ float red[8][CG * 32];
  const int t = threadIdx.x;
  const int pg = t >> 5, ln = t & 31;
  float s[CG], q[CG];
#pragma unroll
  for (int c = 0; c < CG; ++c) { s[c] = 0.f; q[c] = 0.f; }
  const int p0 = blockIdx.x * PB;
  const int pend = min(p0 + PB, M);
  for (int p = p0 + pg; p < pend; p += 8) {
#pragma unroll
    for (int c = 0; c < CG; ++c) {
      float v;
      if (BF16)
        v = bf2f(((const u16*)in_)[(size_t)p * C + c * 32 + ln]);
      else
        v = ((const float*)in_)[(size_t)p * C + c * 32 + ln];
      s[c] += v;
      q[c] += v * v;
    }
  }
#pragma unroll
  for (int c = 0; c < CG; ++c) red[pg][c * 32 + ln] = s[c];
  __syncthreads();
  if (t < C) {
    float tot = 0.f;
#pragma unroll
    for (int k = 0; k < 8; ++k) tot += red[k][t];
    atomicAdd(&gsum[t], tot);
  }
  __syncthreads();
#pragma unroll
  for (int c = 0; c < CG; ++c) red[pg][c * 32 + ln] = q[c];
  __syncthreads();
  if (t < C) {
    float tot = 0.f;
#pragma unroll
    for (int k = 0; k < 8; ++k) tot += red[k][t];
    atomicAdd(&gsq[t], tot);
  }
}

__global__ void k_bnfin(const float* __restrict__ gsum, const float* __restrict__ gsq,
                        const float* __restrict__ g, const float* __restrict__ be,
                        float invM, int C, float* __restrict__ sc,
                        float* __restrict__ sh) {
  const int t = threadIdx.x;
  if (t < C) {
    const float m = gsum[t] * invM;
    const float var = gsq[t] * invM - m * m;
    const float inv = rsqrtf(var + 1e-5f);
    const float s = g[t] * inv;
    sc[t] = s;
    sh[t] = be[t] - m * s;
  }
}

// ---------------------------------------------------------------------------
// K3: conv3 1x1 192->32 on bn(y2 fp32). y3 fp32 [8192][32].
// ---------------------------------------------------------------------------
__global__ __launch_bounds__(256) void k_conv3(const float* __restrict__ y2,
                                               const float* __restrict__ w3,
                                               const float* __restrict__ b3,
                                               const float* __restrict__ sc,
                                               const float* __restrict__ sh,
                                               float* __restrict__ y3) {
  __shared__ float wl[32 * 192];
  __shared__ float scl[192], shl[192];
  const int t = threadIdx.x;
  for (int e = t; e < 6144; e += 256) wl[e] = w3[e];
  if (t < 192) {
    scl[t] = sc[t];
    shl[t] = sh[t];
  }
  __syncthreads();
  const int px = blockIdx.x * 256 + t;
  float acc[32];
#pragma unroll
  for (int oc = 0; oc < 32; ++oc) acc[oc] = 0.f;
  const float* base = &y2[(size_t)px * 192];
  for (int icb = 0; icb < 192; icb += 8) {
    const f32x4 r0 = *(const f32x4*)&base[icb];
    const f32x4 r1 = *(const f32x4*)&base[icb + 4];
    float v[8];
#pragma unroll
    for (int j = 0; j < 8; ++j) {
      const float r = (j < 4) ? r0[j & 3] : r1[j & 3];
      v[j] = r * scl[icb + j] + shl[icb + j];
    }
#pragma unroll
    for (int oc = 0; oc < 32; ++oc) {
      const f32x4 w0 = *(const f32x4*)&wl[oc * 192 + icb];
      const f32x4 w1 = *(const f32x4*)&wl[oc * 192 + icb + 4];
      acc[oc] += v[0] * w0[0] + v[1] * w0[1] + v[2] * w0[2] + v[3] * w0[3] +
                 v[4] * w1[0] + v[5] * w1[1] + v[6] * w1[2] + v[7] * w1[3];
    }
  }
#pragma unroll
  for (int oc = 0; oc < 32; ++oc) y3[(size_t)px * 32 + oc] = acc[oc] + b3[oc];
}

// ---------------------------------------------------------------------------
// K4: classify conv 3x3 p1, 32->32 on hsw(bn2(y3))
// ---------------------------------------------------------------------------
__global__ __launch_bounds__(256) void k_clsconv1(const float* __restrict__ y3,
                                                  const float* __restrict__ w1,
                                                  const float* __restrict__ b1,
                                                  const float* __restrict__ sc,
                                                  const float* __restrict__ sh,
                                                  float* __restrict__ c1) {
  __shared__ float wl[9216];  // [ic][tap][oc]
  __shared__ float scl[32], shl[32];
  const int t = threadIdx.x;
  for (int e = t; e < 9216; e += 256) {
    const int oc = e & 31;
    const int tmp = e >> 5;
    const int tap = tmp % 9, ic = tmp / 9;
    wl[e] = w1[(oc * 32 + ic) * 9 + tap];
  }
  if (t < 32) {
    scl[t] = sc[t];
    shl[t] = sh[t];
  }
  __syncthreads();
  const int px = blockIdx.x * 64 + (t & 63);
  const int ocg = t >> 6;
  const int n = px >> 10, y0 = (px >> 5) & 31, x0 = px & 31;
  float acc[8];
#pragma unroll
  for (int j = 0; j < 8; ++j) acc[j] = 0.f;
  for (int tap = 0; tap < 9; ++tap) {
    const int dy = tap / 3 - 1, dx = tap % 3 - 1;
    const int yy = y0 + dy, xx = x0 + dx;
    if ((unsigned)yy < 32u && (unsigned)xx < 32u) {
      const float* ib = &y3[((n << 10) + yy * 32 + xx) * 32];
      for (int ic = 0; ic < 32; ++ic) {
        const float v = hsw(ib[ic] * scl[ic] + shl[ic]);
        const float* wp = &wl[(ic * 9 + tap) * 32 + ocg * 8];
#pragma unroll
        for (int j = 0; j < 8; ++j) acc[j] += v * wp[j];
      }
    }
  }
#pragma unroll
  for (int j = 0; j < 8; ++j) c1[px * 32 + ocg * 8 + j] = acc[j] + b1[ocg * 8 + j];
}

// ---------------------------------------------------------------------------
// K4c: c2 = conv3x3(hsw(bn(c1))) 32->1, then cls[n,k] = c2 . dw[k] + db[k]
// ---------------------------------------------------------------------------
__global__ __launch_bounds__(256) void k_cls(const float* __restrict__ c1,
                                             const float* __restrict__ w2,
                                             const float* __restrict__ b2,
                                             const float* __restrict__ dw,
                                             const float* __restrict__ db,
                                             const float* __restrict__ sc,
                                             const float* __restrict__ sh,
                                             float* __restrict__ cls) {
  __shared__ float wl[288];
  __shared__ float scl[32], shl[32];
  __shared__ float red0[256], red1[256];
  const int t = threadIdx.x;
  const int n = blockIdx.x;
  for (int e = t; e < 288; e += 256) wl[e] = w2[e];
  if (t < 32) {
    scl[t] = sc[t];
    shl[t] = sh[t];
  }
  __syncthreads();
  float s0 = 0.f, s1 = 0.f;
  for (int i = 0; i < 4; ++i) {
    const int px = i * 256 + t;
    const int y0 = px >> 5, x0 = px & 31;
    float c2 = b2[0];
    for (int tap = 0; tap < 9; ++tap) {
      const int dy = tap / 3 - 1, dx = tap % 3 - 1;
      const int yy = y0 + dy, xx = x0 + dx;
      if ((unsigned)yy < 32u && (unsigned)xx < 32u) {
        const float* ib = &c1[((n << 10) + yy * 32 + xx) * 32];
        for (int ic = 0; ic < 32; ++ic)
          c2 += hsw(ib[ic] * scl[ic] + shl[ic]) * wl[ic * 9 + tap];
      }
    }
    s0 += c2 * dw[px];
    s1 += c2 * dw[1024 + px];
  }
  red0[t] = s0;
  red1[t] = s1;
  __syncthreads();
  for (int s = 128; s; s >>= 1) {
    if (t < s) {
      red0[t] += red0[t + s];
      red1[t] += red1[t + s];
    }
    __syncthreads();
  }
  if (t == 0) {
    cls[n * 2 + 0] = red0[0] + db[0];
    cls[n * 2 + 1] = red1[0] + db[1];
  }
}

// ---------------------------------------------------------------------------
// K6: reg = conv3x3 p1 (hsw(bn(rr))) 32->2, fp32 NCHW [8,2,256,256]
// ---------------------------------------------------------------------------
__global__ __launch_bounds__(256) void k_regconv(const u16* __restrict__ rr,
                                                 const float* __restrict__ w,
                                                 const float* __restrict__ b,
                                                 const float* __restrict__ sc,
                                                 const float* __restrict__ sh,
                                                 float* __restrict__ reg) {
  __shared__ u16 rl[3 * 258 * 33];
  __shared__ float wl[576];
  __shared__ float scl[32], shl[32];
  const int t = threadIdx.x;
  const int n = blockIdx.x >> 8, oy = blockIdx.x & 255;
  for (int e = t; e < 576; e += 256) wl[e] = w[e];
  if (t < 32) {
    scl[t] = sc[t];
    shl[t] = sh[t];
  }
  if (t < 192) {
    const int ry = t / 64, side = (t >> 5) & 1, ic = t & 31;
    rl[(ry * 258 + side * 257) * 33 + ic] = 0;
  }
  __syncthreads();
  for (int e = t; e < 3072; e += 256) {
    const int icq8 = e & 3;
    const int pxx = (e >> 2) & 255;
    const int ry = e >> 10;
    const int rowi = oy - 1 + ry;
    u16x8 raw = {0, 0, 0, 0, 0, 0, 0, 0};
    bool ok = (unsigned)rowi < 256u;
    if (ok)
      raw = *(const u16x8*)&rr[((size_t)((n * 256 + rowi) * 256 + pxx)) * 32 + icq8 * 8];
#pragma unroll
    for (int j = 0; j < 8; ++j) {
      const int ic = icq8 * 8 + j;
      float v = 0.f;
      if (ok) v = hsw(bf2f(raw[j]) * scl[ic] + shl[ic]);
      rl[(ry * 258 + pxx + 1) * 33 + ic] = f2bf(v);
    }
  }
  __syncthreads();
  const int px = t;
  float a0 = b[0], a1 = b[1];
#pragma unroll
  for (int ry = 0; ry < 3; ++ry)
#pragma unroll
    for (int kx = 0; kx < 3; ++kx) {
      const u16* ib = &rl[(ry * 258 + px + kx) * 33];
      for (int ic = 0; ic < 32; ++ic) {
        const float v = bf2f(ib[ic]);
        a0 += v * wl[ic * 9 + ry * 3 + kx];
        a1 += v * wl[288 + ic * 9 + ry * 3 + kx];
      }
    }
  reg[(n * 2 + 0) * 65536 + oy * 256 + px] = a0;
  reg[(n * 2 + 1) * 65536 + oy * 256 + px] = a1;
}

// ---------------------------------------------------------------------------
// K7: per (n, ch) spatial argmax, lowest-index tie-break
// ---------------------------------------------------------------------------
__global__ __launch_bounds__(256) void k_argmax(const float* __restrict__ hm,
                                                int* __restrict__ idx) {
  __shared__ float bv[256];
  __shared__ int bi[256];
  const int t = threadIdx.x;
  const float* base = &hm[(size_t)blockIdx.x * 65536];
  float best = -3.402823466e38f;
  int bidx = 2147483647;
  for (int i = t; i < 65536; i += 256) {
    const float v = base[i];
    if (v > best) {
      best = v;
      bidx = i;
    }
  }
  bv[t] = best;
  bi[t] = bidx;
  __syncthreads();
  for (int s = 128; s; s >>= 1) {
    if (t < s) {
      if (bv[t + s] > bv[t] || (bv[t + s] == bv[t] && bi[t + s] < bi[t])) {
        bv[t] = bv[t + s];
        bi[t] = bi[t + s];
      }
    }
    __syncthreads();
  }
  if (t == 0) idx[blockIdx.x] = bi[0];
}

// ---------------------------------------------------------------------------
// K8: decode -> out [8,2,9]
// ---------------------------------------------------------------------------
__global__ void k_final(const float* __restrict__ cls, const int* __restrict__ idx,
                        const float* __restrict__ reg, float* __restrict__ out) {
  const int t = threadIdx.x;
  if (t >= 16) return;
  const int n = t >> 1, p = t & 1;
  const float cv = cls[n * 2 + p];
  float* o = &out[(n * 2 + p) * 9];
  if (!(cv > 0.6f)) {
    for (int i = 0; i < 9; ++i) o[i] = -1.f;
    return;
  }
  o[0] = (float)p;
  for (int c = 0; c < 4; ++c) {
    const int id = idx[n * 8 + p * 4 + c];
    const int yi = id >> 8, xi = id & 255;
    const float ox_ = reg[(n * 2 + 0) * 65536 + id];
    const float oy_ = reg[(n * 2 + 1) * 65536 + id];
    o[1 + c] = fminf(fmaxf((ox_ + (float)xi) * (1.f / 256.f), 0.f), 1.f);
    o[5 + c] = fminf(fmaxf((oy_ + (float)yi) * (1.f / 256.f), 0.f), 1.f);
  }
}

// ---------------------------------------------------------------------------
extern "C" void kernel_launch(void* const* d_in, const int* in_sizes, int n_in,
                              void* d_out, int out_size, void* d_ws, size_t ws_size,
                              hipStream_t stream) {
  const float* feature = (const float*)d_in[0];
  const float* ch_w1 = (const float*)d_in[1];
  const float* ch_b1 = (const float*)d_in[2];
  const float* ch_w2 = (const float*)d_in[3];
  const float* ch_b2 = (const float*)d_in[4];
  const float* ch_w3 = (const float*)d_in[5];
  const float* ch_b3 = (const float*)d_in[6];
  const float* ch_g1 = (const float*)d_in[7];
  const float* ch_be1 = (const float*)d_in[8];
  const float* ch_g2 = (const float*)d_in[9];
  const float* ch_be2 = (const float*)d_in[10];
  const float* cl_w1 = (const float*)d_in[11];
  const float* cl_b1 = (const float*)d_in[12];
  const float* cl_w2 = (const float*)d_in[13];
  const float* cl_b2 = (const float*)d_in[14];
  const float* cl_g = (const float*)d_in[15];
  const float* cl_be = (const float*)d_in[16];
  const float* cl_dw = (const float*)d_in[17];
  const float* cl_db = (const float*)d_in[18];
  const float* rg_tw = (const float*)d_in[19];
  const float* rg_tb = (const float*)d_in[20];
  const float* rg_g = (const float*)d_in[21];
  const float* rg_be = (const float*)d_in[22];
  const float* rg_w = (const float*)d_in[23];
  const float* rg_b = (const float*)d_in[24];
  const float* hm_tw = (const float*)d_in[25];
  const float* hm_tb = (const float*)d_in[26];
  float* out = (float*)d_out;

  char* w = (char*)d_ws;
  const size_t OFF_FB = 0;                  // 134217728
  const size_t OFF_BP1 = 134217728;         // 1769472
  const size_t OFF_BP2 = 135987200;         // 663552
  const size_t OFF_BP5 = 136650752;         // 442368
  const size_t OFF_Y1 = 137093120;          // 12582912 (bf16)
  const size_t OFF_Y2 = 149676032;          // 6291456  (fp32)
  const size_t OFF_Y3 = 155967488;          // 1048576
  const size_t OFF_C1 = 157016064;          // 1048576
  const size_t OFF_RR = 158064640;          // 33554432
  const size_t OFF_HM = 191619072;          // 16777216
  const size_t OFF_REG = 208396288;         // 4194304
  const size_t OFF_STATS = 212590592;       // 3840
  const size_t OFF_PARAMS = 212594432;      // 3840
  const size_t OFF_CLS = 212598272;         // 64
  const size_t OFF_IDX = 212598336;         // 256
  const size_t WS_NEED = 212598592;
  if (ws_size < WS_NEED) return;

  u16* FB = (u16*)(w + OFF_FB);
  u16* BP1 = (u16*)(w + OFF_BP1);
  u16* BP2 = (u16*)(w + OFF_BP2);
  u16* BP5 = (u16*)(w + OFF_BP5);
  u16* Y1 = (u16*)(w + OFF_Y1);
  float* Y2 = (float*)(w + OFF_Y2);
  float* Y3 = (float*)(w + OFF_Y3);
  float* C1 = (float*)(w + OFF_C1);
  u16* RR = (u16*)(w + OFF_RR);
  float* HM = (float*)(w + OFF_HM);
  float* REG = (float*)(w + OFF_REG);
  float* GSUM = (float*)(w + OFF_STATS);
  float* GSQ = GSUM + 480;
  float* SC = (float*)(w + OFF_PARAMS);
  float* SH = SC + 480;
  float* CLS = (float*)(w + OFF_CLS);
  int* IDX = (int*)(w + OFF_IDX);

  (void)hipMemsetAsync(w + OFF_STATS, 0, 3840, stream);

  k_tobf<<<16384, 256, 0, stream>>>(feature, FB);
  k_pack1<<<3456, 256, 0, stream>>>(ch_w1, BP1);
  k_pack2<<<1296, 256, 0, stream>>>(ch_w2, BP2);
  k_pack5<<<864, 256, 0, stream>>>(rg_tw, hm_tw, BP5);

  // CommonHead
  k_conv1<<<2048, 256, 0, stream>>>(FB, BP1, ch_b1, Y1);
  k_stats<6, true><<<128, 256, 0, stream>>>(Y1, 32768, 256, GSUM + 0, GSQ + 0);
  k_bnfin<<<1, 256, 0, stream>>>(GSUM + 0, GSQ + 0, ch_g1, ch_be1, 1.f / 32768.f, 192,
                                 SC + 0, SH + 0);
  k_conv2<<<128, 256, 0, stream>>>(Y1, BP2, ch_b2, SC + 0, SH + 0, Y2);
  k_stats<6, false><<<32, 256, 0, stream>>>(Y2, 8192, 256, GSUM + 192, GSQ + 192);
  k_bnfin<<<1, 256, 0, stream>>>(GSUM + 192, GSQ + 192, ch_g1, ch_be1, 1.f / 8192.f,
                                 192, SC + 192, SH + 192);
  k_conv3<<<32, 256, 0, stream>>>(Y2, ch_w3, ch_b3, SC + 192, SH + 192, Y3);
  k_stats<1, false><<<8, 256, 0, stream>>>(Y3, 8192, 1024, GSUM + 384, GSQ + 384);
  k_bnfin<<<1, 256, 0, stream>>>(GSUM + 384, GSQ + 384, ch_g2, ch_be2, 1.f / 8192.f,
                                 32, SC + 384, SH + 384);
  // Classify head
  k_clsconv1<<<128, 256, 0, stream>>>(Y3, cl_w1, cl_b1, SC + 384, SH + 384, C1);
  k_stats<1, false><<<8, 256, 0, stream>>>(C1, 8192, 1024, GSUM + 416, GSQ + 416);
  k_bnfin<<<1, 256, 0, stream>>>(GSUM + 416, GSQ + 416, cl_g, cl_be, 1.f / 8192.f, 32,
                                 SC + 416, SH + 416);
  k_cls<<<8, 256, 0, stream>>>(C1, cl_w2, cl_b2, cl_dw, cl_db, SC + 416, SH + 416,
                               CLS);
  // Regression + heatmap (fused convT, R7 version)
  k_convt<<<1024, 256, 0, stream>>>(FB, BP5, rg_tb, hm_tb, RR, HM);
  k_stats<1, true><<<256, 256, 0, stream>>>(RR, 524288, 2048, GSUM + 448, GSQ + 448);
  k_bnfin<<<1, 256, 0, stream>>>(GSUM + 448, GSQ + 448, rg_g, rg_be, 1.f / 524288.f,
                                 32, SC + 448, SH + 448);
  k_regconv<<<2048, 256, 0, stream>>>(RR, rg_w, rg_b, SC + 448, SH + 448, REG);
  // Decode
  k_argmax<<<64, 256, 0, stream>>>(HM, IDX);
  k_final<<<1, 64, 0, stream>>>(CLS, IDX, REG, out);
}

// Round 10
// 866.223 us; speedup vs baseline: 1.0098x; 1.0098x over previous
//
#include <hip/hip_runtime.h>

typedef unsigned short u16;
typedef u16 u16x8 __attribute__((ext_vector_type(8)));
typedef __bf16 bf16x8 __attribute__((ext_vector_type(8)));
typedef float f32x4 __attribute__((ext_vector_type(4)));

__device__ __forceinline__ float bf2f(u16 v) {
  unsigned u = ((unsigned)v) << 16;
  return __builtin_bit_cast(float, u);
}
__device__ __forceinline__ u16 f2bf(float f) {
  unsigned u = __builtin_bit_cast(unsigned, f);
  u += 0x7FFFu + ((u >> 16) & 1u);
  return (u16)(u >> 16);
}
__device__ __forceinline__ float hsw(float v) {
  return v * fminf(fmaxf(v + 3.f, 0.f), 6.f) * (1.f / 6.f);
}
__device__ __forceinline__ f32x4 mfma16(u16x8 a, u16x8 b, f32x4 c) {
  return __builtin_amdgcn_mfma_f32_16x16x32_bf16(
      __builtin_bit_cast(bf16x8, a), __builtin_bit_cast(bf16x8, b), c, 0, 0, 0);
}

#define LR 40  // padded LDS row stride in u16 (80 B)

// ---------------------------------------------------------------------------
// K0: feature NCHW fp32 -> NHWC bf16 (single plane)
// ---------------------------------------------------------------------------
__global__ __launch_bounds__(256) void k_tobf(const float* __restrict__ f,
                                              u16* __restrict__ fbh) {
  __shared__ float tl[64 * 65];
  const int t = threadIdx.x;
  const int bid = blockIdx.x;
  const int ict = bid & 7, xt = (bid >> 3) & 1, y = (bid >> 4) & 127, n = bid >> 11;
  const int x0 = xt * 64, ic0 = ict * 64;
#pragma unroll
  for (int i = 0; i < 16; ++i) {
    const int e = t + i * 256;
    const int icl = e >> 6, xl = e & 63;
    tl[icl * 65 + xl] = f[((n * 512 + ic0 + icl) * 128 + y) * 128 + x0 + xl];
  }
  __syncthreads();
#pragma unroll
  for (int i = 0; i < 16; ++i) {
    const int e = t + i * 256;
    const int xl = e >> 6, icl = e & 63;
    const size_t idx = ((size_t)((n * 128 + y) * 128 + x0 + xl) << 9) + ic0 + icl;
    fbh[idx] = f2bf(tl[icl * 65 + xl]);
  }
}

// ---------------------------------------------------------------------------
// Weight prepacks: [tap][icc][oc][ic32] bf16
// ---------------------------------------------------------------------------
__global__ __launch_bounds__(256) void k_pack1(const float* __restrict__ w,
                                               u16* __restrict__ bph) {
  const int e = blockIdx.x * 256 + threadIdx.x;  // < 9*16*192*32
  const int ici = e & 31;
  const int rest = e >> 5;
  const int oc = rest % 192;
  const int kc = rest / 192;
  const int icc = kc & 15, tap = kc >> 4;
  const int ic = icc * 32 + ici;
  bph[e] = f2bf(w[(oc * 512 + ic) * 9 + tap]);
}

__global__ __launch_bounds__(256) void k_pack2(const float* __restrict__ w,
                                               u16* __restrict__ bph) {
  const int e = blockIdx.x * 256 + threadIdx.x;  // < 9*6*192*32
  const int ici = e & 31;
  const int rest = e >> 5;
  const int oc = rest % 192;
  const int kc = rest / 192;
  const int icc = kc % 6, tap = kc / 6;
  const int ic = icc * 32 + ici;
  bph[e] = f2bf(w[(oc * 192 + ic) * 9 + tap]);
}

__global__ __launch_bounds__(256) void k_pack5(const float* __restrict__ rgw,
                                               const float* __restrict__ hmw,
                                               u16* __restrict__ bph) {
  const int e = blockIdx.x * 256 + threadIdx.x;  // < 9*16*48*32
  const int ici = e & 31;
  const int rest = e >> 5;
  const int oc = rest % 48;
  const int sic = rest / 48;
  const int icc = sic & 15, slot = sic >> 4;
  const int ic = icc * 32 + ici;
  const int kytab[9] = {1, 1, 1, 2, 0, 2, 2, 0, 0};
  const int kxtab[9] = {1, 2, 0, 1, 1, 2, 0, 2, 0};
  const int ky = kytab[slot], kx = kxtab[slot];
  float v = 0.f;
  if (oc < 32)
    v = rgw[((ic * 32 + oc) * 3 + ky) * 3 + kx];
  else if (oc < 40)
    v = hmw[((ic * 8 + (oc - 32)) * 3 + ky) * 3 + kx];
  bph[e] = f2bf(v);
}

// ---------------------------------------------------------------------------
// K1 v3: conv1 3x3 s2 p1, 512->192. Block = (n, oy, ocg 48-oc slice).
// Parity-split A layout [ry][par][pp] -> tap reads are unit-stride (2-way,
// free). Chunked XCD swizzle: each XCD owns one n -> sibling ocg blocks
// share A rows in L2. 27 MFMA per wave per barrier pair. y1 bf16 NHWC.
// ---------------------------------------------------------------------------
__global__ __launch_bounds__(256) void k_conv1(const u16* __restrict__ fbh,
                                               const u16* __restrict__ bph,
                                               const float* __restrict__ bias,
                                               u16* __restrict__ y1) {
  __shared__ u16 AL[3 * 2 * 66 * LR];  // 31.7 KB: [ry][par][pp 0..65][32ch]
  __shared__ u16 BH[9 * 48 * LR];      // 34.6 KB: [tap][oco][32ch]
  const int t = threadIdx.x;
  // chunked XCD swizzle: XCD j (= blockIdx mod 8) gets contiguous bids
  // j*256..j*256+255 -> one full n (64 oy x 4 ocg adjacent in time)
  const int bid = (blockIdx.x & 7) * 256 + (blockIdx.x >> 3);
  const int ocg = bid & 3, oy = (bid >> 2) & 63, n = bid >> 8;
  const int lane = t & 63, wv = t >> 6;
  const int row = lane & 15, g = lane >> 4;

  float bias3[3];
#pragma unroll
  for (int nf = 0; nf < 3; ++nf) bias3[nf] = bias[ocg * 48 + nf * 16 + row];

  const f32x4 z4 = {0.f, 0.f, 0.f, 0.f};
  f32x4 acc[3];
#pragma unroll
  for (int j = 0; j < 3; ++j) acc[j] = z4;

  // A: 1560 u16x8 chunks (3 ry * 130 p * 4 icq); B: 1728 (9*48*4)
#define C1_LOAD_A(ICC, DST)                                                    \
  _Pragma("unroll") for (int i = 0; i < 7; ++i) {                              \
    const int e = t + i * 256;                                                 \
    u16x8 v = {0, 0, 0, 0, 0, 0, 0, 0};                                        \
    if (e < 1560) {                                                            \
      const int icq = e & 3, q = e >> 2;                                       \
      const int ry = q / 130, p = q - ry * 130;                                \
      const int iy = 2 * oy - 1 + ry, ix = p - 1;                              \
      if (iy >= 0 && (unsigned)ix < 128u)                                      \
        v = *(const u16x8*)&fbh[((size_t)((n * 128 + iy) * 128 + ix) << 9) +   \
                                (ICC)*32 + icq * 8];                           \
    }                                                                          \
    DST[i] = v;                                                                \
  }

#define C1_LOAD_B(ICC, DST)                                                    \
  _Pragma("unroll") for (int i = 0; i < 7; ++i) {                              \
    const int e = t + i * 256;                                                 \
    u16x8 v = {0, 0, 0, 0, 0, 0, 0, 0};                                        \
    if (e < 1728) {                                                            \
      const int icq = e & 3, q = e >> 2;                                       \
      const int tap = q / 48, oco = q - tap * 48;                              \
      v = *(const u16x8*)&bph[((size_t)((tap * 16 + (ICC)) * 192 + ocg * 48 +  \
                                        oco)                                   \
                              << 5) +                                          \
                              icq * 8];                                        \
    }                                                                          \
    DST[i] = v;                                                                \
  }

  u16x8 aA[7], bA[7], aB[7], bB[7];
  C1_LOAD_A(0, aA);
  C1_LOAD_B(0, bA);

  for (int icc = 0; icc < 16; ++icc) {
    __syncthreads();
#pragma unroll
    for (int i = 0; i < 7; ++i) {
      const int e = t + i * 256;
      if (e < 1560) {
        const int icq = e & 3, q = e >> 2;
        const int ry = q / 130, p = q - ry * 130;
        // parity-split: [ry][par][pp]
        *(u16x8*)&AL[((ry * 2 + (p & 1)) * 66 + (p >> 1)) * LR + icq * 8] = aA[i];
      }
    }
#pragma unroll
    for (int i = 0; i < 7; ++i) {
      const int e = t + i * 256;
      if (e < 1728) {
        const int icq = e & 3, q = e >> 2;
        *(u16x8*)&BH[q * LR + icq * 8] = bA[i];
      }
    }
    __syncthreads();

    if (icc < 15) {
      C1_LOAD_A(icc + 1, aB);
      C1_LOAD_B(icc + 1, bB);
    }

    const int m = wv * 16 + row;
#pragma unroll
    for (int tap = 0; tap < 9; ++tap) {
      const int ry = tap / 3, kx = tap - ry * 3;
      // p = 2m + kx -> par = kx&1, pp = m + (kx>>1): unit-stride read
      const u16x8 af =
          *(const u16x8*)&AL[((ry * 2 + (kx & 1)) * 66 + m + (kx >> 1)) * LR +
                             g * 8];
      const u16x8 bf0 = *(const u16x8*)&BH[(tap * 48 + row) * LR + g * 8];
      const u16x8 bf1 = *(const u16x8*)&BH[(tap * 48 + 16 + row) * LR + g * 8];
      const u16x8 bf2 = *(const u16x8*)&BH[(tap * 48 + 32 + row) * LR + g * 8];
      acc[0] = mfma16(af, bf0, acc[0]);
      acc[1] = mfma16(af, bf1, acc[1]);
      acc[2] = mfma16(af, bf2, acc[2]);
    }

#pragma unroll
    for (int i = 0; i < 7; ++i) {
      aA[i] = aB[i];
      bA[i] = bB[i];
    }
  }
#undef C1_LOAD_A
#undef C1_LOAD_B

#pragma unroll
  for (int nf = 0; nf < 3; ++nf)
#pragma unroll
    for (int r = 0; r < 4; ++r) {
      const int m = wv * 16 + g * 4 + r;
      const int oc = ocg * 48 + nf * 16 + row;
      y1[((n * 64 + oy) * 64 + m) * 192 + oc] = f2bf(acc[nf][r] + bias3[nf]);
    }
}

// ---------------------------------------------------------------------------
// K2: conv2 3x3 s2 p1, 192->192 on bn1(y1 bf16), prefetch. y2 fp32 NHWC.
// ---------------------------------------------------------------------------
__global__ __launch_bounds__(256) void k_conv2(const u16* __restrict__ y1,
                                               const u16* __restrict__ bph,
                                               const float* __restrict__ bias,
                                               const float* __restrict__ sc,
                                               const float* __restrict__ sh,
                                               float* __restrict__ y2) {
  __shared__ u16 Al[64 * LR];
  __shared__ u16 Bl[192 * LR];
  __shared__ float bl[192], scl[192], shl[192];
  const int t = threadIdx.x;
  const int n = blockIdx.x >> 4, oyp = blockIdx.x & 15;
  if (t < 192) {
    bl[t] = bias[t];
    scl[t] = sc[t];
    shl[t] = sh[t];
  }
  __syncthreads();
  const int lane = t & 63, wv = t >> 6;
  const int row = lane & 15, g = lane >> 4;
  const int ms = t >> 2, icq = t & 3;
  const int ryr = ms >> 5, oxs = ms & 31;
  const f32x4 z4 = {0.f, 0.f, 0.f, 0.f};
  f32x4 acc[4][3];
#pragma unroll
  for (int i = 0; i < 4; ++i)
#pragma unroll
    for (int j = 0; j < 3; ++j) acc[i][j] = z4;

#define C2_LOAD(KC, RAW, OK, BV)                                               \
  {                                                                            \
    const int tap_ = (KC) / 6, icc_ = (KC)-tap_ * 6;                           \
    const int ky_ = tap_ / 3, kx_ = tap_ - ky_ * 3;                            \
    const int iy_ = 2 * (oyp * 2 + ryr) - 1 + ky_;                             \
    const int ix_ = 2 * oxs - 1 + kx_;                                         \
    OK = ((unsigned)iy_ < 64u) && ((unsigned)ix_ < 64u);                       \
    u16x8 v_ = {0, 0, 0, 0, 0, 0, 0, 0};                                       \
    if (OK)                                                                    \
      v_ = *(const u16x8*)&y1[((n * 64 + iy_) * 64 + ix_) * 192 + icc_ * 32 +  \
                              icq * 8];                                        \
    RAW = v_;                                                                  \
    const size_t bbase_ = (size_t)(tap_ * 6 + icc_) * (192 * 32);              \
    _Pragma("unroll") for (int i_ = 0; i_ < 3; ++i_) {                         \
      const int e_ = t + i_ * 256;                                             \
      BV[i_] = *(const u16x8*)&bph[bbase_ + (e_ >> 2) * 32 + (e_ & 3) * 8];    \
    }                                                                          \
  }

  u16x8 rawA, bvA[3], rawB, bvB[3];
  bool okA, okB;
  C2_LOAD(0, rawA, okA, bvA);

  for (int kc = 0; kc < 54; ++kc) {
    const int tap = kc / 6, icc = kc - tap * 6;
    const int icb = icc * 32 + icq * 8;
    u16x8 av = {0, 0, 0, 0, 0, 0, 0, 0};
    if (okA) {
#pragma unroll
      for (int j = 0; j < 8; ++j)
        av[j] = f2bf(bf2f(rawA[j]) * scl[icb + j] + shl[icb + j]);
    }
    __syncthreads();
    *(u16x8*)&Al[ms * LR + icq * 8] = av;
#pragma unroll
    for (int i = 0; i < 3; ++i) {
      const int e = t + i * 256;
      *(u16x8*)&Bl[(e >> 2) * LR + (e & 3) * 8] = bvA[i];
    }
    __syncthreads();
    if (kc < 53) C2_LOAD(kc + 1, rawB, okB, bvB);
    u16x8 af[4], bf[3];
#pragma unroll
    for (int mf = 0; mf < 4; ++mf)
      af[mf] = *(const u16x8*)&Al[(mf * 16 + row) * LR + g * 8];
#pragma unroll
    for (int nf = 0; nf < 3; ++nf)
      bf[nf] = *(const u16x8*)&Bl[(wv * 48 + nf * 16 + row) * LR + g * 8];
#pragma unroll
    for (int mf = 0; mf < 4; ++mf)
#pragma unroll
      for (int nf = 0; nf < 3; ++nf) acc[mf][nf] = mfma16(af[mf], bf[nf], acc[mf][nf]);
    rawA = rawB;
    okA = okB;
#pragma unroll
    for (int i = 0; i < 3; ++i) bvA[i] = bvB[i];
  }
#undef C2_LOAD
#pragma unroll
  for (int mf = 0; mf < 4; ++mf)
#pragma unroll
    for (int nf = 0; nf < 3; ++nf)
#pragma unroll
      for (int r = 0; r < 4; ++r) {
        const int m = mf * 16 + g * 4 + r;
        const int oy = oyp * 2 + (m >> 5), ox = m & 31;
        const int oc = wv * 48 + nf * 16 + row;
        y2[((n * 32 + oy) * 32 + ox) * 192 + oc] = acc[mf][nf][r] + bl[oc];
      }
}

// ---------------------------------------------------------------------------
// K5 (R7, measured 156 us): fused ConvT single-bf16, pipelined staging,
// pad-40 LDS, chunked XCD swizzle.
// ---------------------------------------------------------------------------
#define AST 40           // px stride in u16 (80 B)
#define ARS (130 * 40)   // per-row plane stride in u16
#define BST 40           // oc stride in u16
__global__ __launch_bounds__(256) void k_convt(const u16* __restrict__ fbh,
                                               const u16* __restrict__ bph,
                                               const float* __restrict__ rgb,
                                               const float* __restrict__ hmb,
                                               u16* __restrict__ rr,
                                               float* __restrict__ hm) {
  __shared__ u16 AH[2 * ARS];       // 20.8 KB
  __shared__ u16 BH[9 * 48 * BST];  // 34.6 KB
  const int t = threadIdx.x;
  const int bid = (blockIdx.x & 7) * 128 + (blockIdx.x >> 3);
  const int n = bid >> 7, iyb = bid & 127;
  const int lane = t & 63, wv = t >> 6;
  const int row = lane & 15, g = lane >> 4;

  if (t < 8) {
    const int r = t >> 2, j = t & 3;
    const u16x8 z = {0, 0, 0, 0, 0, 0, 0, 0};
    *(u16x8*)&AH[r * ARS + 128 * AST + j * 8] = z;
  }

  float bias3[3];
#pragma unroll
  for (int nf = 0; nf < 3; ++nf) {
    const int oc = nf * 16 + row;
    bias3[nf] = (oc < 32) ? rgb[oc] : ((oc < 40) ? hmb[oc - 32] : 0.f);
  }

  const int SCt[9] = {0, 1, 1, 2, 2, 3, 3, 3, 3};
  const int SDt[9] = {0, 0, 0, 0, 1, 0, 0, 1, 1};
  const int SXt[9] = {0, 0, 1, 0, 0, 0, 1, 0, 1};

  int rr_[4], px_[4], iq_[4];
#pragma unroll
  for (int i = 0; i < 4; ++i) {
    const int u = t + i * 256;
    rr_[i] = u >> 9;
    px_[i] = (u >> 2) & 127;
    iq_[i] = u & 3;
  }

  const f32x4 z4 = {0.f, 0.f, 0.f, 0.f};
  f32x4 acc[4][2][3];
#pragma unroll
  for (int c = 0; c < 4; ++c)
#pragma unroll
    for (int m = 0; m < 2; ++m)
#pragma unroll
      for (int j = 0; j < 3; ++j) acc[c][m][j] = z4;

#define LOAD_A(ICC, DST)                                                       \
  _Pragma("unroll") for (int i = 0; i < 4; ++i) {                              \
    const int iy = iyb + rr_[i];                                               \
    u16x8 v = {0, 0, 0, 0, 0, 0, 0, 0};                                        \
    if (iy < 128)                                                              \
      v = *(const u16x8*)&fbh[((size_t)((n * 128 + iy) * 128 + px_[i]) << 9) + \
                              (ICC)*32 + iq_[i] * 8];                          \
    DST[i] = v;                                                                \
  }

#define LOAD_B(ICC, DST)                                                       \
  _Pragma("unroll") for (int i = 0; i < 7; ++i) {                              \
    const int e = t + i * 256;                                                 \
    u16x8 v = {0, 0, 0, 0, 0, 0, 0, 0};                                        \
    if (e < 1728) {                                                            \
      const int slot = e / 192, rem = e % 192;                                 \
      const int oc = rem >> 2, icq = rem & 3;                                  \
      v = *(const u16x8*)&bph[((size_t)((slot * 16 + (ICC)) * 48 + oc) << 5) + \
                              icq * 8];                                        \
    }                                                                          \
    DST[i] = v;                                                                \
  }

  u16x8 ahA[4], bhA[7], ahB[4], bhB[7];
  LOAD_A(0, ahA);
  LOAD_B(0, bhA);

  for (int icc = 0; icc < 16; ++icc) {
    __syncthreads();
#pragma unroll
    for (int i = 0; i < 4; ++i)
      *(u16x8*)&AH[rr_[i] * ARS + px_[i] * AST + iq_[i] * 8] = ahA[i];
#pragma unroll
    for (int i = 0; i < 7; ++i) {
      const int e = t + i * 256;
      if (e < 1728) {
        const int slot = e / 192, rem = e % 192;
        const int oc = rem >> 2, icq = rem & 3;
        *(u16x8*)&BH[(slot * 48 + oc) * BST + icq * 8] = bhA[i];
      }
    }
    __syncthreads();

    if (icc < 15) {
      LOAD_A(icc + 1, ahB);
      LOAD_B(icc + 1, bhB);
    }

#pragma unroll
    for (int slot = 0; slot < 9; ++slot) {
      const int cls = SCt[slot], diy = SDt[slot], dix = SXt[slot];
      const u16x8 bf0 = *(const u16x8*)&BH[(slot * 48 + row) * BST + g * 8];
      const u16x8 bf1 = *(const u16x8*)&BH[(slot * 48 + 16 + row) * BST + g * 8];
      const u16x8 bf2 = *(const u16x8*)&BH[(slot * 48 + 32 + row) * BST + g * 8];
#pragma unroll
      for (int mfl = 0; mfl < 2; ++mfl) {
        const int mf = wv * 2 + mfl;
        const u16x8 af =
            *(const u16x8*)&AH[diy * ARS + (mf * 16 + row + dix) * AST + g * 8];
        acc[cls][mfl][0] = mfma16(af, bf0, acc[cls][mfl][0]);
        acc[cls][mfl][1] = mfma16(af, bf1, acc[cls][mfl][1]);
        acc[cls][mfl][2] = mfma16(af, bf2, acc[cls][mfl][2]);
      }
    }

#pragma unroll
    for (int i = 0; i < 4; ++i) ahA[i] = ahB[i];
#pragma unroll
    for (int i = 0; i < 7; ++i) bhA[i] = bhB[i];
  }
#undef LOAD_A
#undef LOAD_B

#pragma unroll
  for (int cls = 0; cls < 4; ++cls) {
    const int oy = 2 * iyb + (cls >> 1);
    const int xp = cls & 1;
#pragma unroll
    for (int mfl = 0; mfl < 2; ++mfl)
#pragma unroll
      for (int nf = 0; nf < 3; ++nf)
#pragma unroll
        for (int r = 0; r < 4; ++r) {
          const int m = (wv * 2 + mfl) * 16 + g * 4 + r;
          const int ox = 2 * m + xp;
          const int oc = nf * 16 + row;
          const float v = acc[cls][mfl][nf][r] + bias3[nf];
          if (oc < 32)
            rr[((size_t)((n * 256 + oy) * 256 + ox)) * 32 + oc] = f2bf(v);
          else if (oc < 40)
            hm[(size_t)(n * 8 + (oc - 32)) * 65536 + oy * 256 + ox] = v;
        }
  }
}

// ---------------------------------------------------------------------------
// Generic per-channel sum/sumsq over [M][C] (C = CG*32)
// ---------------------------------------------------------------------------
template <int CG, bool BF16>
__global__ __launch_bounds__(256) void k_stats(const void* __restrict__ in_, int M,
                                               int PB, float* __restrict__ gsum,
                                               float* __restrict__ gsq) {
  const int C = CG * 32;
  __shared__ float red[8][CG * 32];
  const int t = threadIdx.x;
  const int pg = t >> 5, ln = t & 31;
  float s[CG], q[CG];
#pragma unroll
  for (int c = 0; c < CG; ++c) { s[c] = 0.f; q[c] = 0.f; }
  const int p0 = blockIdx.x * PB;
  const int pend = min(p0 + PB, M);
  for (int p = p0 + pg; p < pend; p += 8) {
#pragma unroll
    for (int c = 0; c < CG; ++c) {
      float v;
      if (BF16)
        v = bf2f(((const u16*)in_)[(size_t)p * C + c * 32 + ln]);
      else
        v = ((const float*)in_)[(size_t)p * C + c * 32 + ln];
      s[c] += v;
      q[c] += v * v;
    }
  }
#pragma unroll
  for (int c = 0; c < CG; ++c) red[pg][c * 32 + ln] = s[c];
  __syncthreads();
  if (t < C) {
    float tot = 0.f;
#pragma unroll
    for (int k = 0; k < 8; ++k) tot += red[k][t];
    atomicAdd(&gsum[t], tot);
  }
  __syncthreads();
#pragma unroll
  for (int c = 0; c < CG; ++c) red[pg][c * 32 + ln] = q[c];
  __syncthreads();
  if (t < C) {
    float tot = 0.f;
#pragma unroll
    for (int k = 0; k < 8; ++k) tot += red[k][t];
    atomicAdd(&gsq[t], tot);
  }
}

__global__ void k_bnfin(const float* __restrict__ gsum, const float* __restrict__ gsq,
                        const float* __restrict__ g, const float* __restrict__ be,
                        float invM, int C, float* __restrict__ sc,
                        float* __restrict__ sh) {
  const int t = threadIdx.x;
  if (t < C) {
    const float m = gsum[t] * invM;
    const float var = gsq[t] * invM - m * m;
    const float inv = rsqrtf(var + 1e-5f);
    const float s = g[t] * inv;
    sc[t] = s;
    sh[t] = be[t] - m * s;
  }
}

// ---------------------------------------------------------------------------
// K3: conv3 1x1 192->32 on bn(y2 fp32). y3 fp32 [8192][32].
// ---------------------------------------------------------------------------
__global__ __launch_bounds__(256) void k_conv3(const float* __restrict__ y2,
                                               const float* __restrict__ w3,
                                               const float* __restrict__ b3,
                                               const float* __restrict__ sc,
                                               const float* __restrict__ sh,
                                               float* __restrict__ y3) {
  __shared__ float wl[32 * 192];
  __shared__ float scl[192], shl[192];
  const int t = threadIdx.x;
  for (int e = t; e < 6144; e += 256) wl[e] = w3[e];
  if (t < 192) {
    scl[t] = sc[t];
    shl[t] = sh[t];
  }
  __syncthreads();
  const int px = blockIdx.x * 256 + t;
  float acc[32];
#pragma unroll
  for (int oc = 0; oc < 32; ++oc) acc[oc] = 0.f;
  const float* base = &y2[(size_t)px * 192];
  for (int icb = 0; icb < 192; icb += 8) {
    const f32x4 r0 = *(const f32x4*)&base[icb];
    const f32x4 r1 = *(const f32x4*)&base[icb + 4];
    float v[8];
#pragma unroll
    for (int j = 0; j < 8; ++j) {
      const float r = (j < 4) ? r0[j & 3] : r1[j & 3];
      v[j] = r * scl[icb + j] + shl[icb + j];
    }
#pragma unroll
    for (int oc = 0; oc < 32; ++oc) {
      const f32x4 w0 = *(const f32x4*)&wl[oc * 192 + icb];
      const f32x4 w1 = *(const f32x4*)&wl[oc * 192 + icb + 4];
      acc[oc] += v[0] * w0[0] + v[1] * w0[1] + v[2] * w0[2] + v[3] * w0[3] +
                 v[4] * w1[0] + v[5] * w1[1] + v[6] * w1[2] + v[7] * w1[3];
    }
  }
#pragma unroll
  for (int oc = 0; oc < 32; ++oc) y3[(size_t)px * 32 + oc] = acc[oc] + b3[oc];
}

// ---------------------------------------------------------------------------
// K4: classify conv 3x3 p1, 32->32 on hsw(bn2(y3))
// ---------------------------------------------------------------------------
__global__ __launch_bounds__(256) void k_clsconv1(const float* __restrict__ y3,
                                                  const float* __restrict__ w1,
                                                  const float* __restrict__ b1,
                                                  const float* __restrict__ sc,
                                                  const float* __restrict__ sh,
                                                  float* __restrict__ c1) {
  __shared__ float wl[9216];  // [ic][tap][oc]
  __shared__ float scl[32], shl[32];
  const int t = threadIdx.x;
  for (int e = t; e < 9216; e += 256) {
    const int oc = e & 31;
    const int tmp = e >> 5;
    const int tap = tmp % 9, ic = tmp / 9;
    wl[e] = w1[(oc * 32 + ic) * 9 + tap];
  }
  if (t < 32) {
    scl[t] = sc[t];
    shl[t] = sh[t];
  }
  __syncthreads();
  const int px = blockIdx.x * 64 + (t & 63);
  const int ocg = t >> 6;
  const int n = px >> 10, y0 = (px >> 5) & 31, x0 = px & 31;
  float acc[8];
#pragma unroll
  for (int j = 0; j < 8; ++j) acc[j] = 0.f;
  for (int tap = 0; tap < 9; ++tap) {
    const int dy = tap / 3 - 1, dx = tap % 3 - 1;
    const int yy = y0 + dy, xx = x0 + dx;
    if ((unsigned)yy < 32u && (unsigned)xx < 32u) {
      const float* ib = &y3[((n << 10) + yy * 32 + xx) * 32];
      for (int ic = 0; ic < 32; ++ic) {
        const float v = hsw(ib[ic] * scl[ic] + shl[ic]);
        const float* wp = &wl[(ic * 9 + tap) * 32 + ocg * 8];
#pragma unroll
        for (int j = 0; j < 8; ++j) acc[j] += v * wp[j];
      }
    }
  }
#pragma unroll
  for (int j = 0; j < 8; ++j) c1[px * 32 + ocg * 8 + j] = acc[j] + b1[ocg * 8 + j];
}

// ---------------------------------------------------------------------------
// K4c: c2 = conv3x3(hsw(bn(c1))) 32->1, then cls[n,k] = c2 . dw[k] + db[k]
// ---------------------------------------------------------------------------
__global__ __launch_bounds__(256) void k_cls(const float* __restrict__ c1,
                                             const float* __restrict__ w2,
                                             const float* __restrict__ b2,
                                             const float* __restrict__ dw,
                                             const float* __restrict__ db,
                                             const float* __restrict__ sc,
                                             const float* __restrict__ sh,
                                             float* __restrict__ cls) {
  __shared__ float wl[288];
  __shared__ float scl[32], shl[32];
  __shared__ float red0[256], red1[256];
  const int t = threadIdx.x;
  const int n = blockIdx.x;
  for (int e = t; e < 288; e += 256) wl[e] = w2[e];
  if (t < 32) {
    scl[t] = sc[t];
    shl[t] = sh[t];
  }
  __syncthreads();
  float s0 = 0.f, s1 = 0.f;
  for (int i = 0; i < 4; ++i) {
    const int px = i * 256 + t;
    const int y0 = px >> 5, x0 = px & 31;
    float c2 = b2[0];
    for (int tap = 0; tap < 9; ++tap) {
      const int dy = tap / 3 - 1, dx = tap % 3 - 1;
      const int yy = y0 + dy, xx = x0 + dx;
      if ((unsigned)yy < 32u && (unsigned)xx < 32u) {
        const float* ib = &c1[((n << 10) + yy * 32 + xx) * 32];
        for (int ic = 0; ic < 32; ++ic)
          c2 += hsw(ib[ic] * scl[ic] + shl[ic]) * wl[ic * 9 + tap];
      }
    }
    s0 += c2 * dw[px];
    s1 += c2 * dw[1024 + px];
  }
  red0[t] = s0;
  red1[t] = s1;
  __syncthreads();
  for (int s = 128; s; s >>= 1) {
    if (t < s) {
      red0[t] += red0[t + s];
      red1[t] += red1[t + s];
    }
    __syncthreads();
  }
  if (t == 0) {
    cls[n * 2 + 0] = red0[0] + db[0];
    cls[n * 2 + 1] = red1[0] + db[1];
  }
}

// ---------------------------------------------------------------------------
// K6: reg = conv3x3 p1 (hsw(bn(rr))) 32->2, fp32 NCHW [8,2,256,256]
// ---------------------------------------------------------------------------
__global__ __launch_bounds__(256) void k_regconv(const u16* __restrict__ rr,
                                                 const float* __restrict__ w,
                                                 const float* __restrict__ b,
                                                 const float* __restrict__ sc,
                                                 const float* __restrict__ sh,
                                                 float* __restrict__ reg) {
  __shared__ u16 rl[3 * 258 * 33];
  __shared__ float wl[576];
  __shared__ float scl[32], shl[32];
  const int t = threadIdx.x;
  const int n = blockIdx.x >> 8, oy = blockIdx.x & 255;
  for (int e = t; e < 576; e += 256) wl[e] = w[e];
  if (t < 32) {
    scl[t] = sc[t];
    shl[t] = sh[t];
  }
  if (t < 192) {
    const int ry = t / 64, side = (t >> 5) & 1, ic = t & 31;
    rl[(ry * 258 + side * 257) * 33 + ic] = 0;
  }
  __syncthreads();
  for (int e = t; e < 3072; e += 256) {
    const int icq8 = e & 3;
    const int pxx = (e >> 2) & 255;
    const int ry = e >> 10;
    const int rowi = oy - 1 + ry;
    u16x8 raw = {0, 0, 0, 0, 0, 0, 0, 0};
    bool ok = (unsigned)rowi < 256u;
    if (ok)
      raw = *(const u16x8*)&rr[((size_t)((n * 256 + rowi) * 256 + pxx)) * 32 + icq8 * 8];
#pragma unroll
    for (int j = 0; j < 8; ++j) {
      const int ic = icq8 * 8 + j;
      float v = 0.f;
      if (ok) v = hsw(bf2f(raw[j]) * scl[ic] + shl[ic]);
      rl[(ry * 258 + pxx + 1) * 33 + ic] = f2bf(v);
    }
  }
  __syncthreads();
  const int px = t;
  float a0 = b[0], a1 = b[1];
#pragma unroll
  for (int ry = 0; ry < 3; ++ry)
#pragma unroll
    for (int kx = 0; kx < 3; ++kx) {
      const u16* ib = &rl[(ry * 258 + px + kx) * 33];
      for (int ic = 0; ic < 32; ++ic) {
        const float v = bf2f(ib[ic]);
        a0 += v * wl[ic * 9 + ry * 3 + kx];
        a1 += v * wl[288 + ic * 9 + ry * 3 + kx];
      }
    }
  reg[(n * 2 + 0) * 65536 + oy * 256 + px] = a0;
  reg[(n * 2 + 1) * 65536 + oy * 256 + px] = a1;
}

// ---------------------------------------------------------------------------
// K7: per (n, ch) spatial argmax, lowest-index tie-break
// ---------------------------------------------------------------------------
__global__ __launch_bounds__(256) void k_argmax(const float* __restrict__ hm,
                                                int* __restrict__ idx) {
  __shared__ float bv[256];
  __shared__ int bi[256];
  const int t = threadIdx.x;
  const float* base = &hm[(size_t)blockIdx.x * 65536];
  float best = -3.402823466e38f;
  int bidx = 2147483647;
  for (int i = t; i < 65536; i += 256) {
    const float v = base[i];
    if (v > best) {
      best = v;
      bidx = i;
    }
  }
  bv[t] = best;
  bi[t] = bidx;
  __syncthreads();
  for (int s = 128; s; s >>= 1) {
    if (t < s) {
      if (bv[t + s] > bv[t] || (bv[t + s] == bv[t] && bi[t + s] < bi[t])) {
        bv[t] = bv[t + s];
        bi[t] = bi[t + s];
      }
    }
    __syncthreads();
  }
  if (t == 0) idx[blockIdx.x] = bi[0];
}

// ---------------------------------------------------------------------------
// K8: decode -> out [8,2,9]
// ---------------------------------------------------------------------------
__global__ void k_final(const float* __restrict__ cls, const int* __restrict__ idx,
                        const float* __restrict__ reg, float* __restrict__ out) {
  const int t = threadIdx.x;
  if (t >= 16) return;
  const int n = t >> 1, p = t & 1;
  const float cv = cls[n * 2 + p];
  float* o = &out[(n * 2 + p) * 9];
  if (!(cv > 0.6f)) {
    for (int i = 0; i < 9; ++i) o[i] = -1.f;
    return;
  }
  o[0] = (float)p;
  for (int c = 0; c < 4; ++c) {
    const int id = idx[n * 8 + p * 4 + c];
    const int yi = id >> 8, xi = id & 255;
    const float ox_ = reg[(n * 2 + 0) * 65536 + id];
    const float oy_ = reg[(n * 2 + 1) * 65536 + id];
    o[1 + c] = fminf(fmaxf((ox_ + (float)xi) * (1.f / 256.f), 0.f), 1.f);
    o[5 + c] = fminf(fmaxf((oy_ + (float)yi) * (1.f / 256.f), 0.f), 1.f);
  }
}

// ---------------------------------------------------------------------------
extern "C" void kernel_launch(void* const* d_in, const int* in_sizes, int n_in,
                              void* d_out, int out_size, void* d_ws, size_t ws_size,
                              hipStream_t stream) {
  const float* feature = (const float*)d_in[0];
  const float* ch_w1 = (const float*)d_in[1];
  const float* ch_b1 = (const float*)d_in[2];
  const float* ch_w2 = (const float*)d_in[3];
  const float* ch_b2 = (const float*)d_in[4];
  const float* ch_w3 = (const float*)d_in[5];
  const float* ch_b3 = (const float*)d_in[6];
  const float* ch_g1 = (const float*)d_in[7];
  const float* ch_be1 = (const float*)d_in[8];
  const float* ch_g2 = (const float*)d_in[9];
  const float* ch_be2 = (const float*)d_in[10];
  const float* cl_w1 = (const float*)d_in[11];
  const float* cl_b1 = (const float*)d_in[12];
  const float* cl_w2 = (const float*)d_in[13];
  const float* cl_b2 = (const float*)d_in[14];
  const float* cl_g = (const float*)d_in[15];
  const float* cl_be = (const float*)d_in[16];
  const float* cl_dw = (const float*)d_in[17];
  const float* cl_db = (const float*)d_in[18];
  const float* rg_tw = (const float*)d_in[19];
  const float* rg_tb = (const float*)d_in[20];
  const float* rg_g = (const float*)d_in[21];
  const float* rg_be = (const float*)d_in[22];
  const float* rg_w = (const float*)d_in[23];
  const float* rg_b = (const float*)d_in[24];
  const float* hm_tw = (const float*)d_in[25];
  const float* hm_tb = (const float*)d_in[26];
  float* out = (float*)d_out;

  char* w = (char*)d_ws;
  const size_t OFF_FB = 0;                  // 134217728
  const size_t OFF_BP1 = 134217728;         // 1769472
  const size_t OFF_BP2 = 135987200;         // 663552
  const size_t OFF_BP5 = 136650752;         // 442368
  const size_t OFF_Y1 = 137093120;          // 12582912 (bf16)
  const size_t OFF_Y2 = 149676032;          // 6291456  (fp32)
  const size_t OFF_Y3 = 155967488;          // 1048576
  const size_t OFF_C1 = 157016064;          // 1048576
  const size_t OFF_RR = 158064640;          // 33554432
  const size_t OFF_HM = 191619072;          // 16777216
  const size_t OFF_REG = 208396288;         // 4194304
  const size_t OFF_STATS = 212590592;       // 3840
  const size_t OFF_PARAMS = 212594432;      // 3840
  const size_t OFF_CLS = 212598272;         // 64
  const size_t OFF_IDX = 212598336;         // 256
  const size_t WS_NEED = 212598592;
  if (ws_size < WS_NEED) return;

  u16* FB = (u16*)(w + OFF_FB);
  u16* BP1 = (u16*)(w + OFF_BP1);
  u16* BP2 = (u16*)(w + OFF_BP2);
  u16* BP5 = (u16*)(w + OFF_BP5);
  u16* Y1 = (u16*)(w + OFF_Y1);
  float* Y2 = (float*)(w + OFF_Y2);
  float* Y3 = (float*)(w + OFF_Y3);
  float* C1 = (float*)(w + OFF_C1);
  u16* RR = (u16*)(w + OFF_RR);
  float* HM = (float*)(w + OFF_HM);
  float* REG = (float*)(w + OFF_REG);
  float* GSUM = (float*)(w + OFF_STATS);
  float* GSQ = GSUM + 480;
  float* SC = (float*)(w + OFF_PARAMS);
  float* SH = SC + 480;
  float* CLS = (float*)(w + OFF_CLS);
  int* IDX = (int*)(w + OFF_IDX);

  (void)hipMemsetAsync(w + OFF_STATS, 0, 3840, stream);

  k_tobf<<<16384, 256, 0, stream>>>(feature, FB);
  k_pack1<<<3456, 256, 0, stream>>>(ch_w1, BP1);
  k_pack2<<<1296, 256, 0, stream>>>(ch_w2, BP2);
  k_pack5<<<864, 256, 0, stream>>>(rg_tw, hm_tw, BP5);

  // CommonHead
  k_conv1<<<2048, 256, 0, stream>>>(FB, BP1, ch_b1, Y1);
  k_stats<6, true><<<128, 256, 0, stream>>>(Y1, 32768, 256, GSUM + 0, GSQ + 0);
  k_bnfin<<<1, 256, 0, stream>>>(GSUM + 0, GSQ + 0, ch_g1, ch_be1, 1.f / 32768.f, 192,
                                 SC + 0, SH + 0);
  k_conv2<<<128, 256, 0, stream>>>(Y1, BP2, ch_b2, SC + 0, SH + 0, Y2);
  k_stats<6, false><<<32, 256, 0, stream>>>(Y2, 8192, 256, GSUM + 192, GSQ + 192);
  k_bnfin<<<1, 256, 0, stream>>>(GSUM + 192, GSQ + 192, ch_g1, ch_be1, 1.f / 8192.f,
                                 192, SC + 192, SH + 192);
  k_conv3<<<32, 256, 0, stream>>>(Y2, ch_w3, ch_b3, SC + 192, SH + 192, Y3);
  k_stats<1, false><<<8, 256, 0, stream>>>(Y3, 8192, 1024, GSUM + 384, GSQ + 384);
  k_bnfin<<<1, 256, 0, stream>>>(GSUM + 384, GSQ + 384, ch_g2, ch_be2, 1.f / 8192.f,
                                 32, SC + 384, SH + 384);
  // Classify head
  k_clsconv1<<<128, 256, 0, stream>>>(Y3, cl_w1, cl_b1, SC + 384, SH + 384, C1);
  k_stats<1, false><<<8, 256, 0, stream>>>(C1, 8192, 1024, GSUM + 416, GSQ + 416);
  k_bnfin<<<1, 256, 0, stream>>>(GSUM + 416, GSQ + 416, cl_g, cl_be, 1.f / 8192.f, 32,
                                 SC + 416, SH + 416);
  k_cls<<<8, 256, 0, stream>>>(C1, cl_w2, cl_b2, cl_dw, cl_db, SC + 416, SH + 416,
                               CLS);
  // Regression + heatmap (fused convT, R7 version)
  k_convt<<<1024, 256, 0, stream>>>(FB, BP5, rg_tb, hm_tb, RR, HM);
  k_stats<1, true><<<256, 256, 0, stream>>>(RR, 524288, 2048, GSUM + 448, GSQ + 448);
  k_bnfin<<<1, 256, 0, stream>>>(GSUM + 448, GSQ + 448, rg_g, rg_be, 1.f / 524288.f,
                                 32, SC + 448, SH + 448);
  k_regconv<<<2048, 256, 0, stream>>>(RR, rg_w, rg_b, SC + 448, SH + 448, REG);
  // Decode
  k_argmax<<<64, 256, 0, stream>>>(HM, IDX);
  k_final<<<1, 64, 0, stream>>>(CLS, IDX, REG, out);
}

// Round 11
// 812.585 us; speedup vs baseline: 1.0765x; 1.0660x over previous
//
#include <hip/hip_runtime.h>

typedef unsigned short u16;
typedef u16 u16x4 __attribute__((ext_vector_type(4)));
typedef u16 u16x8 __attribute__((ext_vector_type(8)));
typedef __bf16 bf16x8 __attribute__((ext_vector_type(8)));
typedef float f32x4 __attribute__((ext_vector_type(4)));

__device__ __forceinline__ float bf2f(u16 v) {
  unsigned u = ((unsigned)v) << 16;
  return __builtin_bit_cast(float, u);
}
__device__ __forceinline__ u16 f2bf(float f) {
  unsigned u = __builtin_bit_cast(unsigned, f);
  u += 0x7FFFu + ((u >> 16) & 1u);
  return (u16)(u >> 16);
}
__device__ __forceinline__ float hsw(float v) {
  return v * fminf(fmaxf(v + 3.f, 0.f), 6.f) * (1.f / 6.f);
}
__device__ __forceinline__ f32x4 mfma16(u16x8 a, u16x8 b, f32x4 c) {
  return __builtin_amdgcn_mfma_f32_16x16x32_bf16(
      __builtin_bit_cast(bf16x8, a), __builtin_bit_cast(bf16x8, b), c, 0, 0, 0);
}

#define LR 40  // padded LDS row stride in u16 (80 B)

// ---------------------------------------------------------------------------
// K0: feature NCHW fp32 -> NHWC bf16. float4 reads, u16x4 stores.
// ---------------------------------------------------------------------------
__global__ __launch_bounds__(256) void k_tobf(const float* __restrict__ f,
                                              u16* __restrict__ fbh) {
  __shared__ float tl[64 * 65];
  const int t = threadIdx.x;
  const int bid = blockIdx.x;
  const int ict = bid & 7, xt = (bid >> 3) & 1, y = (bid >> 4) & 127, n = bid >> 11;
  const int x0 = xt * 64, ic0 = ict * 64;
#pragma unroll
  for (int i = 0; i < 4; ++i) {
    const int e = t + i * 256;        // 0..1023
    const int icl = e >> 4, xq = e & 15;
    const f32x4 v =
        *(const f32x4*)&f[((n * 512 + ic0 + icl) * 128 + y) * 128 + x0 + xq * 4];
#pragma unroll
    for (int j = 0; j < 4; ++j) tl[icl * 65 + xq * 4 + j] = v[j];
  }
  __syncthreads();
#pragma unroll
  for (int i = 0; i < 4; ++i) {
    const int e = t + i * 256;        // 0..1023
    const int xl = e >> 4;            // 0..63
    const int icg = (e & 15) * 4;     // 0..60 step 4
    u16x4 v;
#pragma unroll
    for (int j = 0; j < 4; ++j) v[j] = f2bf(tl[(icg + j) * 65 + xl]);
    *(u16x4*)&fbh[(((size_t)((n * 128 + y) * 128 + x0 + xl)) << 9) + ic0 + icg] = v;
  }
}

// ---------------------------------------------------------------------------
// Weight prepacks: [tap][icc][oc][ic32] bf16
// ---------------------------------------------------------------------------
__global__ __launch_bounds__(256) void k_pack1(const float* __restrict__ w,
                                               u16* __restrict__ bph) {
  const int e = blockIdx.x * 256 + threadIdx.x;  // < 9*16*192*32
  const int ici = e & 31;
  const int rest = e >> 5;
  const int oc = rest % 192;
  const int kc = rest / 192;
  const int icc = kc & 15, tap = kc >> 4;
  const int ic = icc * 32 + ici;
  bph[e] = f2bf(w[(oc * 512 + ic) * 9 + tap]);
}

__global__ __launch_bounds__(256) void k_pack2(const float* __restrict__ w,
                                               u16* __restrict__ bph) {
  const int e = blockIdx.x * 256 + threadIdx.x;  // < 9*6*192*32
  const int ici = e & 31;
  const int rest = e >> 5;
  const int oc = rest % 192;
  const int kc = rest / 192;
  const int icc = kc % 6, tap = kc / 6;
  const int ic = icc * 32 + ici;
  bph[e] = f2bf(w[(oc * 192 + ic) * 9 + tap]);
}

__global__ __launch_bounds__(256) void k_pack5(const float* __restrict__ rgw,
                                               const float* __restrict__ hmw,
                                               u16* __restrict__ bph) {
  const int e = blockIdx.x * 256 + threadIdx.x;  // < 9*16*48*32
  const int ici = e & 31;
  const int rest = e >> 5;
  const int oc = rest % 48;
  const int sic = rest / 48;
  const int icc = sic & 15, slot = sic >> 4;
  const int ic = icc * 32 + ici;
  const int kytab[9] = {1, 1, 1, 2, 0, 2, 2, 0, 0};
  const int kxtab[9] = {1, 2, 0, 1, 1, 2, 0, 2, 0};
  const int ky = kytab[slot], kx = kxtab[slot];
  float v = 0.f;
  if (oc < 32)
    v = rgw[((ic * 32 + oc) * 3 + ky) * 3 + kx];
  else if (oc < 40)
    v = hmw[((ic * 8 + (oc - 32)) * 3 + ky) * 3 + kx];
  bph[e] = f2bf(v);
}

// ---------------------------------------------------------------------------
// K1 (R7 revert, ~132 us): conv1 3x3 s2 p1, 512->192, register-dbuf
// prefetch, 2-barrier loop, simple shift/mask addressing. y1 bf16 NHWC.
// ---------------------------------------------------------------------------
__global__ __launch_bounds__(256) void k_conv1(const u16* __restrict__ fbh,
                                               const u16* __restrict__ bph,
                                               const float* __restrict__ bias,
                                               u16* __restrict__ y1) {
  __shared__ u16 Al[64 * LR];
  __shared__ u16 Bl[192 * LR];
  __shared__ float bl[192];
  const int t = threadIdx.x;
  const int n = blockIdx.x >> 6, oy = blockIdx.x & 63;
  if (t < 192) bl[t] = bias[t];
  const int lane = t & 63, wv = t >> 6;
  const int row = lane & 15, g = lane >> 4;
  const int oxs = t >> 2, icq = t & 3;
  const f32x4 z4 = {0.f, 0.f, 0.f, 0.f};
  f32x4 acc[4][3];
#pragma unroll
  for (int i = 0; i < 4; ++i)
#pragma unroll
    for (int j = 0; j < 3; ++j) acc[i][j] = z4;

#define C1_LOAD(KC, AV, BV)                                                    \
  {                                                                            \
    const int tap_ = (KC) >> 4, icc_ = (KC)&15;                                \
    const int ky_ = tap_ / 3, kx_ = tap_ - ky_ * 3;                            \
    const int iy_ = 2 * oy - 1 + ky_;                                          \
    const int ix_ = 2 * oxs - 1 + kx_;                                         \
    u16x8 v_ = {0, 0, 0, 0, 0, 0, 0, 0};                                       \
    if ((unsigned)iy_ < 128u && (unsigned)ix_ < 128u)                          \
      v_ = *(const u16x8*)&fbh[((size_t)((n * 128 + iy_) * 128 + ix_) << 9) +  \
                               icc_ * 32 + icq * 8];                           \
    AV = v_;                                                                   \
    const size_t bbase_ = (size_t)(tap_ * 16 + icc_) * (192 * 32);             \
    _Pragma("unroll") for (int i_ = 0; i_ < 3; ++i_) {                         \
      const int e_ = t + i_ * 256;                                             \
      BV[i_] = *(const u16x8*)&bph[bbase_ + (e_ >> 2) * 32 + (e_ & 3) * 8];    \
    }                                                                          \
  }

  u16x8 avA, bvA[3], avB, bvB[3];
  C1_LOAD(0, avA, bvA);

  for (int kc = 0; kc < 144; ++kc) {
    __syncthreads();
    *(u16x8*)&Al[oxs * LR + icq * 8] = avA;
#pragma unroll
    for (int i = 0; i < 3; ++i) {
      const int e = t + i * 256;
      *(u16x8*)&Bl[(e >> 2) * LR + (e & 3) * 8] = bvA[i];
    }
    __syncthreads();
    if (kc < 143) C1_LOAD(kc + 1, avB, bvB);
    u16x8 af[4], bf[3];
#pragma unroll
    for (int mf = 0; mf < 4; ++mf)
      af[mf] = *(const u16x8*)&Al[(mf * 16 + row) * LR + g * 8];
#pragma unroll
    for (int nf = 0; nf < 3; ++nf)
      bf[nf] = *(const u16x8*)&Bl[(wv * 48 + nf * 16 + row) * LR + g * 8];
#pragma unroll
    for (int mf = 0; mf < 4; ++mf)
#pragma unroll
      for (int nf = 0; nf < 3; ++nf) acc[mf][nf] = mfma16(af[mf], bf[nf], acc[mf][nf]);
    avA = avB;
#pragma unroll
    for (int i = 0; i < 3; ++i) bvA[i] = bvB[i];
  }
#undef C1_LOAD
#pragma unroll
  for (int mf = 0; mf < 4; ++mf)
#pragma unroll
    for (int nf = 0; nf < 3; ++nf)
#pragma unroll
      for (int r = 0; r < 4; ++r) {
        const int m = mf * 16 + g * 4 + r;
        const int oc = wv * 48 + nf * 16 + row;
        y1[((n * 64 + oy) * 64 + m) * 192 + oc] = f2bf(acc[mf][nf][r] + bl[oc]);
      }
}

// ---------------------------------------------------------------------------
// K2: conv2 3x3 s2 p1, 192->192 on bn1(y1 bf16), prefetch. y2 fp32 NHWC.
// ---------------------------------------------------------------------------
__global__ __launch_bounds__(256) void k_conv2(const u16* __restrict__ y1,
                                               const u16* __restrict__ bph,
                                               const float* __restrict__ bias,
                                               const float* __restrict__ sc,
                                               const float* __restrict__ sh,
                                               float* __restrict__ y2) {
  __shared__ u16 Al[64 * LR];
  __shared__ u16 Bl[192 * LR];
  __shared__ float bl[192], scl[192], shl[192];
  const int t = threadIdx.x;
  const int n = blockIdx.x >> 4, oyp = blockIdx.x & 15;
  if (t < 192) {
    bl[t] = bias[t];
    scl[t] = sc[t];
    shl[t] = sh[t];
  }
  __syncthreads();
  const int lane = t & 63, wv = t >> 6;
  const int row = lane & 15, g = lane >> 4;
  const int ms = t >> 2, icq = t & 3;
  const int ryr = ms >> 5, oxs = ms & 31;
  const f32x4 z4 = {0.f, 0.f, 0.f, 0.f};
  f32x4 acc[4][3];
#pragma unroll
  for (int i = 0; i < 4; ++i)
#pragma unroll
    for (int j = 0; j < 3; ++j) acc[i][j] = z4;

#define C2_LOAD(KC, RAW, OK, BV)                                               \
  {                                                                            \
    const int tap_ = (KC) / 6, icc_ = (KC)-tap_ * 6;                           \
    const int ky_ = tap_ / 3, kx_ = tap_ - ky_ * 3;                            \
    const int iy_ = 2 * (oyp * 2 + ryr) - 1 + ky_;                             \
    const int ix_ = 2 * oxs - 1 + kx_;                                         \
    OK = ((unsigned)iy_ < 64u) && ((unsigned)ix_ < 64u);                       \
    u16x8 v_ = {0, 0, 0, 0, 0, 0, 0, 0};                                       \
    if (OK)                                                                    \
      v_ = *(const u16x8*)&y1[((n * 64 + iy_) * 64 + ix_) * 192 + icc_ * 32 +  \
                              icq * 8];                                        \
    RAW = v_;                                                                  \
    const size_t bbase_ = (size_t)(tap_ * 6 + icc_) * (192 * 32);              \
    _Pragma("unroll") for (int i_ = 0; i_ < 3; ++i_) {                         \
      const int e_ = t + i_ * 256;                                             \
      BV[i_] = *(const u16x8*)&bph[bbase_ + (e_ >> 2) * 32 + (e_ & 3) * 8];    \
    }                                                                          \
  }

  u16x8 rawA, bvA[3], rawB, bvB[3];
  bool okA, okB;
  C2_LOAD(0, rawA, okA, bvA);

  for (int kc = 0; kc < 54; ++kc) {
    const int tap = kc / 6, icc = kc - tap * 6;
    const int icb = icc * 32 + icq * 8;
    u16x8 av = {0, 0, 0, 0, 0, 0, 0, 0};
    if (okA) {
#pragma unroll
      for (int j = 0; j < 8; ++j)
        av[j] = f2bf(bf2f(rawA[j]) * scl[icb + j] + shl[icb + j]);
    }
    __syncthreads();
    *(u16x8*)&Al[ms * LR + icq * 8] = av;
#pragma unroll
    for (int i = 0; i < 3; ++i) {
      const int e = t + i * 256;
      *(u16x8*)&Bl[(e >> 2) * LR + (e & 3) * 8] = bvA[i];
    }
    __syncthreads();
    if (kc < 53) C2_LOAD(kc + 1, rawB, okB, bvB);
    u16x8 af[4], bf[3];
#pragma unroll
    for (int mf = 0; mf < 4; ++mf)
      af[mf] = *(const u16x8*)&Al[(mf * 16 + row) * LR + g * 8];
#pragma unroll
    for (int nf = 0; nf < 3; ++nf)
      bf[nf] = *(const u16x8*)&Bl[(wv * 48 + nf * 16 + row) * LR + g * 8];
#pragma unroll
    for (int mf = 0; mf < 4; ++mf)
#pragma unroll
      for (int nf = 0; nf < 3; ++nf) acc[mf][nf] = mfma16(af[mf], bf[nf], acc[mf][nf]);
    rawA = rawB;
    okA = okB;
#pragma unroll
    for (int i = 0; i < 3; ++i) bvA[i] = bvB[i];
  }
#undef C2_LOAD
#pragma unroll
  for (int mf = 0; mf < 4; ++mf)
#pragma unroll
    for (int nf = 0; nf < 3; ++nf)
#pragma unroll
      for (int r = 0; r < 4; ++r) {
        const int m = mf * 16 + g * 4 + r;
        const int oy = oyp * 2 + (m >> 5), ox = m & 31;
        const int oc = wv * 48 + nf * 16 + row;
        y2[((n * 32 + oy) * 32 + ox) * 192 + oc] = acc[mf][nf][r] + bl[oc];
      }
}

// ---------------------------------------------------------------------------
// K5 (R7, measured 156 us): fused ConvT single-bf16, pipelined staging,
// pad-40 LDS, chunked XCD swizzle.
// ---------------------------------------------------------------------------
#define AST 40           // px stride in u16 (80 B)
#define ARS (130 * 40)   // per-row plane stride in u16
#define BST 40           // oc stride in u16
__global__ __launch_bounds__(256) void k_convt(const u16* __restrict__ fbh,
                                               const u16* __restrict__ bph,
                                               const float* __restrict__ rgb,
                                               const float* __restrict__ hmb,
                                               u16* __restrict__ rr,
                                               float* __restrict__ hm) {
  __shared__ u16 AH[2 * ARS];       // 20.8 KB
  __shared__ u16 BH[9 * 48 * BST];  // 34.6 KB
  const int t = threadIdx.x;
  const int bid = (blockIdx.x & 7) * 128 + (blockIdx.x >> 3);
  const int n = bid >> 7, iyb = bid & 127;
  const int lane = t & 63, wv = t >> 6;
  const int row = lane & 15, g = lane >> 4;

  if (t < 8) {
    const int r = t >> 2, j = t & 3;
    const u16x8 z = {0, 0, 0, 0, 0, 0, 0, 0};
    *(u16x8*)&AH[r * ARS + 128 * AST + j * 8] = z;
  }

  float bias3[3];
#pragma unroll
  for (int nf = 0; nf < 3; ++nf) {
    const int oc = nf * 16 + row;
    bias3[nf] = (oc < 32) ? rgb[oc] : ((oc < 40) ? hmb[oc - 32] : 0.f);
  }

  const int SCt[9] = {0, 1, 1, 2, 2, 3, 3, 3, 3};
  const int SDt[9] = {0, 0, 0, 0, 1, 0, 0, 1, 1};
  const int SXt[9] = {0, 0, 1, 0, 0, 0, 1, 0, 1};

  int rr_[4], px_[4], iq_[4];
#pragma unroll
  for (int i = 0; i < 4; ++i) {
    const int u = t + i * 256;
    rr_[i] = u >> 9;
    px_[i] = (u >> 2) & 127;
    iq_[i] = u & 3;
  }

  const f32x4 z4 = {0.f, 0.f, 0.f, 0.f};
  f32x4 acc[4][2][3];
#pragma unroll
  for (int c = 0; c < 4; ++c)
#pragma unroll
    for (int m = 0; m < 2; ++m)
#pragma unroll
      for (int j = 0; j < 3; ++j) acc[c][m][j] = z4;

#define LOAD_A(ICC, DST)                                                       \
  _Pragma("unroll") for (int i = 0; i < 4; ++i) {                              \
    const int iy = iyb + rr_[i];                                               \
    u16x8 v = {0, 0, 0, 0, 0, 0, 0, 0};                                        \
    if (iy < 128)                                                              \
      v = *(const u16x8*)&fbh[((size_t)((n * 128 + iy) * 128 + px_[i]) << 9) + \
                              (ICC)*32 + iq_[i] * 8];                          \
    DST[i] = v;                                                                \
  }

#define LOAD_B(ICC, DST)                                                       \
  _Pragma("unroll") for (int i = 0; i < 7; ++i) {                              \
    const int e = t + i * 256;                                                 \
    u16x8 v = {0, 0, 0, 0, 0, 0, 0, 0};                                        \
    if (e < 1728) {                                                            \
      const int slot = e / 192, rem = e % 192;                                 \
      const int oc = rem >> 2, icq = rem & 3;                                  \
      v = *(const u16x8*)&bph[((size_t)((slot * 16 + (ICC)) * 48 + oc) << 5) + \
                              icq * 8];                                        \
    }                                                                          \
    DST[i] = v;                                                                \
  }

  u16x8 ahA[4], bhA[7], ahB[4], bhB[7];
  LOAD_A(0, ahA);
  LOAD_B(0, bhA);

  for (int icc = 0; icc < 16; ++icc) {
    __syncthreads();
#pragma unroll
    for (int i = 0; i < 4; ++i)
      *(u16x8*)&AH[rr_[i] * ARS + px_[i] * AST + iq_[i] * 8] = ahA[i];
#pragma unroll
    for (int i = 0; i < 7; ++i) {
      const int e = t + i * 256;
      if (e < 1728) {
        const int slot = e / 192, rem = e % 192;
        const int oc = rem >> 2, icq = rem & 3;
        *(u16x8*)&BH[(slot * 48 + oc) * BST + icq * 8] = bhA[i];
      }
    }
    __syncthreads();

    if (icc < 15) {
      LOAD_A(icc + 1, ahB);
      LOAD_B(icc + 1, bhB);
    }

#pragma unroll
    for (int slot = 0; slot < 9; ++slot) {
      const int cls = SCt[slot], diy = SDt[slot], dix = SXt[slot];
      const u16x8 bf0 = *(const u16x8*)&BH[(slot * 48 + row) * BST + g * 8];
      const u16x8 bf1 = *(const u16x8*)&BH[(slot * 48 + 16 + row) * BST + g * 8];
      const u16x8 bf2 = *(const u16x8*)&BH[(slot * 48 + 32 + row) * BST + g * 8];
#pragma unroll
      for (int mfl = 0; mfl < 2; ++mfl) {
        const int mf = wv * 2 + mfl;
        const u16x8 af =
            *(const u16x8*)&AH[diy * ARS + (mf * 16 + row + dix) * AST + g * 8];
        acc[cls][mfl][0] = mfma16(af, bf0, acc[cls][mfl][0]);
        acc[cls][mfl][1] = mfma16(af, bf1, acc[cls][mfl][1]);
        acc[cls][mfl][2] = mfma16(af, bf2, acc[cls][mfl][2]);
      }
    }

#pragma unroll
    for (int i = 0; i < 4; ++i) ahA[i] = ahB[i];
#pragma unroll
    for (int i = 0; i < 7; ++i) bhA[i] = bhB[i];
  }
#undef LOAD_A
#undef LOAD_B

#pragma unroll
  for (int cls = 0; cls < 4; ++cls) {
    const int oy = 2 * iyb + (cls >> 1);
    const int xp = cls & 1;
#pragma unroll
    for (int mfl = 0; mfl < 2; ++mfl)
#pragma unroll
      for (int nf = 0; nf < 3; ++nf)
#pragma unroll
        for (int r = 0; r < 4; ++r) {
          const int m = (wv * 2 + mfl) * 16 + g * 4 + r;
          const int ox = 2 * m + xp;
          const int oc = nf * 16 + row;
          const float v = acc[cls][mfl][nf][r] + bias3[nf];
          if (oc < 32)
            rr[((size_t)((n * 256 + oy) * 256 + ox)) * 32 + oc] = f2bf(v);
          else if (oc < 40)
            hm[(size_t)(n * 8 + (oc - 32)) * 65536 + oy * 256 + ox] = v;
        }
  }
}

// ---------------------------------------------------------------------------
// Generic per-channel sum/sumsq over [M][C] (C = CG*32)
// ---------------------------------------------------------------------------
template <int CG, bool BF16>
__global__ __launch_bounds__(256) void k_stats(const void* __restrict__ in_, int M,
                                               int PB, float* __restrict__ gsum,
                                               float* __restrict__ gsq) {
  const int C = CG * 32;
  __shared__ float red[8][CG * 32];
  const int t = threadIdx.x;
  const int pg = t >> 5, ln = t & 31;
  float s[CG], q[CG];
#pragma unroll
  for (int c = 0; c < CG; ++c) { s[c] = 0.f; q[c] = 0.f; }
  const int p0 = blockIdx.x * PB;
  const int pend = min(p0 + PB, M);
  for (int p = p0 + pg; p < pend; p += 8) {
#pragma unroll
    for (int c = 0; c < CG; ++c) {
      float v;
      if (BF16)
        v = bf2f(((const u16*)in_)[(size_t)p * C + c * 32 + ln]);
      else
        v = ((const float*)in_)[(size_t)p * C + c * 32 + ln];
      s[c] += v;
      q[c] += v * v;
    }
  }
#pragma unroll
  for (int c = 0; c < CG; ++c) red[pg][c * 32 + ln] = s[c];
  __syncthreads();
  if (t < C) {
    float tot = 0.f;
#pragma unroll
    for (int k = 0; k < 8; ++k) tot += red[k][t];
    atomicAdd(&gsum[t], tot);
  }
  __syncthreads();
#pragma unroll
  for (int c = 0; c < CG; ++c) red[pg][c * 32 + ln] = q[c];
  __syncthreads();
  if (t < C) {
    float tot = 0.f;
#pragma unroll
    for (int k = 0; k < 8; ++k) tot += red[k][t];
    atomicAdd(&gsq[t], tot);
  }
}

__global__ void k_bnfin(const float* __restrict__ gsum, const float* __restrict__ gsq,
                        const float* __restrict__ g, const float* __restrict__ be,
                        float invM, int C, float* __restrict__ sc,
                        float* __restrict__ sh) {
  const int t = threadIdx.x;
  if (t < C) {
    const float m = gsum[t] * invM;
    const float var = gsq[t] * invM - m * m;
    const float inv = rsqrtf(var + 1e-5f);
    const float s = g[t] * inv;
    sc[t] = s;
    sh[t] = be[t] - m * s;
  }
}

// ---------------------------------------------------------------------------
// K3: conv3 1x1 192->32 on bn(y2 fp32). y3 fp32 [8192][32].
// ---------------------------------------------------------------------------
__global__ __launch_bounds__(256) void k_conv3(const float* __restrict__ y2,
                                               const float* __restrict__ w3,
                                               const float* __restrict__ b3,
                                               const float* __restrict__ sc,
                                               const float* __restrict__ sh,
                                               float* __restrict__ y3) {
  __shared__ float wl[32 * 192];
  __shared__ float scl[192], shl[192];
  const int t = threadIdx.x;
  for (int e = t; e < 6144; e += 256) wl[e] = w3[e];
  if (t < 192) {
    scl[t] = sc[t];
    shl[t] = sh[t];
  }
  __syncthreads();
  const int px = blockIdx.x * 256 + t;
  float acc[32];
#pragma unroll
  for (int oc = 0; oc < 32; ++oc) acc[oc] = 0.f;
  const float* base = &y2[(size_t)px * 192];
  for (int icb = 0; icb < 192; icb += 8) {
    const f32x4 r0 = *(const f32x4*)&base[icb];
    const f32x4 r1 = *(const f32x4*)&base[icb + 4];
    float v[8];
#pragma unroll
    for (int j = 0; j < 8; ++j) {
      const float r = (j < 4) ? r0[j & 3] : r1[j & 3];
      v[j] = r * scl[icb + j] + shl[icb + j];
    }
#pragma unroll
    for (int oc = 0; oc < 32; ++oc) {
      const f32x4 w0 = *(const f32x4*)&wl[oc * 192 + icb];
      const f32x4 w1 = *(const f32x4*)&wl[oc * 192 + icb + 4];
      acc[oc] += v[0] * w0[0] + v[1] * w0[1] + v[2] * w0[2] + v[3] * w0[3] +
                 v[4] * w1[0] + v[5] * w1[1] + v[6] * w1[2] + v[7] * w1[3];
    }
  }
#pragma unroll
  for (int oc = 0; oc < 32; ++oc) y3[(size_t)px * 32 + oc] = acc[oc] + b3[oc];
}

// ---------------------------------------------------------------------------
// K4: classify conv 3x3 p1, 32->32 on hsw(bn2(y3))
// ---------------------------------------------------------------------------
__global__ __launch_bounds__(256) void k_clsconv1(const float* __restrict__ y3,
                                                  const float* __restrict__ w1,
                                                  const float* __restrict__ b1,
                                                  const float* __restrict__ sc,
                                                  const float* __restrict__ sh,
                                                  float* __restrict__ c1) {
  __shared__ float wl[9216];  // [ic][tap][oc]
  __shared__ float scl[32], shl[32];
  const int t = threadIdx.x;
  for (int e = t; e < 9216; e += 256) {
    const int oc = e & 31;
    const int tmp = e >> 5;
    const int tap = tmp % 9, ic = tmp / 9;
    wl[e] = w1[(oc * 32 + ic) * 9 + tap];
  }
  if (t < 32) {
    scl[t] = sc[t];
    shl[t] = sh[t];
  }
  __syncthreads();
  const int px = blockIdx.x * 64 + (t & 63);
  const int ocg = t >> 6;
  const int n = px >> 10, y0 = (px >> 5) & 31, x0 = px & 31;
  float acc[8];
#pragma unroll
  for (int j = 0; j < 8; ++j) acc[j] = 0.f;
  for (int tap = 0; tap < 9; ++tap) {
    const int dy = tap / 3 - 1, dx = tap % 3 - 1;
    const int yy = y0 + dy, xx = x0 + dx;
    if ((unsigned)yy < 32u && (unsigned)xx < 32u) {
      const float* ib = &y3[((n << 10) + yy * 32 + xx) * 32];
      for (int ic = 0; ic < 32; ++ic) {
        const float v = hsw(ib[ic] * scl[ic] + shl[ic]);
        const float* wp = &wl[(ic * 9 + tap) * 32 + ocg * 8];
#pragma unroll
        for (int j = 0; j < 8; ++j) acc[j] += v * wp[j];
      }
    }
  }
#pragma unroll
  for (int j = 0; j < 8; ++j) c1[px * 32 + ocg * 8 + j] = acc[j] + b1[ocg * 8 + j];
}

// ---------------------------------------------------------------------------
// K4c: c2 = conv3x3(hsw(bn(c1))) 32->1, then cls[n,k] = c2 . dw[k] + db[k]
// ---------------------------------------------------------------------------
__global__ __launch_bounds__(256) void k_cls(const float* __restrict__ c1,
                                             const float* __restrict__ w2,
                                             const float* __restrict__ b2,
                                             const float* __restrict__ dw,
                                             const float* __restrict__ db,
                                             const float* __restrict__ sc,
                                             const float* __restrict__ sh,
                                             float* __restrict__ cls) {
  __shared__ float wl[288];
  __shared__ float scl[32], shl[32];
  __shared__ float red0[256], red1[256];
  const int t = threadIdx.x;
  const int n = blockIdx.x;
  for (int e = t; e < 288; e += 256) wl[e] = w2[e];
  if (t < 32) {
    scl[t] = sc[t];
    shl[t] = sh[t];
  }
  __syncthreads();
  float s0 = 0.f, s1 = 0.f;
  for (int i = 0; i < 4; ++i) {
    const int px = i * 256 + t;
    const int y0 = px >> 5, x0 = px & 31;
    float c2 = b2[0];
    for (int tap = 0; tap < 9; ++tap) {
      const int dy = tap / 3 - 1, dx = tap % 3 - 1;
      const int yy = y0 + dy, xx = x0 + dx;
      if ((unsigned)yy < 32u && (unsigned)xx < 32u) {
        const float* ib = &c1[((n << 10) + yy * 32 + xx) * 32];
        for (int ic = 0; ic < 32; ++ic)
          c2 += hsw(ib[ic] * scl[ic] + shl[ic]) * wl[ic * 9 + tap];
      }
    }
    s0 += c2 * dw[px];
    s1 += c2 * dw[1024 + px];
  }
  red0[t] = s0;
  red1[t] = s1;
  __syncthreads();
  for (int s = 128; s; s >>= 1) {
    if (t < s) {
      red0[t] += red0[t + s];
      red1[t] += red1[t + s];
    }
    __syncthreads();
  }
  if (t == 0) {
    cls[n * 2 + 0] = red0[0] + db[0];
    cls[n * 2 + 1] = red1[0] + db[1];
  }
}

// ---------------------------------------------------------------------------
// K6: reg = conv3x3 p1 (hsw(bn(rr))) 32->2, fp32 NCHW [8,2,256,256]
// ---------------------------------------------------------------------------
__global__ __launch_bounds__(256) void k_regconv(const u16* __restrict__ rr,
                                                 const float* __restrict__ w,
                                                 const float* __restrict__ b,
                                                 const float* __restrict__ sc,
                                                 const float* __restrict__ sh,
                                                 float* __restrict__ reg) {
  __shared__ u16 rl[3 * 258 * 33];
  __shared__ float wl[576];
  __shared__ float scl[32], shl[32];
  const int t = threadIdx.x;
  const int n = blockIdx.x >> 8, oy = blockIdx.x & 255;
  for (int e = t; e < 576; e += 256) wl[e] = w[e];
  if (t < 32) {
    scl[t] = sc[t];
    shl[t] = sh[t];
  }
  if (t < 192) {
    const int ry = t / 64, side = (t >> 5) & 1, ic = t & 31;
    rl[(ry * 258 + side * 257) * 33 + ic] = 0;
  }
  __syncthreads();
  for (int e = t; e < 3072; e += 256) {
    const int icq8 = e & 3;
    const int pxx = (e >> 2) & 255;
    const int ry = e >> 10;
    const int rowi = oy - 1 + ry;
    u16x8 raw = {0, 0, 0, 0, 0, 0, 0, 0};
    bool ok = (unsigned)rowi < 256u;
    if (ok)
      raw = *(const u16x8*)&rr[((size_t)((n * 256 + rowi) * 256 + pxx)) * 32 + icq8 * 8];
#pragma unroll
    for (int j = 0; j < 8; ++j) {
      const int ic = icq8 * 8 + j;
      float v = 0.f;
      if (ok) v = hsw(bf2f(raw[j]) * scl[ic] + shl[ic]);
      rl[(ry * 258 + pxx + 1) * 33 + ic] = f2bf(v);
    }
  }
  __syncthreads();
  const int px = t;
  float a0 = b[0], a1 = b[1];
#pragma unroll
  for (int ry = 0; ry < 3; ++ry)
#pragma unroll
    for (int kx = 0; kx < 3; ++kx) {
      const u16* ib = &rl[(ry * 258 + px + kx) * 33];
      for (int ic = 0; ic < 32; ++ic) {
        const float v = bf2f(ib[ic]);
        a0 += v * wl[ic * 9 + ry * 3 + kx];
        a1 += v * wl[288 + ic * 9 + ry * 3 + kx];
      }
    }
  reg[(n * 2 + 0) * 65536 + oy * 256 + px] = a0;
  reg[(n * 2 + 1) * 65536 + oy * 256 + px] = a1;
}

// ---------------------------------------------------------------------------
// K7: per (n, ch) spatial argmax, lowest-index tie-break
// ---------------------------------------------------------------------------
__global__ __launch_bounds__(256) void k_argmax(const float* __restrict__ hm,
                                                int* __restrict__ idx) {
  __shared__ float bv[256];
  __shared__ int bi[256];
  const int t = threadIdx.x;
  const float* base = &hm[(size_t)blockIdx.x * 65536];
  float best = -3.402823466e38f;
  int bidx = 2147483647;
  for (int i = t; i < 65536; i += 256) {
    const float v = base[i];
    if (v > best) {
      best = v;
      bidx = i;
    }
  }
  bv[t] = best;
  bi[t] = bidx;
  __syncthreads();
  for (int s = 128; s; s >>= 1) {
    if (t < s) {
      if (bv[t + s] > bv[t] || (bv[t + s] == bv[t] && bi[t + s] < bi[t])) {
        bv[t] = bv[t + s];
        bi[t] = bi[t + s];
      }
    }
    __syncthreads();
  }
  if (t == 0) idx[blockIdx.x] = bi[0];
}

// ---------------------------------------------------------------------------
// K8: decode -> out [8,2,9]
// ---------------------------------------------------------------------------
__global__ void k_final(const float* __restrict__ cls, const int* __restrict__ idx,
                        const float* __restrict__ reg, float* __restrict__ out) {
  const int t = threadIdx.x;
  if (t >= 16) return;
  const int n = t >> 1, p = t & 1;
  const float cv = cls[n * 2 + p];
  float* o = &out[(n * 2 + p) * 9];
  if (!(cv > 0.6f)) {
    for (int i = 0; i < 9; ++i) o[i] = -1.f;
    return;
  }
  o[0] = (float)p;
  for (int c = 0; c < 4; ++c) {
    const int id = idx[n * 8 + p * 4 + c];
    const int yi = id >> 8, xi = id & 255;
    const float ox_ = reg[(n * 2 + 0) * 65536 + id];
    const float oy_ = reg[(n * 2 + 1) * 65536 + id];
    o[1 + c] = fminf(fmaxf((ox_ + (float)xi) * (1.f / 256.f), 0.f), 1.f);
    o[5 + c] = fminf(fmaxf((oy_ + (float)yi) * (1.f / 256.f), 0.f), 1.f);
  }
}

// ---------------------------------------------------------------------------
extern "C" void kernel_launch(void* const* d_in, const int* in_sizes, int n_in,
                              void* d_out, int out_size, void* d_ws, size_t ws_size,
                              hipStream_t stream) {
  const float* feature = (const float*)d_in[0];
  const float* ch_w1 = (const float*)d_in[1];
  const float* ch_b1 = (const float*)d_in[2];
  const float* ch_w2 = (const float*)d_in[3];
  const float* ch_b2 = (const float*)d_in[4];
  const float* ch_w3 = (const float*)d_in[5];
  const float* ch_b3 = (const float*)d_in[6];
  const float* ch_g1 = (const float*)d_in[7];
  const float* ch_be1 = (const float*)d_in[8];
  const float* ch_g2 = (const float*)d_in[9];
  const float* ch_be2 = (const float*)d_in[10];
  const float* cl_w1 = (const float*)d_in[11];
  const float* cl_b1 = (const float*)d_in[12];
  const float* cl_w2 = (const float*)d_in[13];
  const float* cl_b2 = (const float*)d_in[14];
  const float* cl_g = (const float*)d_in[15];
  const float* cl_be = (const float*)d_in[16];
  const float* cl_dw = (const float*)d_in[17];
  const float* cl_db = (const float*)d_in[18];
  const float* rg_tw = (const float*)d_in[19];
  const float* rg_tb = (const float*)d_in[20];
  const float* rg_g = (const float*)d_in[21];
  const float* rg_be = (const float*)d_in[22];
  const float* rg_w = (const float*)d_in[23];
  const float* rg_b = (const float*)d_in[24];
  const float* hm_tw = (const float*)d_in[25];
  const float* hm_tb = (const float*)d_in[26];
  float* out = (float*)d_out;

  char* w = (char*)d_ws;
  const size_t OFF_FB = 0;                  // 134217728
  const size_t OFF_BP1 = 134217728;         // 1769472
  const size_t OFF_BP2 = 135987200;         // 663552
  const size_t OFF_BP5 = 136650752;         // 442368
  const size_t OFF_Y1 = 137093120;          // 12582912 (bf16)
  const size_t OFF_Y2 = 149676032;          // 6291456  (fp32)
  const size_t OFF_Y3 = 155967488;          // 1048576
  const size_t OFF_C1 = 157016064;          // 1048576
  const size_t OFF_RR = 158064640;          // 33554432
  const size_t OFF_HM = 191619072;          // 16777216
  const size_t OFF_REG = 208396288;         // 4194304
  const size_t OFF_STATS = 212590592;       // 3840
  const size_t OFF_PARAMS = 212594432;      // 3840
  const size_t OFF_CLS = 212598272;         // 64
  const size_t OFF_IDX = 212598336;         // 256
  const size_t WS_NEED = 212598592;
  if (ws_size < WS_NEED) return;

  u16* FB = (u16*)(w + OFF_FB);
  u16* BP1 = (u16*)(w + OFF_BP1);
  u16* BP2 = (u16*)(w + OFF_BP2);
  u16* BP5 = (u16*)(w + OFF_BP5);
  u16* Y1 = (u16*)(w + OFF_Y1);
  float* Y2 = (float*)(w + OFF_Y2);
  float* Y3 = (float*)(w + OFF_Y3);
  float* C1 = (float*)(w + OFF_C1);
  u16* RR = (u16*)(w + OFF_RR);
  float* HM = (float*)(w + OFF_HM);
  float* REG = (float*)(w + OFF_REG);
  float* GSUM = (float*)(w + OFF_STATS);
  float* GSQ = GSUM + 480;
  float* SC = (float*)(w + OFF_PARAMS);
  float* SH = SC + 480;
  float* CLS = (float*)(w + OFF_CLS);
  int* IDX = (int*)(w + OFF_IDX);

  (void)hipMemsetAsync(w + OFF_STATS, 0, 3840, stream);

  k_tobf<<<16384, 256, 0, stream>>>(feature, FB);
  k_pack1<<<3456, 256, 0, stream>>>(ch_w1, BP1);
  k_pack2<<<1296, 256, 0, stream>>>(ch_w2, BP2);
  k_pack5<<<864, 256, 0, stream>>>(rg_tw, hm_tw, BP5);

  // CommonHead
  k_conv1<<<512, 256, 0, stream>>>(FB, BP1, ch_b1, Y1);
  k_stats<6, true><<<128, 256, 0, stream>>>(Y1, 32768, 256, GSUM + 0, GSQ + 0);
  k_bnfin<<<1, 256, 0, stream>>>(GSUM + 0, GSQ + 0, ch_g1, ch_be1, 1.f / 32768.f, 192,
                                 SC + 0, SH + 0);
  k_conv2<<<128, 256, 0, stream>>>(Y1, BP2, ch_b2, SC + 0, SH + 0, Y2);
  k_stats<6, false><<<32, 256, 0, stream>>>(Y2, 8192, 256, GSUM + 192, GSQ + 192);
  k_bnfin<<<1, 256, 0, stream>>>(GSUM + 192, GSQ + 192, ch_g1, ch_be1, 1.f / 8192.f,
                                 192, SC + 192, SH + 192);
  k_conv3<<<32, 256, 0, stream>>>(Y2, ch_w3, ch_b3, SC + 192, SH + 192, Y3);
  k_stats<1, false><<<8, 256, 0, stream>>>(Y3, 8192, 1024, GSUM + 384, GSQ + 384);
  k_bnfin<<<1, 256, 0, stream>>>(GSUM + 384, GSQ + 384, ch_g2, ch_be2, 1.f / 8192.f,
                                 32, SC + 384, SH + 384);
  // Classify head
  k_clsconv1<<<128, 256, 0, stream>>>(Y3, cl_w1, cl_b1, SC + 384, SH + 384, C1);
  k_stats<1, false><<<8, 256, 0, stream>>>(C1, 8192, 1024, GSUM + 416, GSQ + 416);
  k_bnfin<<<1, 256, 0, stream>>>(GSUM + 416, GSQ + 416, cl_g, cl_be, 1.f / 8192.f, 32,
                                 SC + 416, SH + 416);
  k_cls<<<8, 256, 0, stream>>>(C1, cl_w2, cl_b2, cl_dw, cl_db, SC + 416, SH + 416,
                               CLS);
  // Regression + heatmap (fused convT, R7 version)
  k_convt<<<1024, 256, 0, stream>>>(FB, BP5, rg_tb, hm_tb, RR, HM);
  k_stats<1, true><<<256, 256, 0, stream>>>(RR, 524288, 2048, GSUM + 448, GSQ + 448);
  k_bnfin<<<1, 256, 0, stream>>>(GSUM + 448, GSQ + 448, rg_g, rg_be, 1.f / 524288.f,
                                 32, SC + 448, SH + 448);
  k_regconv<<<2048, 256, 0, stream>>>(RR, rg_w, rg_b, SC + 448, SH + 448, REG);
  // Decode
  k_argmax<<<64, 256, 0, stream>>>(HM, IDX);
  k_final<<<1, 64, 0, stream>>>(CLS, IDX, REG, out);
}

// Round 12
// 809.520 us; speedup vs baseline: 1.0805x; 1.0038x over previous
//
#include <hip/hip_runtime.h>

typedef unsigned short u16;
typedef u16 u16x4 __attribute__((ext_vector_type(4)));
typedef u16 u16x8 __attribute__((ext_vector_type(8)));
typedef __bf16 bf16x8 __attribute__((ext_vector_type(8)));
typedef float f32x4 __attribute__((ext_vector_type(4)));

__device__ __forceinline__ float bf2f(u16 v) {
  unsigned u = ((unsigned)v) << 16;
  return __builtin_bit_cast(float, u);
}
__device__ __forceinline__ u16 f2bf(float f) {
  unsigned u = __builtin_bit_cast(unsigned, f);
  u += 0x7FFFu + ((u >> 16) & 1u);
  return (u16)(u >> 16);
}
__device__ __forceinline__ float hsw(float v) {
  return v * fminf(fmaxf(v + 3.f, 0.f), 6.f) * (1.f / 6.f);
}
__device__ __forceinline__ f32x4 mfma16(u16x8 a, u16x8 b, f32x4 c) {
  return __builtin_amdgcn_mfma_f32_16x16x32_bf16(
      __builtin_bit_cast(bf16x8, a), __builtin_bit_cast(bf16x8, b), c, 0, 0, 0);
}

#define LR 40  // padded LDS row stride in u16 (80 B)

// ---------------------------------------------------------------------------
// K0: feature NCHW fp32 -> NHWC bf16. float4 reads, u16x4 stores.
// ---------------------------------------------------------------------------
__global__ __launch_bounds__(256) void k_tobf(const float* __restrict__ f,
                                              u16* __restrict__ fbh) {
  __shared__ float tl[64 * 65];
  const int t = threadIdx.x;
  const int bid = blockIdx.x;
  const int ict = bid & 7, xt = (bid >> 3) & 1, y = (bid >> 4) & 127, n = bid >> 11;
  const int x0 = xt * 64, ic0 = ict * 64;
#pragma unroll
  for (int i = 0; i < 4; ++i) {
    const int e = t + i * 256;        // 0..1023
    const int icl = e >> 4, xq = e & 15;
    const f32x4 v =
        *(const f32x4*)&f[((n * 512 + ic0 + icl) * 128 + y) * 128 + x0 + xq * 4];
#pragma unroll
    for (int j = 0; j < 4; ++j) tl[icl * 65 + xq * 4 + j] = v[j];
  }
  __syncthreads();
#pragma unroll
  for (int i = 0; i < 4; ++i) {
    const int e = t + i * 256;        // 0..1023
    const int xl = e >> 4;            // 0..63
    const int icg = (e & 15) * 4;     // 0..60 step 4
    u16x4 v;
#pragma unroll
    for (int j = 0; j < 4; ++j) v[j] = f2bf(tl[(icg + j) * 65 + xl]);
    *(u16x4*)&fbh[(((size_t)((n * 128 + y) * 128 + x0 + xl)) << 9) + ic0 + icg] = v;
  }
}

// ---------------------------------------------------------------------------
// Merged weight prepack: [tap][icc][oc][ic32] bf16 for conv1/conv2/convT
// blocks 0..3455 -> pack1; 3456..4751 -> pack2; 4752..5615 -> pack5
// ---------------------------------------------------------------------------
__global__ __launch_bounds__(256) void k_pack_all(const float* __restrict__ w1,
                                                  const float* __restrict__ w2,
                                                  const float* __restrict__ rgw,
                                                  const float* __restrict__ hmw,
                                                  u16* __restrict__ bp1,
                                                  u16* __restrict__ bp2,
                                                  u16* __restrict__ bp5) {
  const int b = blockIdx.x;
  if (b < 3456) {
    const int e = b * 256 + threadIdx.x;  // < 9*16*192*32
    const int ici = e & 31;
    const int rest = e >> 5;
    const int oc = rest % 192;
    const int kc = rest / 192;
    const int icc = kc & 15, tap = kc >> 4;
    const int ic = icc * 32 + ici;
    bp1[e] = f2bf(w1[(oc * 512 + ic) * 9 + tap]);
  } else if (b < 4752) {
    const int e = (b - 3456) * 256 + threadIdx.x;  // < 9*6*192*32
    const int ici = e & 31;
    const int rest = e >> 5;
    const int oc = rest % 192;
    const int kc = rest / 192;
    const int icc = kc % 6, tap = kc / 6;
    const int ic = icc * 32 + ici;
    bp2[e] = f2bf(w2[(oc * 192 + ic) * 9 + tap]);
  } else {
    const int e = (b - 4752) * 256 + threadIdx.x;  // < 9*16*48*32
    const int ici = e & 31;
    const int rest = e >> 5;
    const int oc = rest % 48;
    const int sic = rest / 48;
    const int icc = sic & 15, slot = sic >> 4;
    const int ic = icc * 32 + ici;
    const int kytab[9] = {1, 1, 1, 2, 0, 2, 2, 0, 0};
    const int kxtab[9] = {1, 2, 0, 1, 1, 2, 0, 2, 0};
    const int ky = kytab[slot], kx = kxtab[slot];
    float v = 0.f;
    if (oc < 32)
      v = rgw[((ic * 32 + oc) * 3 + ky) * 3 + kx];
    else if (oc < 40)
      v = hmw[((ic * 8 + (oc - 32)) * 3 + ky) * 3 + kx];
    bp5[e] = f2bf(v);
  }
}

// ---------------------------------------------------------------------------
// K1 (R7, measured ~132 us): conv1 3x3 s2 p1, 512->192, register-dbuf
// prefetch, 2-barrier loop. y1 bf16 NHWC.
// ---------------------------------------------------------------------------
__global__ __launch_bounds__(256) void k_conv1(const u16* __restrict__ fbh,
                                               const u16* __restrict__ bph,
                                               const float* __restrict__ bias,
                                               u16* __restrict__ y1) {
  __shared__ u16 Al[64 * LR];
  __shared__ u16 Bl[192 * LR];
  __shared__ float bl[192];
  const int t = threadIdx.x;
  const int n = blockIdx.x >> 6, oy = blockIdx.x & 63;
  if (t < 192) bl[t] = bias[t];
  const int lane = t & 63, wv = t >> 6;
  const int row = lane & 15, g = lane >> 4;
  const int oxs = t >> 2, icq = t & 3;
  const f32x4 z4 = {0.f, 0.f, 0.f, 0.f};
  f32x4 acc[4][3];
#pragma unroll
  for (int i = 0; i < 4; ++i)
#pragma unroll
    for (int j = 0; j < 3; ++j) acc[i][j] = z4;

#define C1_LOAD(KC, AV, BV)                                                    \
  {                                                                            \
    const int tap_ = (KC) >> 4, icc_ = (KC)&15;                                \
    const int ky_ = tap_ / 3, kx_ = tap_ - ky_ * 3;                            \
    const int iy_ = 2 * oy - 1 + ky_;                                          \
    const int ix_ = 2 * oxs - 1 + kx_;                                         \
    u16x8 v_ = {0, 0, 0, 0, 0, 0, 0, 0};                                       \
    if ((unsigned)iy_ < 128u && (unsigned)ix_ < 128u)                          \
      v_ = *(const u16x8*)&fbh[((size_t)((n * 128 + iy_) * 128 + ix_) << 9) +  \
                               icc_ * 32 + icq * 8];                           \
    AV = v_;                                                                   \
    const size_t bbase_ = (size_t)(tap_ * 16 + icc_) * (192 * 32);             \
    _Pragma("unroll") for (int i_ = 0; i_ < 3; ++i_) {                         \
      const int e_ = t + i_ * 256;                                             \
      BV[i_] = *(const u16x8*)&bph[bbase_ + (e_ >> 2) * 32 + (e_ & 3) * 8];    \
    }                                                                          \
  }

  u16x8 avA, bvA[3], avB, bvB[3];
  C1_LOAD(0, avA, bvA);

  for (int kc = 0; kc < 144; ++kc) {
    __syncthreads();
    *(u16x8*)&Al[oxs * LR + icq * 8] = avA;
#pragma unroll
    for (int i = 0; i < 3; ++i) {
      const int e = t + i * 256;
      *(u16x8*)&Bl[(e >> 2) * LR + (e & 3) * 8] = bvA[i];
    }
    __syncthreads();
    if (kc < 143) C1_LOAD(kc + 1, avB, bvB);
    u16x8 af[4], bf[3];
#pragma unroll
    for (int mf = 0; mf < 4; ++mf)
      af[mf] = *(const u16x8*)&Al[(mf * 16 + row) * LR + g * 8];
#pragma unroll
    for (int nf = 0; nf < 3; ++nf)
      bf[nf] = *(const u16x8*)&Bl[(wv * 48 + nf * 16 + row) * LR + g * 8];
#pragma unroll
    for (int mf = 0; mf < 4; ++mf)
#pragma unroll
      for (int nf = 0; nf < 3; ++nf) acc[mf][nf] = mfma16(af[mf], bf[nf], acc[mf][nf]);
    avA = avB;
#pragma unroll
    for (int i = 0; i < 3; ++i) bvA[i] = bvB[i];
  }
#undef C1_LOAD
#pragma unroll
  for (int mf = 0; mf < 4; ++mf)
#pragma unroll
    for (int nf = 0; nf < 3; ++nf)
#pragma unroll
      for (int r = 0; r < 4; ++r) {
        const int m = mf * 16 + g * 4 + r;
        const int oc = wv * 48 + nf * 16 + row;
        y1[((n * 64 + oy) * 64 + m) * 192 + oc] = f2bf(acc[mf][nf][r] + bl[oc]);
      }
}

// ---------------------------------------------------------------------------
// K2: conv2 3x3 s2 p1, 192->192 on bn1(y1 bf16), prefetch. y2 fp32 NHWC.
// ---------------------------------------------------------------------------
__global__ __launch_bounds__(256) void k_conv2(const u16* __restrict__ y1,
                                               const u16* __restrict__ bph,
                                               const float* __restrict__ bias,
                                               const float* __restrict__ sc,
                                               const float* __restrict__ sh,
                                               float* __restrict__ y2) {
  __shared__ u16 Al[64 * LR];
  __shared__ u16 Bl[192 * LR];
  __shared__ float bl[192], scl[192], shl[192];
  const int t = threadIdx.x;
  const int n = blockIdx.x >> 4, oyp = blockIdx.x & 15;
  if (t < 192) {
    bl[t] = bias[t];
    scl[t] = sc[t];
    shl[t] = sh[t];
  }
  __syncthreads();
  const int lane = t & 63, wv = t >> 6;
  const int row = lane & 15, g = lane >> 4;
  const int ms = t >> 2, icq = t & 3;
  const int ryr = ms >> 5, oxs = ms & 31;
  const f32x4 z4 = {0.f, 0.f, 0.f, 0.f};
  f32x4 acc[4][3];
#pragma unroll
  for (int i = 0; i < 4; ++i)
#pragma unroll
    for (int j = 0; j < 3; ++j) acc[i][j] = z4;

#define C2_LOAD(KC, RAW, OK, BV)                                               \
  {                                                                            \
    const int tap_ = (KC) / 6, icc_ = (KC)-tap_ * 6;                           \
    const int ky_ = tap_ / 3, kx_ = tap_ - ky_ * 3;                            \
    const int iy_ = 2 * (oyp * 2 + ryr) - 1 + ky_;                             \
    const int ix_ = 2 * oxs - 1 + kx_;                                         \
    OK = ((unsigned)iy_ < 64u) && ((unsigned)ix_ < 64u);                       \
    u16x8 v_ = {0, 0, 0, 0, 0, 0, 0, 0};                                       \
    if (OK)                                                                    \
      v_ = *(const u16x8*)&y1[((n * 64 + iy_) * 64 + ix_) * 192 + icc_ * 32 +  \
                              icq * 8];                                        \
    RAW = v_;                                                                  \
    const size_t bbase_ = (size_t)(tap_ * 6 + icc_) * (192 * 32);              \
    _Pragma("unroll") for (int i_ = 0; i_ < 3; ++i_) {                         \
      const int e_ = t + i_ * 256;                                             \
      BV[i_] = *(const u16x8*)&bph[bbase_ + (e_ >> 2) * 32 + (e_ & 3) * 8];    \
    }                                                                          \
  }

  u16x8 rawA, bvA[3], rawB, bvB[3];
  bool okA, okB;
  C2_LOAD(0, rawA, okA, bvA);

  for (int kc = 0; kc < 54; ++kc) {
    const int tap = kc / 6, icc = kc - tap * 6;
    const int icb = icc * 32 + icq * 8;
    u16x8 av = {0, 0, 0, 0, 0, 0, 0, 0};
    if (okA) {
#pragma unroll
      for (int j = 0; j < 8; ++j)
        av[j] = f2bf(bf2f(rawA[j]) * scl[icb + j] + shl[icb + j]);
    }
    __syncthreads();
    *(u16x8*)&Al[ms * LR + icq * 8] = av;
#pragma unroll
    for (int i = 0; i < 3; ++i) {
      const int e = t + i * 256;
      *(u16x8*)&Bl[(e >> 2) * LR + (e & 3) * 8] = bvA[i];
    }
    __syncthreads();
    if (kc < 53) C2_LOAD(kc + 1, rawB, okB, bvB);
    u16x8 af[4], bf[3];
#pragma unroll
    for (int mf = 0; mf < 4; ++mf)
      af[mf] = *(const u16x8*)&Al[(mf * 16 + row) * LR + g * 8];
#pragma unroll
    for (int nf = 0; nf < 3; ++nf)
      bf[nf] = *(const u16x8*)&Bl[(wv * 48 + nf * 16 + row) * LR + g * 8];
#pragma unroll
    for (int mf = 0; mf < 4; ++mf)
#pragma unroll
      for (int nf = 0; nf < 3; ++nf) acc[mf][nf] = mfma16(af[mf], bf[nf], acc[mf][nf]);
    rawA = rawB;
    okA = okB;
#pragma unroll
    for (int i = 0; i < 3; ++i) bvA[i] = bvB[i];
  }
#undef C2_LOAD
#pragma unroll
  for (int mf = 0; mf < 4; ++mf)
#pragma unroll
    for (int nf = 0; nf < 3; ++nf)
#pragma unroll
      for (int r = 0; r < 4; ++r) {
        const int m = mf * 16 + g * 4 + r;
        const int oy = oyp * 2 + (m >> 5), ox = m & 31;
        const int oc = wv * 48 + nf * 16 + row;
        y2[((n * 32 + oy) * 32 + ox) * 192 + oc] = acc[mf][nf][r] + bl[oc];
      }
}

// ---------------------------------------------------------------------------
// K5 (R7, measured 156 us): fused ConvT single-bf16, pipelined staging,
// pad-40 LDS, chunked XCD swizzle.
// ---------------------------------------------------------------------------
#define AST 40           // px stride in u16 (80 B)
#define ARS (130 * 40)   // per-row plane stride in u16
#define BST 40           // oc stride in u16
__global__ __launch_bounds__(256) void k_convt(const u16* __restrict__ fbh,
                                               const u16* __restrict__ bph,
                                               const float* __restrict__ rgb,
                                               const float* __restrict__ hmb,
                                               u16* __restrict__ rr,
                                               float* __restrict__ hm) {
  __shared__ u16 AH[2 * ARS];       // 20.8 KB
  __shared__ u16 BH[9 * 48 * BST];  // 34.6 KB
  const int t = threadIdx.x;
  const int bid = (blockIdx.x & 7) * 128 + (blockIdx.x >> 3);
  const int n = bid >> 7, iyb = bid & 127;
  const int lane = t & 63, wv = t >> 6;
  const int row = lane & 15, g = lane >> 4;

  if (t < 8) {
    const int r = t >> 2, j = t & 3;
    const u16x8 z = {0, 0, 0, 0, 0, 0, 0, 0};
    *(u16x8*)&AH[r * ARS + 128 * AST + j * 8] = z;
  }

  float bias3[3];
#pragma unroll
  for (int nf = 0; nf < 3; ++nf) {
    const int oc = nf * 16 + row;
    bias3[nf] = (oc < 32) ? rgb[oc] : ((oc < 40) ? hmb[oc - 32] : 0.f);
  }

  const int SCt[9] = {0, 1, 1, 2, 2, 3, 3, 3, 3};
  const int SDt[9] = {0, 0, 0, 0, 1, 0, 0, 1, 1};
  const int SXt[9] = {0, 0, 1, 0, 0, 0, 1, 0, 1};

  int rr_[4], px_[4], iq_[4];
#pragma unroll
  for (int i = 0; i < 4; ++i) {
    const int u = t + i * 256;
    rr_[i] = u >> 9;
    px_[i] = (u >> 2) & 127;
    iq_[i] = u & 3;
  }

  const f32x4 z4 = {0.f, 0.f, 0.f, 0.f};
  f32x4 acc[4][2][3];
#pragma unroll
  for (int c = 0; c < 4; ++c)
#pragma unroll
    for (int m = 0; m < 2; ++m)
#pragma unroll
      for (int j = 0; j < 3; ++j) acc[c][m][j] = z4;

#define LOAD_A(ICC, DST)                                                       \
  _Pragma("unroll") for (int i = 0; i < 4; ++i) {                              \
    const int iy = iyb + rr_[i];                                               \
    u16x8 v = {0, 0, 0, 0, 0, 0, 0, 0};                                        \
    if (iy < 128)                                                              \
      v = *(const u16x8*)&fbh[((size_t)((n * 128 + iy) * 128 + px_[i]) << 9) + \
                              (ICC)*32 + iq_[i] * 8];                          \
    DST[i] = v;                                                                \
  }

#define LOAD_B(ICC, DST)                                                       \
  _Pragma("unroll") for (int i = 0; i < 7; ++i) {                              \
    const int e = t + i * 256;                                                 \
    u16x8 v = {0, 0, 0, 0, 0, 0, 0, 0};                                        \
    if (e < 1728) {                                                            \
      const int slot = e / 192, rem = e % 192;                                 \
      const int oc = rem >> 2, icq = rem & 3;                                  \
      v = *(const u16x8*)&bph[((size_t)((slot * 16 + (ICC)) * 48 + oc) << 5) + \
                              icq * 8];                                        \
    }                                                                          \
    DST[i] = v;                                                                \
  }

  u16x8 ahA[4], bhA[7], ahB[4], bhB[7];
  LOAD_A(0, ahA);
  LOAD_B(0, bhA);

  for (int icc = 0; icc < 16; ++icc) {
    __syncthreads();
#pragma unroll
    for (int i = 0; i < 4; ++i)
      *(u16x8*)&AH[rr_[i] * ARS + px_[i] * AST + iq_[i] * 8] = ahA[i];
#pragma unroll
    for (int i = 0; i < 7; ++i) {
      const int e = t + i * 256;
      if (e < 1728) {
        const int slot = e / 192, rem = e % 192;
        const int oc = rem >> 2, icq = rem & 3;
        *(u16x8*)&BH[(slot * 48 + oc) * BST + icq * 8] = bhA[i];
      }
    }
    __syncthreads();

    if (icc < 15) {
      LOAD_A(icc + 1, ahB);
      LOAD_B(icc + 1, bhB);
    }

#pragma unroll
    for (int slot = 0; slot < 9; ++slot) {
      const int cls = SCt[slot], diy = SDt[slot], dix = SXt[slot];
      const u16x8 bf0 = *(const u16x8*)&BH[(slot * 48 + row) * BST + g * 8];
      const u16x8 bf1 = *(const u16x8*)&BH[(slot * 48 + 16 + row) * BST + g * 8];
      const u16x8 bf2 = *(const u16x8*)&BH[(slot * 48 + 32 + row) * BST + g * 8];
#pragma unroll
      for (int mfl = 0; mfl < 2; ++mfl) {
        const int mf = wv * 2 + mfl;
        const u16x8 af =
            *(const u16x8*)&AH[diy * ARS + (mf * 16 + row + dix) * AST + g * 8];
        acc[cls][mfl][0] = mfma16(af, bf0, acc[cls][mfl][0]);
        acc[cls][mfl][1] = mfma16(af, bf1, acc[cls][mfl][1]);
        acc[cls][mfl][2] = mfma16(af, bf2, acc[cls][mfl][2]);
      }
    }

#pragma unroll
    for (int i = 0; i < 4; ++i) ahA[i] = ahB[i];
#pragma unroll
    for (int i = 0; i < 7; ++i) bhA[i] = bhB[i];
  }
#undef LOAD_A
#undef LOAD_B

#pragma unroll
  for (int cls = 0; cls < 4; ++cls) {
    const int oy = 2 * iyb + (cls >> 1);
    const int xp = cls & 1;
#pragma unroll
    for (int mfl = 0; mfl < 2; ++mfl)
#pragma unroll
      for (int nf = 0; nf < 3; ++nf)
#pragma unroll
        for (int r = 0; r < 4; ++r) {
          const int m = (wv * 2 + mfl) * 16 + g * 4 + r;
          const int ox = 2 * m + xp;
          const int oc = nf * 16 + row;
          const float v = acc[cls][mfl][nf][r] + bias3[nf];
          if (oc < 32)
            rr[((size_t)((n * 256 + oy) * 256 + ox)) * 32 + oc] = f2bf(v);
          else if (oc < 40)
            hm[(size_t)(n * 8 + (oc - 32)) * 65536 + oy * 256 + ox] = v;
        }
  }
}

// ---------------------------------------------------------------------------
// Stats with fused BN finalize: per-channel sum/sumsq over [M][C]; the last
// block to finish (device-scope counter) computes sc/sh. Removes k_bnfin.
// ---------------------------------------------------------------------------
template <int CG, bool BF16>
__global__ __launch_bounds__(256) void k_statsf(
    const void* __restrict__ in_, int M, int PB, float* __restrict__ gsum,
    float* __restrict__ gsq, int* __restrict__ counter,
    const float* __restrict__ g, const float* __restrict__ be, float invM,
    float* __restrict__ sc, float* __restrict__ sh) {
  const int C = CG * 32;
  __shared__ float red[8][CG * 32];
  __shared__ int lastBlk;
  const int t = threadIdx.x;
  const int pg = t >> 5, ln = t & 31;
  float s[CG], q[CG];
#pragma unroll
  for (int c = 0; c < CG; ++c) { s[c] = 0.f; q[c] = 0.f; }
  const int p0 = blockIdx.x * PB;
  const int pend = min(p0 + PB, M);
  for (int p = p0 + pg; p < pend; p += 8) {
#pragma unroll
    for (int c = 0; c < CG; ++c) {
      float v;
      if (BF16)
        v = bf2f(((const u16*)in_)[(size_t)p * C + c * 32 + ln]);
      else
        v = ((const float*)in_)[(size_t)p * C + c * 32 + ln];
      s[c] += v;
      q[c] += v * v;
    }
  }
#pragma unroll
  for (int c = 0; c < CG; ++c) red[pg][c * 32 + ln] = s[c];
  __syncthreads();
  if (t < C) {
    float tot = 0.f;
#pragma unroll
    for (int k = 0; k < 8; ++k) tot += red[k][t];
    atomicAdd(&gsum[t], tot);
  }
  __syncthreads();
#pragma unroll
  for (int c = 0; c < CG; ++c) red[pg][c * 32 + ln] = q[c];
  __syncthreads();
  if (t < C) {
    float tot = 0.f;
#pragma unroll
    for (int k = 0; k < 8; ++k) tot += red[k][t];
    atomicAdd(&gsq[t], tot);
  }
  // last-block finalize
  __syncthreads();
  if (t == 0) {
    __threadfence();
    lastBlk = (atomicAdd(counter, 1) == (int)gridDim.x - 1) ? 1 : 0;
  }
  __syncthreads();
  if (lastBlk) {
    __threadfence();
    if (t < C) {
      const float m = gsum[t] * invM;
      const float var = gsq[t] * invM - m * m;
      const float inv = rsqrtf(var + 1e-5f);
      const float sg = g[t] * inv;
      sc[t] = sg;
      sh[t] = be[t] - m * sg;
    }
  }
}

// ---------------------------------------------------------------------------
// K3: conv3 1x1 192->32 on bn(y2 fp32). y3 fp32 [8192][32].
// ---------------------------------------------------------------------------
__global__ __launch_bounds__(256) void k_conv3(const float* __restrict__ y2,
                                               const float* __restrict__ w3,
                                               const float* __restrict__ b3,
                                               const float* __restrict__ sc,
                                               const float* __restrict__ sh,
                                               float* __restrict__ y3) {
  __shared__ float wl[32 * 192];
  __shared__ float scl[192], shl[192];
  const int t = threadIdx.x;
  for (int e = t; e < 6144; e += 256) wl[e] = w3[e];
  if (t < 192) {
    scl[t] = sc[t];
    shl[t] = sh[t];
  }
  __syncthreads();
  const int px = blockIdx.x * 256 + t;
  float acc[32];
#pragma unroll
  for (int oc = 0; oc < 32; ++oc) acc[oc] = 0.f;
  const float* base = &y2[(size_t)px * 192];
  for (int icb = 0; icb < 192; icb += 8) {
    const f32x4 r0 = *(const f32x4*)&base[icb];
    const f32x4 r1 = *(const f32x4*)&base[icb + 4];
    float v[8];
#pragma unroll
    for (int j = 0; j < 8; ++j) {
      const float r = (j < 4) ? r0[j & 3] : r1[j & 3];
      v[j] = r * scl[icb + j] + shl[icb + j];
    }
#pragma unroll
    for (int oc = 0; oc < 32; ++oc) {
      const f32x4 w0 = *(const f32x4*)&wl[oc * 192 + icb];
      const f32x4 w1 = *(const f32x4*)&wl[oc * 192 + icb + 4];
      acc[oc] += v[0] * w0[0] + v[1] * w0[1] + v[2] * w0[2] + v[3] * w0[3] +
                 v[4] * w1[0] + v[5] * w1[1] + v[6] * w1[2] + v[7] * w1[3];
    }
  }
#pragma unroll
  for (int oc = 0; oc < 32; ++oc) y3[(size_t)px * 32 + oc] = acc[oc] + b3[oc];
}

// ---------------------------------------------------------------------------
// K4: classify conv 3x3 p1, 32->32 on hsw(bn2(y3))
// ---------------------------------------------------------------------------
__global__ __launch_bounds__(256) void k_clsconv1(const float* __restrict__ y3,
                                                  const float* __restrict__ w1,
                                                  const float* __restrict__ b1,
                                                  const float* __restrict__ sc,
                                                  const float* __restrict__ sh,
                                                  float* __restrict__ c1) {
  __shared__ float wl[9216];  // [ic][tap][oc]
  __shared__ float scl[32], shl[32];
  const int t = threadIdx.x;
  for (int e = t; e < 9216; e += 256) {
    const int oc = e & 31;
    const int tmp = e >> 5;
    const int tap = tmp % 9, ic = tmp / 9;
    wl[e] = w1[(oc * 32 + ic) * 9 + tap];
  }
  if (t < 32) {
    scl[t] = sc[t];
    shl[t] = sh[t];
  }
  __syncthreads();
  const int px = blockIdx.x * 64 + (t & 63);
  const int ocg = t >> 6;
  const int n = px >> 10, y0 = (px >> 5) & 31, x0 = px & 31;
  float acc[8];
#pragma unroll
  for (int j = 0; j < 8; ++j) acc[j] = 0.f;
  for (int tap = 0; tap < 9; ++tap) {
    const int dy = tap / 3 - 1, dx = tap % 3 - 1;
    const int yy = y0 + dy, xx = x0 + dx;
    if ((unsigned)yy < 32u && (unsigned)xx < 32u) {
      const float* ib = &y3[((n << 10) + yy * 32 + xx) * 32];
      for (int ic = 0; ic < 32; ++ic) {
        const float v = hsw(ib[ic] * scl[ic] + shl[ic]);
        const float* wp = &wl[(ic * 9 + tap) * 32 + ocg * 8];
#pragma unroll
        for (int j = 0; j < 8; ++j) acc[j] += v * wp[j];
      }
    }
  }
#pragma unroll
  for (int j = 0; j < 8; ++j) c1[px * 32 + ocg * 8 + j] = acc[j] + b1[ocg * 8 + j];
}

// ---------------------------------------------------------------------------
// K4c: c2 = conv3x3(hsw(bn(c1))) 32->1, then cls[n,k] = c2 . dw[k] + db[k]
// ---------------------------------------------------------------------------
__global__ __launch_bounds__(256) void k_cls(const float* __restrict__ c1,
                                             const float* __restrict__ w2,
                                             const float* __restrict__ b2,
                                             const float* __restrict__ dw,
                                             const float* __restrict__ db,
                                             const float* __restrict__ sc,
                                             const float* __restrict__ sh,
                                             float* __restrict__ cls) {
  __shared__ float wl[288];
  __shared__ float scl[32], shl[32];
  __shared__ float red0[256], red1[256];
  const int t = threadIdx.x;
  const int n = blockIdx.x;
  for (int e = t; e < 288; e += 256) wl[e] = w2[e];
  if (t < 32) {
    scl[t] = sc[t];
    shl[t] = sh[t];
  }
  __syncthreads();
  float s0 = 0.f, s1 = 0.f;
  for (int i = 0; i < 4; ++i) {
    const int px = i * 256 + t;
    const int y0 = px >> 5, x0 = px & 31;
    float c2 = b2[0];
    for (int tap = 0; tap < 9; ++tap) {
      const int dy = tap / 3 - 1, dx = tap % 3 - 1;
      const int yy = y0 + dy, xx = x0 + dx;
      if ((unsigned)yy < 32u && (unsigned)xx < 32u) {
        const float* ib = &c1[((n << 10) + yy * 32 + xx) * 32];
        for (int ic = 0; ic < 32; ++ic)
          c2 += hsw(ib[ic] * scl[ic] + shl[ic]) * wl[ic * 9 + tap];
      }
    }
    s0 += c2 * dw[px];
    s1 += c2 * dw[1024 + px];
  }
  red0[t] = s0;
  red1[t] = s1;
  __syncthreads();
  for (int s = 128; s; s >>= 1) {
    if (t < s) {
      red0[t] += red0[t + s];
      red1[t] += red1[t + s];
    }
    __syncthreads();
  }
  if (t == 0) {
    cls[n * 2 + 0] = red0[0] + db[0];
    cls[n * 2 + 1] = red1[0] + db[1];
  }
}

// ---------------------------------------------------------------------------
// K6: reg = conv3x3 p1 (hsw(bn(rr))) 32->2, fp32 NCHW [8,2,256,256]
// ---------------------------------------------------------------------------
__global__ __launch_bounds__(256) void k_regconv(const u16* __restrict__ rr,
                                                 const float* __restrict__ w,
                                                 const float* __restrict__ b,
                                                 const float* __restrict__ sc,
                                                 const float* __restrict__ sh,
                                                 float* __restrict__ reg) {
  __shared__ u16 rl[3 * 258 * 33];
  __shared__ float wl[576];
  __shared__ float scl[32], shl[32];
  const int t = threadIdx.x;
  const int n = blockIdx.x >> 8, oy = blockIdx.x & 255;
  for (int e = t; e < 576; e += 256) wl[e] = w[e];
  if (t < 32) {
    scl[t] = sc[t];
    shl[t] = sh[t];
  }
  if (t < 192) {
    const int ry = t / 64, side = (t >> 5) & 1, ic = t & 31;
    rl[(ry * 258 + side * 257) * 33 + ic] = 0;
  }
  __syncthreads();
  for (int e = t; e < 3072; e += 256) {
    const int icq8 = e & 3;
    const int pxx = (e >> 2) & 255;
    const int ry = e >> 10;
    const int rowi = oy - 1 + ry;
    u16x8 raw = {0, 0, 0, 0, 0, 0, 0, 0};
    bool ok = (unsigned)rowi < 256u;
    if (ok)
      raw = *(const u16x8*)&rr[((size_t)((n * 256 + rowi) * 256 + pxx)) * 32 + icq8 * 8];
#pragma unroll
    for (int j = 0; j < 8; ++j) {
      const int ic = icq8 * 8 + j;
      float v = 0.f;
      if (ok) v = hsw(bf2f(raw[j]) * scl[ic] + shl[ic]);
      rl[(ry * 258 + pxx + 1) * 33 + ic] = f2bf(v);
    }
  }
  __syncthreads();
  const int px = t;
  float a0 = b[0], a1 = b[1];
#pragma unroll
  for (int ry = 0; ry < 3; ++ry)
#pragma unroll
    for (int kx = 0; kx < 3; ++kx) {
      const u16* ib = &rl[(ry * 258 + px + kx) * 33];
      for (int ic = 0; ic < 32; ++ic) {
        const float v = bf2f(ib[ic]);
        a0 += v * wl[ic * 9 + ry * 3 + kx];
        a1 += v * wl[288 + ic * 9 + ry * 3 + kx];
      }
    }
  reg[(n * 2 + 0) * 65536 + oy * 256 + px] = a0;
  reg[(n * 2 + 1) * 65536 + oy * 256 + px] = a1;
}

// ---------------------------------------------------------------------------
// K7: per (n, ch) argmax; last block also decodes -> out [8,2,9]
// ---------------------------------------------------------------------------
__global__ __launch_bounds__(256) void k_argmaxfin(const float* __restrict__ hm,
                                                   int* __restrict__ idx,
                                                   int* __restrict__ counter,
                                                   const float* __restrict__ cls,
                                                   const float* __restrict__ reg,
                                                   float* __restrict__ out) {
  __shared__ float bv[256];
  __shared__ int bi[256];
  __shared__ int lastBlk;
  const int t = threadIdx.x;
  const float* base = &hm[(size_t)blockIdx.x * 65536];
  float best = -3.402823466e38f;
  int bidx = 2147483647;
  for (int i = t; i < 65536; i += 256) {
    const float v = base[i];
    if (v > best) {
      best = v;
      bidx = i;
    }
  }
  bv[t] = best;
  bi[t] = bidx;
  __syncthreads();
  for (int s = 128; s; s >>= 1) {
    if (t < s) {
      if (bv[t + s] > bv[t] || (bv[t + s] == bv[t] && bi[t + s] < bi[t])) {
        bv[t] = bv[t + s];
        bi[t] = bi[t + s];
      }
    }
    __syncthreads();
  }
  if (t == 0) {
    idx[blockIdx.x] = bi[0];
    __threadfence();
    lastBlk = (atomicAdd(counter, 1) == (int)gridDim.x - 1) ? 1 : 0;
  }
  __syncthreads();
  if (lastBlk) {
    __threadfence();
    if (t < 16) {
      const int n = t >> 1, p = t & 1;
      const float cv = cls[n * 2 + p];
      float* o = &out[(n * 2 + p) * 9];
      if (!(cv > 0.6f)) {
        for (int i = 0; i < 9; ++i) o[i] = -1.f;
      } else {
        o[0] = (float)p;
        for (int c = 0; c < 4; ++c) {
          const int id = idx[n * 8 + p * 4 + c];
          const int yi = id >> 8, xi = id & 255;
          const float ox_ = reg[(n * 2 + 0) * 65536 + id];
          const float oy_ = reg[(n * 2 + 1) * 65536 + id];
          o[1 + c] = fminf(fmaxf((ox_ + (float)xi) * (1.f / 256.f), 0.f), 1.f);
          o[5 + c] = fminf(fmaxf((oy_ + (float)yi) * (1.f / 256.f), 0.f), 1.f);
        }
      }
    }
  }
}

// ---------------------------------------------------------------------------
extern "C" void kernel_launch(void* const* d_in, const int* in_sizes, int n_in,
                              void* d_out, int out_size, void* d_ws, size_t ws_size,
                              hipStream_t stream) {
  const float* feature = (const float*)d_in[0];
  const float* ch_w1 = (const float*)d_in[1];
  const float* ch_b1 = (const float*)d_in[2];
  const float* ch_w2 = (const float*)d_in[3];
  const float* ch_b2 = (const float*)d_in[4];
  const float* ch_w3 = (const float*)d_in[5];
  const float* ch_b3 = (const float*)d_in[6];
  const float* ch_g1 = (const float*)d_in[7];
  const float* ch_be1 = (const float*)d_in[8];
  const float* ch_g2 = (const float*)d_in[9];
  const float* ch_be2 = (const float*)d_in[10];
  const float* cl_w1 = (const float*)d_in[11];
  const float* cl_b1 = (const float*)d_in[12];
  const float* cl_w2 = (const float*)d_in[13];
  const float* cl_b2 = (const float*)d_in[14];
  const float* cl_g = (const float*)d_in[15];
  const float* cl_be = (const float*)d_in[16];
  const float* cl_dw = (const float*)d_in[17];
  const float* cl_db = (const float*)d_in[18];
  const float* rg_tw = (const float*)d_in[19];
  const float* rg_tb = (const float*)d_in[20];
  const float* rg_g = (const float*)d_in[21];
  const float* rg_be = (const float*)d_in[22];
  const float* rg_w = (const float*)d_in[23];
  const float* rg_b = (const float*)d_in[24];
  const float* hm_tw = (const float*)d_in[25];
  const float* hm_tb = (const float*)d_in[26];
  float* out = (float*)d_out;

  char* w = (char*)d_ws;
  const size_t OFF_FB = 0;                  // 134217728
  const size_t OFF_BP1 = 134217728;         // 1769472
  const size_t OFF_BP2 = 135987200;         // 663552
  const size_t OFF_BP5 = 136650752;         // 442368
  const size_t OFF_Y1 = 137093120;          // 12582912 (bf16)
  const size_t OFF_Y2 = 149676032;          // 6291456  (fp32)
  const size_t OFF_Y3 = 155967488;          // 1048576
  const size_t OFF_C1 = 157016064;          // 1048576
  const size_t OFF_RR = 158064640;          // 33554432
  const size_t OFF_HM = 191619072;          // 16777216
  const size_t OFF_REG = 208396288;         // 4194304
  const size_t OFF_STATS = 212590592;       // 3840 sums + 64 counters
  const size_t OFF_PARAMS = 212594496;      // 3840
  const size_t OFF_CLS = 212598336;         // 64
  const size_t OFF_IDX = 212598400;         // 256
  const size_t WS_NEED = 212598656;
  if (ws_size < WS_NEED) return;

  u16* FB = (u16*)(w + OFF_FB);
  u16* BP1 = (u16*)(w + OFF_BP1);
  u16* BP2 = (u16*)(w + OFF_BP2);
  u16* BP5 = (u16*)(w + OFF_BP5);
  u16* Y1 = (u16*)(w + OFF_Y1);
  float* Y2 = (float*)(w + OFF_Y2);
  float* Y3 = (float*)(w + OFF_Y3);
  float* C1 = (float*)(w + OFF_C1);
  u16* RR = (u16*)(w + OFF_RR);
  float* HM = (float*)(w + OFF_HM);
  float* REG = (float*)(w + OFF_REG);
  float* GSUM = (float*)(w + OFF_STATS);
  float* GSQ = GSUM + 480;
  int* CNT = (int*)(w + OFF_STATS + 3840);
  float* SC = (float*)(w + OFF_PARAMS);
  float* SH = SC + 480;
  float* CLS = (float*)(w + OFF_CLS);
  int* IDX = (int*)(w + OFF_IDX);

  (void)hipMemsetAsync(w + OFF_STATS, 0, 3904, stream);

  k_tobf<<<16384, 256, 0, stream>>>(feature, FB);
  k_pack_all<<<5616, 256, 0, stream>>>(ch_w1, ch_w2, rg_tw, hm_tw, BP1, BP2, BP5);

  // CommonHead
  k_conv1<<<512, 256, 0, stream>>>(FB, BP1, ch_b1, Y1);
  k_statsf<6, true><<<128, 256, 0, stream>>>(Y1, 32768, 256, GSUM + 0, GSQ + 0,
                                             CNT + 0, ch_g1, ch_be1, 1.f / 32768.f,
                                             SC + 0, SH + 0);
  k_conv2<<<128, 256, 0, stream>>>(Y1, BP2, ch_b2, SC + 0, SH + 0, Y2);
  k_statsf<6, false><<<32, 256, 0, stream>>>(Y2, 8192, 256, GSUM + 192, GSQ + 192,
                                             CNT + 1, ch_g1, ch_be1, 1.f / 8192.f,
                                             SC + 192, SH + 192);
  k_conv3<<<32, 256, 0, stream>>>(Y2, ch_w3, ch_b3, SC + 192, SH + 192, Y3);
  k_statsf<1, false><<<8, 256, 0, stream>>>(Y3, 8192, 1024, GSUM + 384, GSQ + 384,
                                            CNT + 2, ch_g2, ch_be2, 1.f / 8192.f,
                                            SC + 384, SH + 384);
  // Classify head
  k_clsconv1<<<128, 256, 0, stream>>>(Y3, cl_w1, cl_b1, SC + 384, SH + 384, C1);
  k_statsf<1, false><<<8, 256, 0, stream>>>(C1, 8192, 1024, GSUM + 416, GSQ + 416,
                                            CNT + 3, cl_g, cl_be, 1.f / 8192.f,
                                            SC + 416, SH + 416);
  k_cls<<<8, 256, 0, stream>>>(C1, cl_w2, cl_b2, cl_dw, cl_db, SC + 416, SH + 416,
                               CLS);
  // Regression + heatmap (fused convT, R7 version)
  k_convt<<<1024, 256, 0, stream>>>(FB, BP5, rg_tb, hm_tb, RR, HM);
  k_statsf<1, true><<<256, 256, 0, stream>>>(RR, 524288, 2048, GSUM + 448, GSQ + 448,
                                             CNT + 4, rg_g, rg_be, 1.f / 524288.f,
                                             SC + 448, SH + 448);
  k_regconv<<<2048, 256, 0, stream>>>(RR, rg_w, rg_b, SC + 448, SH + 448, REG);
  // Decode (argmax + final fused)
  k_argmaxfin<<<64, 256, 0, stream>>>(HM, IDX, CNT + 5, CLS, REG, out);
}

// Round 13
// 768.456 us; speedup vs baseline: 1.1383x; 1.0534x over previous
//
#include <hip/hip_runtime.h>

typedef unsigned short u16;
typedef u16 u16x4 __attribute__((ext_vector_type(4)));
typedef u16 u16x8 __attribute__((ext_vector_type(8)));
typedef __bf16 bf16x8 __attribute__((ext_vector_type(8)));
typedef float f32x4 __attribute__((ext_vector_type(4)));

__device__ __forceinline__ float bf2f(u16 v) {
  unsigned u = ((unsigned)v) << 16;
  return __builtin_bit_cast(float, u);
}
__device__ __forceinline__ u16 f2bf(float f) {
  unsigned u = __builtin_bit_cast(unsigned, f);
  u += 0x7FFFu + ((u >> 16) & 1u);
  return (u16)(u >> 16);
}
__device__ __forceinline__ float hsw(float v) {
  return v * fminf(fmaxf(v + 3.f, 0.f), 6.f) * (1.f / 6.f);
}
__device__ __forceinline__ f32x4 mfma16(u16x8 a, u16x8 b, f32x4 c) {
  return __builtin_amdgcn_mfma_f32_16x16x32_bf16(
      __builtin_bit_cast(bf16x8, a), __builtin_bit_cast(bf16x8, b), c, 0, 0, 0);
}

#define LR 40  // padded LDS row stride in u16 (80 B)

// ---------------------------------------------------------------------------
// K0: feature NCHW fp32 -> NHWC bf16. float4 reads, u16x4 stores.
// ---------------------------------------------------------------------------
__global__ __launch_bounds__(256) void k_tobf(const float* __restrict__ f,
                                              u16* __restrict__ fbh) {
  __shared__ float tl[64 * 65];
  const int t = threadIdx.x;
  const int bid = blockIdx.x;
  const int ict = bid & 7, xt = (bid >> 3) & 1, y = (bid >> 4) & 127, n = bid >> 11;
  const int x0 = xt * 64, ic0 = ict * 64;
#pragma unroll
  for (int i = 0; i < 4; ++i) {
    const int e = t + i * 256;
    const int icl = e >> 4, xq = e & 15;
    const f32x4 v =
        *(const f32x4*)&f[((n * 512 + ic0 + icl) * 128 + y) * 128 + x0 + xq * 4];
#pragma unroll
    for (int j = 0; j < 4; ++j) tl[icl * 65 + xq * 4 + j] = v[j];
  }
  __syncthreads();
#pragma unroll
  for (int i = 0; i < 4; ++i) {
    const int e = t + i * 256;
    const int xl = e >> 4;
    const int icg = (e & 15) * 4;
    u16x4 v;
#pragma unroll
    for (int j = 0; j < 4; ++j) v[j] = f2bf(tl[(icg + j) * 65 + xl]);
    *(u16x4*)&fbh[(((size_t)((n * 128 + y) * 128 + x0 + xl)) << 9) + ic0 + icg] = v;
  }
}

// ---------------------------------------------------------------------------
// Merged weight prepack
// ---------------------------------------------------------------------------
__global__ __launch_bounds__(256) void k_pack_all(const float* __restrict__ w1,
                                                  const float* __restrict__ w2,
                                                  const float* __restrict__ rgw,
                                                  const float* __restrict__ hmw,
                                                  u16* __restrict__ bp1,
                                                  u16* __restrict__ bp2,
                                                  u16* __restrict__ bp5) {
  const int b = blockIdx.x;
  if (b < 3456) {
    const int e = b * 256 + threadIdx.x;
    const int ici = e & 31;
    const int rest = e >> 5;
    const int oc = rest % 192;
    const int kc = rest / 192;
    const int icc = kc & 15, tap = kc >> 4;
    const int ic = icc * 32 + ici;
    bp1[e] = f2bf(w1[(oc * 512 + ic) * 9 + tap]);
  } else if (b < 4752) {
    const int e = (b - 3456) * 256 + threadIdx.x;
    const int ici = e & 31;
    const int rest = e >> 5;
    const int oc = rest % 192;
    const int kc = rest / 192;
    const int icc = kc % 6, tap = kc / 6;
    const int ic = icc * 32 + ici;
    bp2[e] = f2bf(w2[(oc * 192 + ic) * 9 + tap]);
  } else {
    const int e = (b - 4752) * 256 + threadIdx.x;
    const int ici = e & 31;
    const int rest = e >> 5;
    const int oc = rest % 48;
    const int sic = rest / 48;
    const int icc = sic & 15, slot = sic >> 4;
    const int ic = icc * 32 + ici;
    const int kytab[9] = {1, 1, 1, 2, 0, 2, 2, 0, 0};
    const int kxtab[9] = {1, 2, 0, 1, 1, 2, 0, 2, 0};
    const int ky = kytab[slot], kx = kxtab[slot];
    float v = 0.f;
    if (oc < 32)
      v = rgw[((ic * 32 + oc) * 3 + ky) * 3 + kx];
    else if (oc < 40)
      v = hmw[((ic * 8 + (oc - 32)) * 3 + ky) * 3 + kx];
    bp5[e] = f2bf(v);
  }
}

// ---------------------------------------------------------------------------
// K1: conv1 (R7 K-loop, byte-identical) + fused BN stats epilogue.
// ---------------------------------------------------------------------------
__global__ __launch_bounds__(256) void k_conv1(const u16* __restrict__ fbh,
                                               const u16* __restrict__ bph,
                                               const float* __restrict__ bias,
                                               u16* __restrict__ y1,
                                               float* __restrict__ gsum,
                                               float* __restrict__ gsq,
                                               int* __restrict__ counter,
                                               const float* __restrict__ g1,
                                               const float* __restrict__ be1,
                                               float* __restrict__ sc,
                                               float* __restrict__ sh) {
  __shared__ u16 Al[64 * LR];
  __shared__ u16 Bl[192 * LR];
  __shared__ float bl[192];
  __shared__ float ssum[192], ssq[192];
  __shared__ int lastBlk;
  const int t = threadIdx.x;
  const int n = blockIdx.x >> 6, oy = blockIdx.x & 63;
  if (t < 192) {
    bl[t] = bias[t];
    ssum[t] = 0.f;
    ssq[t] = 0.f;
  }
  const int lane = t & 63, wv = t >> 6;
  const int row = lane & 15, g = lane >> 4;
  const int oxs = t >> 2, icq = t & 3;
  const f32x4 z4 = {0.f, 0.f, 0.f, 0.f};
  f32x4 acc[4][3];
#pragma unroll
  for (int i = 0; i < 4; ++i)
#pragma unroll
    for (int j = 0; j < 3; ++j) acc[i][j] = z4;

#define C1_LOAD(KC, AV, BV)                                                    \
  {                                                                            \
    const int tap_ = (KC) >> 4, icc_ = (KC)&15;                                \
    const int ky_ = tap_ / 3, kx_ = tap_ - ky_ * 3;                            \
    const int iy_ = 2 * oy - 1 + ky_;                                          \
    const int ix_ = 2 * oxs - 1 + kx_;                                         \
    u16x8 v_ = {0, 0, 0, 0, 0, 0, 0, 0};                                       \
    if ((unsigned)iy_ < 128u && (unsigned)ix_ < 128u)                          \
      v_ = *(const u16x8*)&fbh[((size_t)((n * 128 + iy_) * 128 + ix_) << 9) +  \
                               icc_ * 32 + icq * 8];                           \
    AV = v_;                                                                   \
    const size_t bbase_ = (size_t)(tap_ * 16 + icc_) * (192 * 32);             \
    _Pragma("unroll") for (int i_ = 0; i_ < 3; ++i_) {                         \
      const int e_ = t + i_ * 256;                                             \
      BV[i_] = *(const u16x8*)&bph[bbase_ + (e_ >> 2) * 32 + (e_ & 3) * 8];    \
    }                                                                          \
  }

  u16x8 avA, bvA[3], avB, bvB[3];
  C1_LOAD(0, avA, bvA);

  for (int kc = 0; kc < 144; ++kc) {
    __syncthreads();
    *(u16x8*)&Al[oxs * LR + icq * 8] = avA;
#pragma unroll
    for (int i = 0; i < 3; ++i) {
      const int e = t + i * 256;
      *(u16x8*)&Bl[(e >> 2) * LR + (e & 3) * 8] = bvA[i];
    }
    __syncthreads();
    if (kc < 143) C1_LOAD(kc + 1, avB, bvB);
    u16x8 af[4], bf[3];
#pragma unroll
    for (int mf = 0; mf < 4; ++mf)
      af[mf] = *(const u16x8*)&Al[(mf * 16 + row) * LR + g * 8];
#pragma unroll
    for (int nf = 0; nf < 3; ++nf)
      bf[nf] = *(const u16x8*)&Bl[(wv * 48 + nf * 16 + row) * LR + g * 8];
#pragma unroll
    for (int mf = 0; mf < 4; ++mf)
#pragma unroll
      for (int nf = 0; nf < 3; ++nf) acc[mf][nf] = mfma16(af[mf], bf[nf], acc[mf][nf]);
    avA = avB;
#pragma unroll
    for (int i = 0; i < 3; ++i) bvA[i] = bvB[i];
  }
#undef C1_LOAD

  float s3[3] = {0.f, 0.f, 0.f}, q3[3] = {0.f, 0.f, 0.f};
#pragma unroll
  for (int mf = 0; mf < 4; ++mf)
#pragma unroll
    for (int nf = 0; nf < 3; ++nf)
#pragma unroll
      for (int r = 0; r < 4; ++r) {
        const int m = mf * 16 + g * 4 + r;
        const int oc = wv * 48 + nf * 16 + row;
        const float v = acc[mf][nf][r] + bl[oc];
        y1[((n * 64 + oy) * 64 + m) * 192 + oc] = f2bf(v);
        s3[nf] += v;
        q3[nf] += v * v;
      }
#pragma unroll
  for (int nf = 0; nf < 3; ++nf) {
    const int oc = wv * 48 + nf * 16 + row;
    atomicAdd(&ssum[oc], s3[nf]);
    atomicAdd(&ssq[oc], q3[nf]);
  }
  __syncthreads();
  if (t < 192) {
    atomicAdd(&gsum[t], ssum[t]);
    atomicAdd(&gsq[t], ssq[t]);
  }
  __syncthreads();
  if (t == 0) {
    __threadfence();
    lastBlk = (atomicAdd(counter, 1) == (int)gridDim.x - 1) ? 1 : 0;
  }
  __syncthreads();
  if (lastBlk) {
    __threadfence();
    if (t < 192) {
      const float m = gsum[t] * (1.f / 32768.f);
      const float var = gsq[t] * (1.f / 32768.f) - m * m;
      const float inv = rsqrtf(var + 1e-5f);
      const float sg = g1[t] * inv;
      sc[t] = sg;
      sh[t] = be1[t] - m * sg;
    }
  }
}

// ---------------------------------------------------------------------------
// K2: conv2 (R7 K-loop) + fused BN stats epilogue (y2 stats for conv3 BN).
// ---------------------------------------------------------------------------
__global__ __launch_bounds__(256) void k_conv2(const u16* __restrict__ y1,
                                               const u16* __restrict__ bph,
                                               const float* __restrict__ bias,
                                               const float* __restrict__ sc_in,
                                               const float* __restrict__ sh_in,
                                               float* __restrict__ y2,
                                               float* __restrict__ gsum,
                                               float* __restrict__ gsq,
                                               int* __restrict__ counter,
                                               const float* __restrict__ g1,
                                               const float* __restrict__ be1,
                                               float* __restrict__ sc,
                                               float* __restrict__ sh) {
  __shared__ u16 Al[64 * LR];
  __shared__ u16 Bl[192 * LR];
  __shared__ float bl[192], scl[192], shl[192];
  __shared__ float ssum[192], ssq[192];
  __shared__ int lastBlk;
  const int t = threadIdx.x;
  const int n = blockIdx.x >> 4, oyp = blockIdx.x & 15;
  if (t < 192) {
    bl[t] = bias[t];
    scl[t] = sc_in[t];
    shl[t] = sh_in[t];
    ssum[t] = 0.f;
    ssq[t] = 0.f;
  }
  __syncthreads();
  const int lane = t & 63, wv = t >> 6;
  const int row = lane & 15, g = lane >> 4;
  const int ms = t >> 2, icq = t & 3;
  const int ryr = ms >> 5, oxs = ms & 31;
  const f32x4 z4 = {0.f, 0.f, 0.f, 0.f};
  f32x4 acc[4][3];
#pragma unroll
  for (int i = 0; i < 4; ++i)
#pragma unroll
    for (int j = 0; j < 3; ++j) acc[i][j] = z4;

#define C2_LOAD(KC, RAW, OK, BV)                                               \
  {                                                                            \
    const int tap_ = (KC) / 6, icc_ = (KC)-tap_ * 6;                           \
    const int ky_ = tap_ / 3, kx_ = tap_ - ky_ * 3;                            \
    const int iy_ = 2 * (oyp * 2 + ryr) - 1 + ky_;                             \
    const int ix_ = 2 * oxs - 1 + kx_;                                         \
    OK = ((unsigned)iy_ < 64u) && ((unsigned)ix_ < 64u);                       \
    u16x8 v_ = {0, 0, 0, 0, 0, 0, 0, 0};                                       \
    if (OK)                                                                    \
      v_ = *(const u16x8*)&y1[((n * 64 + iy_) * 64 + ix_) * 192 + icc_ * 32 +  \
                              icq * 8];                                        \
    RAW = v_;                                                                  \
    const size_t bbase_ = (size_t)(tap_ * 6 + icc_) * (192 * 32);              \
    _Pragma("unroll") for (int i_ = 0; i_ < 3; ++i_) {                         \
      const int e_ = t + i_ * 256;                                             \
      BV[i_] = *(const u16x8*)&bph[bbase_ + (e_ >> 2) * 32 + (e_ & 3) * 8];    \
    }                                                                          \
  }

  u16x8 rawA, bvA[3], rawB, bvB[3];
  bool okA, okB;
  C2_LOAD(0, rawA, okA, bvA);

  for (int kc = 0; kc < 54; ++kc) {
    const int tap = kc / 6, icc = kc - tap * 6;
    const int icb = icc * 32 + icq * 8;
    u16x8 av = {0, 0, 0, 0, 0, 0, 0, 0};
    if (okA) {
#pragma unroll
      for (int j = 0; j < 8; ++j)
        av[j] = f2bf(bf2f(rawA[j]) * scl[icb + j] + shl[icb + j]);
    }
    __syncthreads();
    *(u16x8*)&Al[ms * LR + icq * 8] = av;
#pragma unroll
    for (int i = 0; i < 3; ++i) {
      const int e = t + i * 256;
      *(u16x8*)&Bl[(e >> 2) * LR + (e & 3) * 8] = bvA[i];
    }
    __syncthreads();
    if (kc < 53) C2_LOAD(kc + 1, rawB, okB, bvB);
    u16x8 af[4], bf[3];
#pragma unroll
    for (int mf = 0; mf < 4; ++mf)
      af[mf] = *(const u16x8*)&Al[(mf * 16 + row) * LR + g * 8];
#pragma unroll
    for (int nf = 0; nf < 3; ++nf)
      bf[nf] = *(const u16x8*)&Bl[(wv * 48 + nf * 16 + row) * LR + g * 8];
#pragma unroll
    for (int mf = 0; mf < 4; ++mf)
#pragma unroll
      for (int nf = 0; nf < 3; ++nf) acc[mf][nf] = mfma16(af[mf], bf[nf], acc[mf][nf]);
    rawA = rawB;
    okA = okB;
#pragma unroll
    for (int i = 0; i < 3; ++i) bvA[i] = bvB[i];
  }
#undef C2_LOAD

  float s3[3] = {0.f, 0.f, 0.f}, q3[3] = {0.f, 0.f, 0.f};
#pragma unroll
  for (int mf = 0; mf < 4; ++mf)
#pragma unroll
    for (int nf = 0; nf < 3; ++nf)
#pragma unroll
      for (int r = 0; r < 4; ++r) {
        const int m = mf * 16 + g * 4 + r;
        const int oy = oyp * 2 + (m >> 5), ox = m & 31;
        const int oc = wv * 48 + nf * 16 + row;
        const float v = acc[mf][nf][r] + bl[oc];
        y2[((n * 32 + oy) * 32 + ox) * 192 + oc] = v;
        s3[nf] += v;
        q3[nf] += v * v;
      }
#pragma unroll
  for (int nf = 0; nf < 3; ++nf) {
    const int oc = wv * 48 + nf * 16 + row;
    atomicAdd(&ssum[oc], s3[nf]);
    atomicAdd(&ssq[oc], q3[nf]);
  }
  __syncthreads();
  if (t < 192) {
    atomicAdd(&gsum[t], ssum[t]);
    atomicAdd(&gsq[t], ssq[t]);
  }
  __syncthreads();
  if (t == 0) {
    __threadfence();
    lastBlk = (atomicAdd(counter, 1) == (int)gridDim.x - 1) ? 1 : 0;
  }
  __syncthreads();
  if (lastBlk) {
    __threadfence();
    if (t < 192) {
      const float m = gsum[t] * (1.f / 8192.f);
      const float var = gsq[t] * (1.f / 8192.f) - m * m;
      const float inv = rsqrtf(var + 1e-5f);
      const float sg = g1[t] * inv;
      sc[t] = sg;
      sh[t] = be1[t] - m * sg;
    }
  }
}

// ---------------------------------------------------------------------------
// K5: convt (R7 K-loop, byte-identical) + fused rr BN stats epilogue.
// ---------------------------------------------------------------------------
#define AST 40
#define ARS (130 * 40)
#define BST 40
__global__ __launch_bounds__(256) void k_convt(const u16* __restrict__ fbh,
                                               const u16* __restrict__ bph,
                                               const float* __restrict__ rgb,
                                               const float* __restrict__ hmb,
                                               u16* __restrict__ rr,
                                               float* __restrict__ hm,
                                               float* __restrict__ gsum,
                                               float* __restrict__ gsq,
                                               int* __restrict__ counter,
                                               const float* __restrict__ rg_g,
                                               const float* __restrict__ rg_be,
                                               float* __restrict__ sc,
                                               float* __restrict__ sh) {
  __shared__ u16 AH[2 * ARS];
  __shared__ u16 BH[9 * 48 * BST];
  __shared__ float ssum[32], ssq[32];
  __shared__ int lastBlk;
  const int t = threadIdx.x;
  const int bid = (blockIdx.x & 7) * 128 + (blockIdx.x >> 3);
  const int n = bid >> 7, iyb = bid & 127;
  const int lane = t & 63, wv = t >> 6;
  const int row = lane & 15, g = lane >> 4;

  if (t < 8) {
    const int r = t >> 2, j = t & 3;
    const u16x8 z = {0, 0, 0, 0, 0, 0, 0, 0};
    *(u16x8*)&AH[r * ARS + 128 * AST + j * 8] = z;
  }
  if (t < 32) {
    ssum[t] = 0.f;
    ssq[t] = 0.f;
  }

  float bias3[3];
#pragma unroll
  for (int nf = 0; nf < 3; ++nf) {
    const int oc = nf * 16 + row;
    bias3[nf] = (oc < 32) ? rgb[oc] : ((oc < 40) ? hmb[oc - 32] : 0.f);
  }

  const int SCt[9] = {0, 1, 1, 2, 2, 3, 3, 3, 3};
  const int SDt[9] = {0, 0, 0, 0, 1, 0, 0, 1, 1};
  const int SXt[9] = {0, 0, 1, 0, 0, 0, 1, 0, 1};

  int rr_[4], px_[4], iq_[4];
#pragma unroll
  for (int i = 0; i < 4; ++i) {
    const int u = t + i * 256;
    rr_[i] = u >> 9;
    px_[i] = (u >> 2) & 127;
    iq_[i] = u & 3;
  }

  const f32x4 z4 = {0.f, 0.f, 0.f, 0.f};
  f32x4 acc[4][2][3];
#pragma unroll
  for (int c = 0; c < 4; ++c)
#pragma unroll
    for (int m = 0; m < 2; ++m)
#pragma unroll
      for (int j = 0; j < 3; ++j) acc[c][m][j] = z4;

#define LOAD_A(ICC, DST)                                                       \
  _Pragma("unroll") for (int i = 0; i < 4; ++i) {                              \
    const int iy = iyb + rr_[i];                                               \
    u16x8 v = {0, 0, 0, 0, 0, 0, 0, 0};                                        \
    if (iy < 128)                                                              \
      v = *(const u16x8*)&fbh[((size_t)((n * 128 + iy) * 128 + px_[i]) << 9) + \
                              (ICC)*32 + iq_[i] * 8];                          \
    DST[i] = v;                                                                \
  }

#define LOAD_B(ICC, DST)                                                       \
  _Pragma("unroll") for (int i = 0; i < 7; ++i) {                              \
    const int e = t + i * 256;                                                 \
    u16x8 v = {0, 0, 0, 0, 0, 0, 0, 0};                                        \
    if (e < 1728) {                                                            \
      const int slot = e / 192, rem = e % 192;                                 \
      const int oc = rem >> 2, icq = rem & 3;                                  \
      v = *(const u16x8*)&bph[((size_t)((slot * 16 + (ICC)) * 48 + oc) << 5) + \
                              icq * 8];                                        \
    }                                                                          \
    DST[i] = v;                                                                \
  }

  u16x8 ahA[4], bhA[7], ahB[4], bhB[7];
  LOAD_A(0, ahA);
  LOAD_B(0, bhA);

  for (int icc = 0; icc < 16; ++icc) {
    __syncthreads();
#pragma unroll
    for (int i = 0; i < 4; ++i)
      *(u16x8*)&AH[rr_[i] * ARS + px_[i] * AST + iq_[i] * 8] = ahA[i];
#pragma unroll
    for (int i = 0; i < 7; ++i) {
      const int e = t + i * 256;
      if (e < 1728) {
        const int slot = e / 192, rem = e % 192;
        const int oc = rem >> 2, icq = rem & 3;
        *(u16x8*)&BH[(slot * 48 + oc) * BST + icq * 8] = bhA[i];
      }
    }
    __syncthreads();

    if (icc < 15) {
      LOAD_A(icc + 1, ahB);
      LOAD_B(icc + 1, bhB);
    }

#pragma unroll
    for (int slot = 0; slot < 9; ++slot) {
      const int cls = SCt[slot], diy = SDt[slot], dix = SXt[slot];
      const u16x8 bf0 = *(const u16x8*)&BH[(slot * 48 + row) * BST + g * 8];
      const u16x8 bf1 = *(const u16x8*)&BH[(slot * 48 + 16 + row) * BST + g * 8];
      const u16x8 bf2 = *(const u16x8*)&BH[(slot * 48 + 32 + row) * BST + g * 8];
#pragma unroll
      for (int mfl = 0; mfl < 2; ++mfl) {
        const int mf = wv * 2 + mfl;
        const u16x8 af =
            *(const u16x8*)&AH[diy * ARS + (mf * 16 + row + dix) * AST + g * 8];
        acc[cls][mfl][0] = mfma16(af, bf0, acc[cls][mfl][0]);
        acc[cls][mfl][1] = mfma16(af, bf1, acc[cls][mfl][1]);
        acc[cls][mfl][2] = mfma16(af, bf2, acc[cls][mfl][2]);
      }
    }

#pragma unroll
    for (int i = 0; i < 4; ++i) ahA[i] = ahB[i];
#pragma unroll
    for (int i = 0; i < 7; ++i) bhA[i] = bhB[i];
  }
#undef LOAD_A
#undef LOAD_B

  float s2[2] = {0.f, 0.f}, q2[2] = {0.f, 0.f};
#pragma unroll
  for (int cls = 0; cls < 4; ++cls) {
    const int oy = 2 * iyb + (cls >> 1);
    const int xp = cls & 1;
#pragma unroll
    for (int mfl = 0; mfl < 2; ++mfl)
#pragma unroll
      for (int nf = 0; nf < 3; ++nf)
#pragma unroll
        for (int r = 0; r < 4; ++r) {
          const int m = (wv * 2 + mfl) * 16 + g * 4 + r;
          const int ox = 2 * m + xp;
          const int oc = nf * 16 + row;
          const float v = acc[cls][mfl][nf][r] + bias3[nf];
          if (oc < 32) {
            rr[((size_t)((n * 256 + oy) * 256 + ox)) * 32 + oc] = f2bf(v);
            s2[nf] += v;
            q2[nf] += v * v;
          } else if (oc < 40)
            hm[(size_t)(n * 8 + (oc - 32)) * 65536 + oy * 256 + ox] = v;
        }
  }
#pragma unroll
  for (int nf = 0; nf < 2; ++nf) {
    atomicAdd(&ssum[nf * 16 + row], s2[nf]);
    atomicAdd(&ssq[nf * 16 + row], q2[nf]);
  }
  __syncthreads();
  if (t < 32) {
    atomicAdd(&gsum[t], ssum[t]);
    atomicAdd(&gsq[t], ssq[t]);
  }
  __syncthreads();
  if (t == 0) {
    __threadfence();
    lastBlk = (atomicAdd(counter, 1) == (int)gridDim.x - 1) ? 1 : 0;
  }
  __syncthreads();
  if (lastBlk) {
    __threadfence();
    if (t < 32) {
      const float m = gsum[t] * (1.f / 524288.f);
      const float var = gsq[t] * (1.f / 524288.f) - m * m;
      const float inv = rsqrtf(var + 1e-5f);
      const float sg = rg_g[t] * inv;
      sc[t] = sg;
      sh[t] = rg_be[t] - m * sg;
    }
  }
}

// ---------------------------------------------------------------------------
// Stats + BN finalize (kept only for small 32-ch tensors Y3, C1)
// ---------------------------------------------------------------------------
template <int CG, bool BF16>
__global__ __launch_bounds__(256) void k_statsf(
    const void* __restrict__ in_, int M, int PB, float* __restrict__ gsum,
    float* __restrict__ gsq, int* __restrict__ counter,
    const float* __restrict__ g, const float* __restrict__ be, float invM,
    float* __restrict__ sc, float* __restrict__ sh) {
  const int C = CG * 32;
  __shared__ float red[8][CG * 32];
  __shared__ int lastBlk;
  const int t = threadIdx.x;
  const int pg = t >> 5, ln = t & 31;
  float s[CG], q[CG];
#pragma unroll
  for (int c = 0; c < CG; ++c) { s[c] = 0.f; q[c] = 0.f; }
  const int p0 = blockIdx.x * PB;
  const int pend = min(p0 + PB, M);
  for (int p = p0 + pg; p < pend; p += 8) {
#pragma unroll
    for (int c = 0; c < CG; ++c) {
      float v;
      if (BF16)
        v = bf2f(((const u16*)in_)[(size_t)p * C + c * 32 + ln]);
      else
        v = ((const float*)in_)[(size_t)p * C + c * 32 + ln];
      s[c] += v;
      q[c] += v * v;
    }
  }
#pragma unroll
  for (int c = 0; c < CG; ++c) red[pg][c * 32 + ln] = s[c];
  __syncthreads();
  if (t < C) {
    float tot = 0.f;
#pragma unroll
    for (int k = 0; k < 8; ++k) tot += red[k][t];
    atomicAdd(&gsum[t], tot);
  }
  __syncthreads();
#pragma unroll
  for (int c = 0; c < CG; ++c) red[pg][c * 32 + ln] = q[c];
  __syncthreads();
  if (t < C) {
    float tot = 0.f;
#pragma unroll
    for (int k = 0; k < 8; ++k) tot += red[k][t];
    atomicAdd(&gsq[t], tot);
  }
  __syncthreads();
  if (t == 0) {
    __threadfence();
    lastBlk = (atomicAdd(counter, 1) == (int)gridDim.x - 1) ? 1 : 0;
  }
  __syncthreads();
  if (lastBlk) {
    __threadfence();
    if (t < C) {
      const float m = gsum[t] * invM;
      const float var = gsq[t] * invM - m * m;
      const float inv = rsqrtf(var + 1e-5f);
      const float sg = g[t] * inv;
      sc[t] = sg;
      sh[t] = be[t] - m * sg;
    }
  }
}

// ---------------------------------------------------------------------------
// K3: conv3 1x1 192->32 on bn(y2 fp32). y3 fp32 [8192][32].
// ---------------------------------------------------------------------------
__global__ __launch_bounds__(256) void k_conv3(const float* __restrict__ y2,
                                               const float* __restrict__ w3,
                                               const float* __restrict__ b3,
                                               const float* __restrict__ sc,
                                               const float* __restrict__ sh,
                                               float* __restrict__ y3) {
  __shared__ float wl[32 * 192];
  __shared__ float scl[192], shl[192];
  const int t = threadIdx.x;
  for (int e = t; e < 6144; e += 256) wl[e] = w3[e];
  if (t < 192) {
    scl[t] = sc[t];
    shl[t] = sh[t];
  }
  __syncthreads();
  const int px = blockIdx.x * 256 + t;
  float acc[32];
#pragma unroll
  for (int oc = 0; oc < 32; ++oc) acc[oc] = 0.f;
  const float* base = &y2[(size_t)px * 192];
  for (int icb = 0; icb < 192; icb += 8) {
    const f32x4 r0 = *(const f32x4*)&base[icb];
    const f32x4 r1 = *(const f32x4*)&base[icb + 4];
    float v[8];
#pragma unroll
    for (int j = 0; j < 8; ++j) {
      const float r = (j < 4) ? r0[j & 3] : r1[j & 3];
      v[j] = r * scl[icb + j] + shl[icb + j];
    }
#pragma unroll
    for (int oc = 0; oc < 32; ++oc) {
      const f32x4 w0 = *(const f32x4*)&wl[oc * 192 + icb];
      const f32x4 w1 = *(const f32x4*)&wl[oc * 192 + icb + 4];
      acc[oc] += v[0] * w0[0] + v[1] * w0[1] + v[2] * w0[2] + v[3] * w0[3] +
                 v[4] * w1[0] + v[5] * w1[1] + v[6] * w1[2] + v[7] * w1[3];
    }
  }
#pragma unroll
  for (int oc = 0; oc < 32; ++oc) y3[(size_t)px * 32 + oc] = acc[oc] + b3[oc];
}

// ---------------------------------------------------------------------------
// K4: classify conv 3x3 p1, 32->32 on hsw(bn2(y3))
// ---------------------------------------------------------------------------
__global__ __launch_bounds__(256) void k_clsconv1(const float* __restrict__ y3,
                                                  const float* __restrict__ w1,
                                                  const float* __restrict__ b1,
                                                  const float* __restrict__ sc,
                                                  const float* __restrict__ sh,
                                                  float* __restrict__ c1) {
  __shared__ float wl[9216];  // [ic][tap][oc]
  __shared__ float scl[32], shl[32];
  const int t = threadIdx.x;
  for (int e = t; e < 9216; e += 256) {
    const int oc = e & 31;
    const int tmp = e >> 5;
    const int tap = tmp % 9, ic = tmp / 9;
    wl[e] = w1[(oc * 32 + ic) * 9 + tap];
  }
  if (t < 32) {
    scl[t] = sc[t];
    shl[t] = sh[t];
  }
  __syncthreads();
  const int px = blockIdx.x * 64 + (t & 63);
  const int ocg = t >> 6;
  const int n = px >> 10, y0 = (px >> 5) & 31, x0 = px & 31;
  float acc[8];
#pragma unroll
  for (int j = 0; j < 8; ++j) acc[j] = 0.f;
  for (int tap = 0; tap < 9; ++tap) {
    const int dy = tap / 3 - 1, dx = tap % 3 - 1;
    const int yy = y0 + dy, xx = x0 + dx;
    if ((unsigned)yy < 32u && (unsigned)xx < 32u) {
      const float* ib = &y3[((n << 10) + yy * 32 + xx) * 32];
      for (int ic = 0; ic < 32; ++ic) {
        const float v = hsw(ib[ic] * scl[ic] + shl[ic]);
        const float* wp = &wl[(ic * 9 + tap) * 32 + ocg * 8];
#pragma unroll
        for (int j = 0; j < 8; ++j) acc[j] += v * wp[j];
      }
    }
  }
#pragma unroll
  for (int j = 0; j < 8; ++j) c1[px * 32 + ocg * 8 + j] = acc[j] + b1[ocg * 8 + j];
}

// ---------------------------------------------------------------------------
// K4c: c2 = conv3x3(hsw(bn(c1))) 32->1, then cls[n,k] = c2 . dw[k] + db[k]
// ---------------------------------------------------------------------------
__global__ __launch_bounds__(256) void k_cls(const float* __restrict__ c1,
                                             const float* __restrict__ w2,
                                             const float* __restrict__ b2,
                                             const float* __restrict__ dw,
                                             const float* __restrict__ db,
                                             const float* __restrict__ sc,
                                             const float* __restrict__ sh,
                                             float* __restrict__ cls) {
  __shared__ float wl[288];
  __shared__ float scl[32], shl[32];
  __shared__ float red0[256], red1[256];
  const int t = threadIdx.x;
  const int n = blockIdx.x;
  for (int e = t; e < 288; e += 256) wl[e] = w2[e];
  if (t < 32) {
    scl[t] = sc[t];
    shl[t] = sh[t];
  }
  __syncthreads();
  float s0 = 0.f, s1 = 0.f;
  for (int i = 0; i < 4; ++i) {
    const int px = i * 256 + t;
    const int y0 = px >> 5, x0 = px & 31;
    float c2 = b2[0];
    for (int tap = 0; tap < 9; ++tap) {
      const int dy = tap / 3 - 1, dx = tap % 3 - 1;
      const int yy = y0 + dy, xx = x0 + dx;
      if ((unsigned)yy < 32u && (unsigned)xx < 32u) {
        const float* ib = &c1[((n << 10) + yy * 32 + xx) * 32];
        for (int ic = 0; ic < 32; ++ic)
          c2 += hsw(ib[ic] * scl[ic] + shl[ic]) * wl[ic * 9 + tap];
      }
    }
    s0 += c2 * dw[px];
    s1 += c2 * dw[1024 + px];
  }
  red0[t] = s0;
  red1[t] = s1;
  __syncthreads();
  for (int s = 128; s; s >>= 1) {
    if (t < s) {
      red0[t] += red0[t + s];
      red1[t] += red1[t + s];
    }
    __syncthreads();
  }
  if (t == 0) {
    cls[n * 2 + 0] = red0[0] + db[0];
    cls[n * 2 + 1] = red1[0] + db[1];
  }
}

// ---------------------------------------------------------------------------
// K6: reg = conv3x3 p1 (hsw(bn(rr))) 32->2, fp32 NCHW [8,2,256,256]
// ---------------------------------------------------------------------------
__global__ __launch_bounds__(256) void k_regconv(const u16* __restrict__ rr,
                                                 const float* __restrict__ w,
                                                 const float* __restrict__ b,
                                                 const float* __restrict__ sc,
                                                 const float* __restrict__ sh,
                                                 float* __restrict__ reg) {
  __shared__ u16 rl[3 * 258 * 33];
  __shared__ float wl[576];
  __shared__ float scl[32], shl[32];
  const int t = threadIdx.x;
  const int n = blockIdx.x >> 8, oy = blockIdx.x & 255;
  for (int e = t; e < 576; e += 256) wl[e] = w[e];
  if (t < 32) {
    scl[t] = sc[t];
    shl[t] = sh[t];
  }
  if (t < 192) {
    const int ry = t / 64, side = (t >> 5) & 1, ic = t & 31;
    rl[(ry * 258 + side * 257) * 33 + ic] = 0;
  }
  __syncthreads();
  for (int e = t; e < 3072; e += 256) {
    const int icq8 = e & 3;
    const int pxx = (e >> 2) & 255;
    const int ry = e >> 10;
    const int rowi = oy - 1 + ry;
    u16x8 raw = {0, 0, 0, 0, 0, 0, 0, 0};
    bool ok = (unsigned)rowi < 256u;
    if (ok)
      raw = *(const u16x8*)&rr[((size_t)((n * 256 + rowi) * 256 + pxx)) * 32 + icq8 * 8];
#pragma unroll
    for (int j = 0; j < 8; ++j) {
      const int ic = icq8 * 8 + j;
      float v = 0.f;
      if (ok) v = hsw(bf2f(raw[j]) * scl[ic] + shl[ic]);
      rl[(ry * 258 + pxx + 1) * 33 + ic] = f2bf(v);
    }
  }
  __syncthreads();
  const int px = t;
  float a0 = b[0], a1 = b[1];
#pragma unroll
  for (int ry = 0; ry < 3; ++ry)
#pragma unroll
    for (int kx = 0; kx < 3; ++kx) {
      const u16* ib = &rl[(ry * 258 + px + kx) * 33];
      for (int ic = 0; ic < 32; ++ic) {
        const float v = bf2f(ib[ic]);
        a0 += v * wl[ic * 9 + ry * 3 + kx];
        a1 += v * wl[288 + ic * 9 + ry * 3 + kx];
      }
    }
  reg[(n * 2 + 0) * 65536 + oy * 256 + px] = a0;
  reg[(n * 2 + 1) * 65536 + oy * 256 + px] = a1;
}

// ---------------------------------------------------------------------------
// K7: per (n, ch) argmax; last block also decodes -> out [8,2,9]
// ---------------------------------------------------------------------------
__global__ __launch_bounds__(256) void k_argmaxfin(const float* __restrict__ hm,
                                                   int* __restrict__ idx,
                                                   int* __restrict__ counter,
                                                   const float* __restrict__ cls,
                                                   const float* __restrict__ reg,
                                                   float* __restrict__ out) {
  __shared__ float bv[256];
  __shared__ int bi[256];
  __shared__ int lastBlk;
  const int t = threadIdx.x;
  const float* base = &hm[(size_t)blockIdx.x * 65536];
  float best = -3.402823466e38f;
  int bidx = 2147483647;
  for (int i = t; i < 65536; i += 256) {
    const float v = base[i];
    if (v > best) {
      best = v;
      bidx = i;
    }
  }
  bv[t] = best;
  bi[t] = bidx;
  __syncthreads();
  for (int s = 128; s; s >>= 1) {
    if (t < s) {
      if (bv[t + s] > bv[t] || (bv[t + s] == bv[t] && bi[t + s] < bi[t])) {
        bv[t] = bv[t + s];
        bi[t] = bi[t + s];
      }
    }
    __syncthreads();
  }
  if (t == 0) {
    idx[blockIdx.x] = bi[0];
    __threadfence();
    lastBlk = (atomicAdd(counter, 1) == (int)gridDim.x - 1) ? 1 : 0;
  }
  __syncthreads();
  if (lastBlk) {
    __threadfence();
    if (t < 16) {
      const int n = t >> 1, p = t & 1;
      const float cv = cls[n * 2 + p];
      float* o = &out[(n * 2 + p) * 9];
      if (!(cv > 0.6f)) {
        for (int i = 0; i < 9; ++i) o[i] = -1.f;
      } else {
        o[0] = (float)p;
        for (int c = 0; c < 4; ++c) {
          const int id = idx[n * 8 + p * 4 + c];
          const int yi = id >> 8, xi = id & 255;
          const float ox_ = reg[(n * 2 + 0) * 65536 + id];
          const float oy_ = reg[(n * 2 + 1) * 65536 + id];
          o[1 + c] = fminf(fmaxf((ox_ + (float)xi) * (1.f / 256.f), 0.f), 1.f);
          o[5 + c] = fminf(fmaxf((oy_ + (float)yi) * (1.f / 256.f), 0.f), 1.f);
        }
      }
    }
  }
}

// ---------------------------------------------------------------------------
extern "C" void kernel_launch(void* const* d_in, const int* in_sizes, int n_in,
                              void* d_out, int out_size, void* d_ws, size_t ws_size,
                              hipStream_t stream) {
  const float* feature = (const float*)d_in[0];
  const float* ch_w1 = (const float*)d_in[1];
  const float* ch_b1 = (const float*)d_in[2];
  const float* ch_w2 = (const float*)d_in[3];
  const float* ch_b2 = (const float*)d_in[4];
  const float* ch_w3 = (const float*)d_in[5];
  const float* ch_b3 = (const float*)d_in[6];
  const float* ch_g1 = (const float*)d_in[7];
  const float* ch_be1 = (const float*)d_in[8];
  const float* ch_g2 = (const float*)d_in[9];
  const float* ch_be2 = (const float*)d_in[10];
  const float* cl_w1 = (const float*)d_in[11];
  const float* cl_b1 = (const float*)d_in[12];
  const float* cl_w2 = (const float*)d_in[13];
  const float* cl_b2 = (const float*)d_in[14];
  const float* cl_g = (const float*)d_in[15];
  const float* cl_be = (const float*)d_in[16];
  const float* cl_dw = (const float*)d_in[17];
  const float* cl_db = (const float*)d_in[18];
  const float* rg_tw = (const float*)d_in[19];
  const float* rg_tb = (const float*)d_in[20];
  const float* rg_g = (const float*)d_in[21];
  const float* rg_be = (const float*)d_in[22];
  const float* rg_w = (const float*)d_in[23];
  const float* rg_b = (const float*)d_in[24];
  const float* hm_tw = (const float*)d_in[25];
  const float* hm_tb = (const float*)d_in[26];
  float* out = (float*)d_out;

  char* w = (char*)d_ws;
  const size_t OFF_FB = 0;                  // 134217728
  const size_t OFF_BP1 = 134217728;         // 1769472
  const size_t OFF_BP2 = 135987200;         // 663552
  const size_t OFF_BP5 = 136650752;         // 442368
  const size_t OFF_Y1 = 137093120;          // 12582912 (bf16)
  const size_t OFF_Y2 = 149676032;          // 6291456  (fp32)
  const size_t OFF_Y3 = 155967488;          // 1048576
  const size_t OFF_C1 = 157016064;          // 1048576
  const size_t OFF_RR = 158064640;          // 33554432
  const size_t OFF_HM = 191619072;          // 16777216
  const size_t OFF_REG = 208396288;         // 4194304
  const size_t OFF_STATS = 212590592;       // 3840 sums + 64 counters
  const size_t OFF_PARAMS = 212594496;      // 3840
  const size_t OFF_CLS = 212598336;         // 64
  const size_t OFF_IDX = 212598400;         // 256
  const size_t WS_NEED = 212598656;
  if (ws_size < WS_NEED) return;

  u16* FB = (u16*)(w + OFF_FB);
  u16* BP1 = (u16*)(w + OFF_BP1);
  u16* BP2 = (u16*)(w + OFF_BP2);
  u16* BP5 = (u16*)(w + OFF_BP5);
  u16* Y1 = (u16*)(w + OFF_Y1);
  float* Y2 = (float*)(w + OFF_Y2);
  float* Y3 = (float*)(w + OFF_Y3);
  float* C1 = (float*)(w + OFF_C1);
  u16* RR = (u16*)(w + OFF_RR);
  float* HM = (float*)(w + OFF_HM);
  float* REG = (float*)(w + OFF_REG);
  float* GSUM = (float*)(w + OFF_STATS);
  float* GSQ = GSUM + 480;
  int* CNT = (int*)(w + OFF_STATS + 3840);
  float* SC = (float*)(w + OFF_PARAMS);
  float* SH = SC + 480;
  float* CLS = (float*)(w + OFF_CLS);
  int* IDX = (int*)(w + OFF_IDX);

  (void)hipMemsetAsync(w + OFF_STATS, 0, 3904, stream);

  k_tobf<<<16384, 256, 0, stream>>>(feature, FB);
  k_pack_all<<<5616, 256, 0, stream>>>(ch_w1, ch_w2, rg_tw, hm_tw, BP1, BP2, BP5);

  // CommonHead (BN1 stats fused into conv1/conv2 epilogues)
  k_conv1<<<512, 256, 0, stream>>>(FB, BP1, ch_b1, Y1, GSUM + 0, GSQ + 0, CNT + 0,
                                   ch_g1, ch_be1, SC + 0, SH + 0);
  k_conv2<<<128, 256, 0, stream>>>(Y1, BP2, ch_b2, SC + 0, SH + 0, Y2, GSUM + 192,
                                   GSQ + 192, CNT + 1, ch_g1, ch_be1, SC + 192,
                                   SH + 192);
  k_conv3<<<32, 256, 0, stream>>>(Y2, ch_w3, ch_b3, SC + 192, SH + 192, Y3);
  k_statsf<1, false><<<8, 256, 0, stream>>>(Y3, 8192, 1024, GSUM + 384, GSQ + 384,
                                            CNT + 2, ch_g2, ch_be2, 1.f / 8192.f,
                                            SC + 384, SH + 384);
  // Classify head
  k_clsconv1<<<128, 256, 0, stream>>>(Y3, cl_w1, cl_b1, SC + 384, SH + 384, C1);
  k_statsf<1, false><<<8, 256, 0, stream>>>(C1, 8192, 1024, GSUM + 416, GSQ + 416,
                                            CNT + 3, cl_g, cl_be, 1.f / 8192.f,
                                            SC + 416, SH + 416);
  k_cls<<<8, 256, 0, stream>>>(C1, cl_w2, cl_b2, cl_dw, cl_db, SC + 416, SH + 416,
                               CLS);
  // Regression + heatmap (rr BN stats fused into convt epilogue)
  k_convt<<<1024, 256, 0, stream>>>(FB, BP5, rg_tb, hm_tb, RR, HM, GSUM + 448,
                                    GSQ + 448, CNT + 4, rg_g, rg_be, SC + 448,
                                    SH + 448);
  k_regconv<<<2048, 256, 0, stream>>>(RR, rg_w, rg_b, SC + 448, SH + 448, REG);
  // Decode (argmax + final fused)
  k_argmaxfin<<<64, 256, 0, stream>>>(HM, IDX, CNT + 5, CLS, REG, out);
}

// Round 14
// 731.539 us; speedup vs baseline: 1.1957x; 1.0505x over previous
//
#include <hip/hip_runtime.h>

typedef unsigned short u16;
typedef u16 u16x4 __attribute__((ext_vector_type(4)));
typedef u16 u16x8 __attribute__((ext_vector_type(8)));
typedef __bf16 bf16x8 __attribute__((ext_vector_type(8)));
typedef float f32x4 __attribute__((ext_vector_type(4)));

__device__ __forceinline__ float bf2f(u16 v) {
  unsigned u = ((unsigned)v) << 16;
  return __builtin_bit_cast(float, u);
}
__device__ __forceinline__ u16 f2bf(float f) {
  unsigned u = __builtin_bit_cast(unsigned, f);
  u += 0x7FFFu + ((u >> 16) & 1u);
  return (u16)(u >> 16);
}
__device__ __forceinline__ float hsw(float v) {
  return v * fminf(fmaxf(v + 3.f, 0.f), 6.f) * (1.f / 6.f);
}
__device__ __forceinline__ f32x4 mfma16(u16x8 a, u16x8 b, f32x4 c) {
  return __builtin_amdgcn_mfma_f32_16x16x32_bf16(
      __builtin_bit_cast(bf16x8, a), __builtin_bit_cast(bf16x8, b), c, 0, 0, 0);
}

#define LR 40  // padded LDS row stride in u16 (80 B)

// ---------------------------------------------------------------------------
// K0: feature NCHW fp32 -> NHWC bf16. float4 reads, u16x4 stores.
// ---------------------------------------------------------------------------
__global__ __launch_bounds__(256) void k_tobf(const float* __restrict__ f,
                                              u16* __restrict__ fbh) {
  __shared__ float tl[64 * 65];
  const int t = threadIdx.x;
  const int bid = blockIdx.x;
  const int ict = bid & 7, xt = (bid >> 3) & 1, y = (bid >> 4) & 127, n = bid >> 11;
  const int x0 = xt * 64, ic0 = ict * 64;
#pragma unroll
  for (int i = 0; i < 4; ++i) {
    const int e = t + i * 256;
    const int icl = e >> 4, xq = e & 15;
    const f32x4 v =
        *(const f32x4*)&f[((n * 512 + ic0 + icl) * 128 + y) * 128 + x0 + xq * 4];
#pragma unroll
    for (int j = 0; j < 4; ++j) tl[icl * 65 + xq * 4 + j] = v[j];
  }
  __syncthreads();
#pragma unroll
  for (int i = 0; i < 4; ++i) {
    const int e = t + i * 256;
    const int xl = e >> 4;
    const int icg = (e & 15) * 4;
    u16x4 v;
#pragma unroll
    for (int j = 0; j < 4; ++j) v[j] = f2bf(tl[(icg + j) * 65 + xl]);
    *(u16x4*)&fbh[(((size_t)((n * 128 + y) * 128 + x0 + xl)) << 9) + ic0 + icg] = v;
  }
}

// ---------------------------------------------------------------------------
// Merged weight prepack
// ---------------------------------------------------------------------------
__global__ __launch_bounds__(256) void k_pack_all(const float* __restrict__ w1,
                                                  const float* __restrict__ w2,
                                                  const float* __restrict__ rgw,
                                                  const float* __restrict__ hmw,
                                                  u16* __restrict__ bp1,
                                                  u16* __restrict__ bp2,
                                                  u16* __restrict__ bp5) {
  const int b = blockIdx.x;
  if (b < 3456) {
    const int e = b * 256 + threadIdx.x;
    const int ici = e & 31;
    const int rest = e >> 5;
    const int oc = rest % 192;
    const int kc = rest / 192;
    const int icc = kc & 15, tap = kc >> 4;
    const int ic = icc * 32 + ici;
    bp1[e] = f2bf(w1[(oc * 512 + ic) * 9 + tap]);
  } else if (b < 4752) {
    const int e = (b - 3456) * 256 + threadIdx.x;
    const int ici = e & 31;
    const int rest = e >> 5;
    const int oc = rest % 192;
    const int kc = rest / 192;
    const int icc = kc % 6, tap = kc / 6;
    const int ic = icc * 32 + ici;
    bp2[e] = f2bf(w2[(oc * 192 + ic) * 9 + tap]);
  } else {
    const int e = (b - 4752) * 256 + threadIdx.x;
    const int ici = e & 31;
    const int rest = e >> 5;
    const int oc = rest % 48;
    const int sic = rest / 48;
    const int icc = sic & 15, slot = sic >> 4;
    const int ic = icc * 32 + ici;
    const int kytab[9] = {1, 1, 1, 2, 0, 2, 2, 0, 0};
    const int kxtab[9] = {1, 2, 0, 1, 1, 2, 0, 2, 0};
    const int ky = kytab[slot], kx = kxtab[slot];
    float v = 0.f;
    if (oc < 32)
      v = rgw[((ic * 32 + oc) * 3 + ky) * 3 + kx];
    else if (oc < 40)
      v = hmw[((ic * 8 + (oc - 32)) * 3 + ky) * 3 + kx];
    bp5[e] = f2bf(v);
  }
}

// ---------------------------------------------------------------------------
// K1: conv1 (R7 K-loop, byte-identical) + shuffle-reduced BN stats epilogue.
// ---------------------------------------------------------------------------
__global__ __launch_bounds__(256) void k_conv1(const u16* __restrict__ fbh,
                                               const u16* __restrict__ bph,
                                               const float* __restrict__ bias,
                                               u16* __restrict__ y1,
                                               float* __restrict__ gsum,
                                               float* __restrict__ gsq,
                                               int* __restrict__ counter,
                                               const float* __restrict__ g1,
                                               const float* __restrict__ be1,
                                               float* __restrict__ sc,
                                               float* __restrict__ sh) {
  __shared__ u16 Al[64 * LR];
  __shared__ u16 Bl[192 * LR];
  __shared__ float bl[192];
  __shared__ float ssum[192], ssq[192];
  __shared__ int lastBlk;
  const int t = threadIdx.x;
  const int n = blockIdx.x >> 6, oy = blockIdx.x & 63;
  if (t < 192) bl[t] = bias[t];
  const int lane = t & 63, wv = t >> 6;
  const int row = lane & 15, g = lane >> 4;
  const int oxs = t >> 2, icq = t & 3;
  const f32x4 z4 = {0.f, 0.f, 0.f, 0.f};
  f32x4 acc[4][3];
#pragma unroll
  for (int i = 0; i < 4; ++i)
#pragma unroll
    for (int j = 0; j < 3; ++j) acc[i][j] = z4;

#define C1_LOAD(KC, AV, BV)                                                    \
  {                                                                            \
    const int tap_ = (KC) >> 4, icc_ = (KC)&15;                                \
    const int ky_ = tap_ / 3, kx_ = tap_ - ky_ * 3;                            \
    const int iy_ = 2 * oy - 1 + ky_;                                          \
    const int ix_ = 2 * oxs - 1 + kx_;                                         \
    u16x8 v_ = {0, 0, 0, 0, 0, 0, 0, 0};                                       \
    if ((unsigned)iy_ < 128u && (unsigned)ix_ < 128u)                          \
      v_ = *(const u16x8*)&fbh[((size_t)((n * 128 + iy_) * 128 + ix_) << 9) +  \
                               icc_ * 32 + icq * 8];                           \
    AV = v_;                                                                   \
    const size_t bbase_ = (size_t)(tap_ * 16 + icc_) * (192 * 32);             \
    _Pragma("unroll") for (int i_ = 0; i_ < 3; ++i_) {                         \
      const int e_ = t + i_ * 256;                                             \
      BV[i_] = *(const u16x8*)&bph[bbase_ + (e_ >> 2) * 32 + (e_ & 3) * 8];    \
    }                                                                          \
  }

  u16x8 avA, bvA[3], avB, bvB[3];
  C1_LOAD(0, avA, bvA);

  for (int kc = 0; kc < 144; ++kc) {
    __syncthreads();
    *(u16x8*)&Al[oxs * LR + icq * 8] = avA;
#pragma unroll
    for (int i = 0; i < 3; ++i) {
      const int e = t + i * 256;
      *(u16x8*)&Bl[(e >> 2) * LR + (e & 3) * 8] = bvA[i];
    }
    __syncthreads();
    if (kc < 143) C1_LOAD(kc + 1, avB, bvB);
    u16x8 af[4], bf[3];
#pragma unroll
    for (int mf = 0; mf < 4; ++mf)
      af[mf] = *(const u16x8*)&Al[(mf * 16 + row) * LR + g * 8];
#pragma unroll
    for (int nf = 0; nf < 3; ++nf)
      bf[nf] = *(const u16x8*)&Bl[(wv * 48 + nf * 16 + row) * LR + g * 8];
#pragma unroll
    for (int mf = 0; mf < 4; ++mf)
#pragma unroll
      for (int nf = 0; nf < 3; ++nf) acc[mf][nf] = mfma16(af[mf], bf[nf], acc[mf][nf]);
    avA = avB;
#pragma unroll
    for (int i = 0; i < 3; ++i) bvA[i] = bvB[i];
  }
#undef C1_LOAD

  float s3[3] = {0.f, 0.f, 0.f}, q3[3] = {0.f, 0.f, 0.f};
#pragma unroll
  for (int mf = 0; mf < 4; ++mf)
#pragma unroll
    for (int nf = 0; nf < 3; ++nf)
#pragma unroll
      for (int r = 0; r < 4; ++r) {
        const int m = mf * 16 + g * 4 + r;
        const int oc = wv * 48 + nf * 16 + row;
        const float v = acc[mf][nf][r] + bl[oc];
        y1[((n * 64 + oy) * 64 + m) * 192 + oc] = f2bf(v);
        s3[nf] += v;
        q3[nf] += v * v;
      }
  // butterfly over g (wave owns disjoint 48-oc slice -> plain stores)
#pragma unroll
  for (int nf = 0; nf < 3; ++nf) {
    s3[nf] += __shfl_xor(s3[nf], 16, 64);
    s3[nf] += __shfl_xor(s3[nf], 32, 64);
    q3[nf] += __shfl_xor(q3[nf], 16, 64);
    q3[nf] += __shfl_xor(q3[nf], 32, 64);
  }
  if (lane < 16) {
#pragma unroll
    for (int nf = 0; nf < 3; ++nf) {
      ssum[wv * 48 + nf * 16 + lane] = s3[nf];
      ssq[wv * 48 + nf * 16 + lane] = q3[nf];
    }
  }
  __syncthreads();
  if (t < 192) {
    atomicAdd(&gsum[t], ssum[t]);
    atomicAdd(&gsq[t], ssq[t]);
  }
  __syncthreads();
  if (t == 0) {
    __threadfence();
    lastBlk = (atomicAdd(counter, 1) == (int)gridDim.x - 1) ? 1 : 0;
  }
  __syncthreads();
  if (lastBlk) {
    __threadfence();
    if (t < 192) {
      const float m = gsum[t] * (1.f / 32768.f);
      const float var = gsq[t] * (1.f / 32768.f) - m * m;
      const float inv = rsqrtf(var + 1e-5f);
      const float sg = g1[t] * inv;
      sc[t] = sg;
      sh[t] = be1[t] - m * sg;
    }
  }
}

// ---------------------------------------------------------------------------
// K2: conv2 (R7 K-loop) + shuffle-reduced BN stats epilogue.
// ---------------------------------------------------------------------------
__global__ __launch_bounds__(256) void k_conv2(const u16* __restrict__ y1,
                                               const u16* __restrict__ bph,
                                               const float* __restrict__ bias,
                                               const float* __restrict__ sc_in,
                                               const float* __restrict__ sh_in,
                                               float* __restrict__ y2,
                                               float* __restrict__ gsum,
                                               float* __restrict__ gsq,
                                               int* __restrict__ counter,
                                               const float* __restrict__ g1,
                                               const float* __restrict__ be1,
                                               float* __restrict__ sc,
                                               float* __restrict__ sh) {
  __shared__ u16 Al[64 * LR];
  __shared__ u16 Bl[192 * LR];
  __shared__ float bl[192], scl[192], shl[192];
  __shared__ float ssum[192], ssq[192];
  __shared__ int lastBlk;
  const int t = threadIdx.x;
  const int n = blockIdx.x >> 4, oyp = blockIdx.x & 15;
  if (t < 192) {
    bl[t] = bias[t];
    scl[t] = sc_in[t];
    shl[t] = sh_in[t];
  }
  __syncthreads();
  const int lane = t & 63, wv = t >> 6;
  const int row = lane & 15, g = lane >> 4;
  const int ms = t >> 2, icq = t & 3;
  const int ryr = ms >> 5, oxs = ms & 31;
  const f32x4 z4 = {0.f, 0.f, 0.f, 0.f};
  f32x4 acc[4][3];
#pragma unroll
  for (int i = 0; i < 4; ++i)
#pragma unroll
    for (int j = 0; j < 3; ++j) acc[i][j] = z4;

#define C2_LOAD(KC, RAW, OK, BV)                                               \
  {                                                                            \
    const int tap_ = (KC) / 6, icc_ = (KC)-tap_ * 6;                           \
    const int ky_ = tap_ / 3, kx_ = tap_ - ky_ * 3;                            \
    const int iy_ = 2 * (oyp * 2 + ryr) - 1 + ky_;                             \
    const int ix_ = 2 * oxs - 1 + kx_;                                         \
    OK = ((unsigned)iy_ < 64u) && ((unsigned)ix_ < 64u);                       \
    u16x8 v_ = {0, 0, 0, 0, 0, 0, 0, 0};                                       \
    if (OK)                                                                    \
      v_ = *(const u16x8*)&y1[((n * 64 + iy_) * 64 + ix_) * 192 + icc_ * 32 +  \
                              icq * 8];                                        \
    RAW = v_;                                                                  \
    const size_t bbase_ = (size_t)(tap_ * 6 + icc_) * (192 * 32);              \
    _Pragma("unroll") for (int i_ = 0; i_ < 3; ++i_) {                         \
      const int e_ = t + i_ * 256;                                             \
      BV[i_] = *(const u16x8*)&bph[bbase_ + (e_ >> 2) * 32 + (e_ & 3) * 8];    \
    }                                                                          \
  }

  u16x8 rawA, bvA[3], rawB, bvB[3];
  bool okA, okB;
  C2_LOAD(0, rawA, okA, bvA);

  for (int kc = 0; kc < 54; ++kc) {
    const int tap = kc / 6, icc = kc - tap * 6;
    const int icb = icc * 32 + icq * 8;
    u16x8 av = {0, 0, 0, 0, 0, 0, 0, 0};
    if (okA) {
#pragma unroll
      for (int j = 0; j < 8; ++j)
        av[j] = f2bf(bf2f(rawA[j]) * scl[icb + j] + shl[icb + j]);
    }
    __syncthreads();
    *(u16x8*)&Al[ms * LR + icq * 8] = av;
#pragma unroll
    for (int i = 0; i < 3; ++i) {
      const int e = t + i * 256;
      *(u16x8*)&Bl[(e >> 2) * LR + (e & 3) * 8] = bvA[i];
    }
    __syncthreads();
    if (kc < 53) C2_LOAD(kc + 1, rawB, okB, bvB);
    u16x8 af[4], bf[3];
#pragma unroll
    for (int mf = 0; mf < 4; ++mf)
      af[mf] = *(const u16x8*)&Al[(mf * 16 + row) * LR + g * 8];
#pragma unroll
    for (int nf = 0; nf < 3; ++nf)
      bf[nf] = *(const u16x8*)&Bl[(wv * 48 + nf * 16 + row) * LR + g * 8];
#pragma unroll
    for (int mf = 0; mf < 4; ++mf)
#pragma unroll
      for (int nf = 0; nf < 3; ++nf) acc[mf][nf] = mfma16(af[mf], bf[nf], acc[mf][nf]);
    rawA = rawB;
    okA = okB;
#pragma unroll
    for (int i = 0; i < 3; ++i) bvA[i] = bvB[i];
  }
#undef C2_LOAD

  float s3[3] = {0.f, 0.f, 0.f}, q3[3] = {0.f, 0.f, 0.f};
#pragma unroll
  for (int mf = 0; mf < 4; ++mf)
#pragma unroll
    for (int nf = 0; nf < 3; ++nf)
#pragma unroll
      for (int r = 0; r < 4; ++r) {
        const int m = mf * 16 + g * 4 + r;
        const int oy = oyp * 2 + (m >> 5), ox = m & 31;
        const int oc = wv * 48 + nf * 16 + row;
        const float v = acc[mf][nf][r] + bl[oc];
        y2[((n * 32 + oy) * 32 + ox) * 192 + oc] = v;
        s3[nf] += v;
        q3[nf] += v * v;
      }
#pragma unroll
  for (int nf = 0; nf < 3; ++nf) {
    s3[nf] += __shfl_xor(s3[nf], 16, 64);
    s3[nf] += __shfl_xor(s3[nf], 32, 64);
    q3[nf] += __shfl_xor(q3[nf], 16, 64);
    q3[nf] += __shfl_xor(q3[nf], 32, 64);
  }
  if (lane < 16) {
#pragma unroll
    for (int nf = 0; nf < 3; ++nf) {
      ssum[wv * 48 + nf * 16 + lane] = s3[nf];
      ssq[wv * 48 + nf * 16 + lane] = q3[nf];
    }
  }
  __syncthreads();
  if (t < 192) {
    atomicAdd(&gsum[t], ssum[t]);
    atomicAdd(&gsq[t], ssq[t]);
  }
  __syncthreads();
  if (t == 0) {
    __threadfence();
    lastBlk = (atomicAdd(counter, 1) == (int)gridDim.x - 1) ? 1 : 0;
  }
  __syncthreads();
  if (lastBlk) {
    __threadfence();
    if (t < 192) {
      const float m = gsum[t] * (1.f / 8192.f);
      const float var = gsq[t] * (1.f / 8192.f) - m * m;
      const float inv = rsqrtf(var + 1e-5f);
      const float sg = g1[t] * inv;
      sc[t] = sg;
      sh[t] = be1[t] - m * sg;
    }
  }
}

// ---------------------------------------------------------------------------
// K5: convt (R7 K-loop, byte-identical) + shuffle-reduced rr BN stats.
// ---------------------------------------------------------------------------
#define AST 40
#define ARS (130 * 40)
#define BST 40
__global__ __launch_bounds__(256) void k_convt(const u16* __restrict__ fbh,
                                               const u16* __restrict__ bph,
                                               const float* __restrict__ rgb,
                                               const float* __restrict__ hmb,
                                               u16* __restrict__ rr,
                                               float* __restrict__ hm,
                                               float* __restrict__ gsum,
                                               float* __restrict__ gsq,
                                               int* __restrict__ counter,
                                               const float* __restrict__ rg_g,
                                               const float* __restrict__ rg_be,
                                               float* __restrict__ sc,
                                               float* __restrict__ sh) {
  __shared__ u16 AH[2 * ARS];
  __shared__ u16 BH[9 * 48 * BST];
  __shared__ float p_s[4][32], p_q[4][32];
  __shared__ int lastBlk;
  const int t = threadIdx.x;
  const int bid = (blockIdx.x & 7) * 128 + (blockIdx.x >> 3);
  const int n = bid >> 7, iyb = bid & 127;
  const int lane = t & 63, wv = t >> 6;
  const int row = lane & 15, g = lane >> 4;

  if (t < 8) {
    const int r = t >> 2, j = t & 3;
    const u16x8 z = {0, 0, 0, 0, 0, 0, 0, 0};
    *(u16x8*)&AH[r * ARS + 128 * AST + j * 8] = z;
  }

  float bias3[3];
#pragma unroll
  for (int nf = 0; nf < 3; ++nf) {
    const int oc = nf * 16 + row;
    bias3[nf] = (oc < 32) ? rgb[oc] : ((oc < 40) ? hmb[oc - 32] : 0.f);
  }

  const int SCt[9] = {0, 1, 1, 2, 2, 3, 3, 3, 3};
  const int SDt[9] = {0, 0, 0, 0, 1, 0, 0, 1, 1};
  const int SXt[9] = {0, 0, 1, 0, 0, 0, 1, 0, 1};

  int rr_[4], px_[4], iq_[4];
#pragma unroll
  for (int i = 0; i < 4; ++i) {
    const int u = t + i * 256;
    rr_[i] = u >> 9;
    px_[i] = (u >> 2) & 127;
    iq_[i] = u & 3;
  }

  const f32x4 z4 = {0.f, 0.f, 0.f, 0.f};
  f32x4 acc[4][2][3];
#pragma unroll
  for (int c = 0; c < 4; ++c)
#pragma unroll
    for (int m = 0; m < 2; ++m)
#pragma unroll
      for (int j = 0; j < 3; ++j) acc[c][m][j] = z4;

#define LOAD_A(ICC, DST)                                                       \
  _Pragma("unroll") for (int i = 0; i < 4; ++i) {                              \
    const int iy = iyb + rr_[i];                                               \
    u16x8 v = {0, 0, 0, 0, 0, 0, 0, 0};                                        \
    if (iy < 128)                                                              \
      v = *(const u16x8*)&fbh[((size_t)((n * 128 + iy) * 128 + px_[i]) << 9) + \
                              (ICC)*32 + iq_[i] * 8];                          \
    DST[i] = v;                                                                \
  }

#define LOAD_B(ICC, DST)                                                       \
  _Pragma("unroll") for (int i = 0; i < 7; ++i) {                              \
    const int e = t + i * 256;                                                 \
    u16x8 v = {0, 0, 0, 0, 0, 0, 0, 0};                                        \
    if (e < 1728) {                                                            \
      const int slot = e / 192, rem = e % 192;                                 \
      const int oc = rem >> 2, icq = rem & 3;                                  \
      v = *(const u16x8*)&bph[((size_t)((slot * 16 + (ICC)) * 48 + oc) << 5) + \
                              icq * 8];                                        \
    }                                                                          \
    DST[i] = v;                                                                \
  }

  u16x8 ahA[4], bhA[7], ahB[4], bhB[7];
  LOAD_A(0, ahA);
  LOAD_B(0, bhA);

  for (int icc = 0; icc < 16; ++icc) {
    __syncthreads();
#pragma unroll
    for (int i = 0; i < 4; ++i)
      *(u16x8*)&AH[rr_[i] * ARS + px_[i] * AST + iq_[i] * 8] = ahA[i];
#pragma unroll
    for (int i = 0; i < 7; ++i) {
      const int e = t + i * 256;
      if (e < 1728) {
        const int slot = e / 192, rem = e % 192;
        const int oc = rem >> 2, icq = rem & 3;
        *(u16x8*)&BH[(slot * 48 + oc) * BST + icq * 8] = bhA[i];
      }
    }
    __syncthreads();

    if (icc < 15) {
      LOAD_A(icc + 1, ahB);
      LOAD_B(icc + 1, bhB);
    }

#pragma unroll
    for (int slot = 0; slot < 9; ++slot) {
      const int cls = SCt[slot], diy = SDt[slot], dix = SXt[slot];
      const u16x8 bf0 = *(const u16x8*)&BH[(slot * 48 + row) * BST + g * 8];
      const u16x8 bf1 = *(const u16x8*)&BH[(slot * 48 + 16 + row) * BST + g * 8];
      const u16x8 bf2 = *(const u16x8*)&BH[(slot * 48 + 32 + row) * BST + g * 8];
#pragma unroll
      for (int mfl = 0; mfl < 2; ++mfl) {
        const int mf = wv * 2 + mfl;
        const u16x8 af =
            *(const u16x8*)&AH[diy * ARS + (mf * 16 + row + dix) * AST + g * 8];
        acc[cls][mfl][0] = mfma16(af, bf0, acc[cls][mfl][0]);
        acc[cls][mfl][1] = mfma16(af, bf1, acc[cls][mfl][1]);
        acc[cls][mfl][2] = mfma16(af, bf2, acc[cls][mfl][2]);
      }
    }

#pragma unroll
    for (int i = 0; i < 4; ++i) ahA[i] = ahB[i];
#pragma unroll
    for (int i = 0; i < 7; ++i) bhA[i] = bhB[i];
  }
#undef LOAD_A
#undef LOAD_B

  float s2[2] = {0.f, 0.f}, q2[2] = {0.f, 0.f};
#pragma unroll
  for (int cls = 0; cls < 4; ++cls) {
    const int oy = 2 * iyb + (cls >> 1);
    const int xp = cls & 1;
#pragma unroll
    for (int mfl = 0; mfl < 2; ++mfl)
#pragma unroll
      for (int nf = 0; nf < 3; ++nf)
#pragma unroll
        for (int r = 0; r < 4; ++r) {
          const int m = (wv * 2 + mfl) * 16 + g * 4 + r;
          const int ox = 2 * m + xp;
          const int oc = nf * 16 + row;
          const float v = acc[cls][mfl][nf][r] + bias3[nf];
          if (oc < 32) {
            rr[((size_t)((n * 256 + oy) * 256 + ox)) * 32 + oc] = f2bf(v);
            s2[nf] += v;
            q2[nf] += v * v;
          } else if (oc < 40)
            hm[(size_t)(n * 8 + (oc - 32)) * 65536 + oy * 256 + ox] = v;
        }
  }
  // butterfly over g, per-wave partials, t<32 combine (no LDS atomics)
#pragma unroll
  for (int nf = 0; nf < 2; ++nf) {
    s2[nf] += __shfl_xor(s2[nf], 16, 64);
    s2[nf] += __shfl_xor(s2[nf], 32, 64);
    q2[nf] += __shfl_xor(q2[nf], 16, 64);
    q2[nf] += __shfl_xor(q2[nf], 32, 64);
  }
  if (lane < 16) {
#pragma unroll
    for (int nf = 0; nf < 2; ++nf) {
      p_s[wv][nf * 16 + lane] = s2[nf];
      p_q[wv][nf * 16 + lane] = q2[nf];
    }
  }
  __syncthreads();
  if (t < 32) {
    const float ts = p_s[0][t] + p_s[1][t] + p_s[2][t] + p_s[3][t];
    const float tq = p_q[0][t] + p_q[1][t] + p_q[2][t] + p_q[3][t];
    atomicAdd(&gsum[t], ts);
    atomicAdd(&gsq[t], tq);
  }
  __syncthreads();
  if (t == 0) {
    __threadfence();
    lastBlk = (atomicAdd(counter, 1) == (int)gridDim.x - 1) ? 1 : 0;
  }
  __syncthreads();
  if (lastBlk) {
    __threadfence();
    if (t < 32) {
      const float m = gsum[t] * (1.f / 524288.f);
      const float var = gsq[t] * (1.f / 524288.f) - m * m;
      const float inv = rsqrtf(var + 1e-5f);
      const float sg = rg_g[t] * inv;
      sc[t] = sg;
      sh[t] = rg_be[t] - m * sg;
    }
  }
}

// ---------------------------------------------------------------------------
// K3: conv3 1x1 192->32 on bn(y2 fp32) + fused Y3 stats epilogue.
// ---------------------------------------------------------------------------
__global__ __launch_bounds__(256) void k_conv3(const float* __restrict__ y2,
                                               const float* __restrict__ w3,
                                               const float* __restrict__ b3,
                                               const float* __restrict__ sc_in,
                                               const float* __restrict__ sh_in,
                                               float* __restrict__ y3,
                                               float* __restrict__ gsum,
                                               float* __restrict__ gsq,
                                               int* __restrict__ counter,
                                               const float* __restrict__ g2,
                                               const float* __restrict__ be2,
                                               float* __restrict__ sc,
                                               float* __restrict__ sh) {
  __shared__ float wl[32 * 192];
  __shared__ float scl[192], shl[192];
  __shared__ float p_s[4][32], p_q[4][32];
  __shared__ int lastBlk;
  const int t = threadIdx.x;
  for (int e = t; e < 6144; e += 256) wl[e] = w3[e];
  if (t < 192) {
    scl[t] = sc_in[t];
    shl[t] = sh_in[t];
  }
  __syncthreads();
  const int px = blockIdx.x * 256 + t;
  float acc[32];
#pragma unroll
  for (int oc = 0; oc < 32; ++oc) acc[oc] = 0.f;
  const float* base = &y2[(size_t)px * 192];
  for (int icb = 0; icb < 192; icb += 8) {
    const f32x4 r0 = *(const f32x4*)&base[icb];
    const f32x4 r1 = *(const f32x4*)&base[icb + 4];
    float v[8];
#pragma unroll
    for (int j = 0; j < 8; ++j) {
      const float r = (j < 4) ? r0[j & 3] : r1[j & 3];
      v[j] = r * scl[icb + j] + shl[icb + j];
    }
#pragma unroll
    for (int oc = 0; oc < 32; ++oc) {
      const f32x4 w0 = *(const f32x4*)&wl[oc * 192 + icb];
      const f32x4 w1 = *(const f32x4*)&wl[oc * 192 + icb + 4];
      acc[oc] += v[0] * w0[0] + v[1] * w0[1] + v[2] * w0[2] + v[3] * w0[3] +
                 v[4] * w1[0] + v[5] * w1[1] + v[6] * w1[2] + v[7] * w1[3];
    }
  }
  const int lane = t & 63, wv = t >> 6;
#pragma unroll
  for (int oc = 0; oc < 32; ++oc) {
    const float v = acc[oc] + b3[oc];
    y3[(size_t)px * 32 + oc] = v;
    float s = v, q = v * v;
#pragma unroll
    for (int off = 1; off < 64; off <<= 1) {
      s += __shfl_xor(s, off, 64);
      q += __shfl_xor(q, off, 64);
    }
    if (lane == 0) {
      p_s[wv][oc] = s;
      p_q[wv][oc] = q;
    }
  }
  __syncthreads();
  if (t < 32) {
    const float ts = p_s[0][t] + p_s[1][t] + p_s[2][t] + p_s[3][t];
    const float tq = p_q[0][t] + p_q[1][t] + p_q[2][t] + p_q[3][t];
    atomicAdd(&gsum[t], ts);
    atomicAdd(&gsq[t], tq);
  }
  __syncthreads();
  if (t == 0) {
    __threadfence();
    lastBlk = (atomicAdd(counter, 1) == (int)gridDim.x - 1) ? 1 : 0;
  }
  __syncthreads();
  if (lastBlk) {
    __threadfence();
    if (t < 32) {
      const float m = gsum[t] * (1.f / 8192.f);
      const float var = gsq[t] * (1.f / 8192.f) - m * m;
      const float inv = rsqrtf(var + 1e-5f);
      const float sg = g2[t] * inv;
      sc[t] = sg;
      sh[t] = be2[t] - m * sg;
    }
  }
}

// ---------------------------------------------------------------------------
// K4: classify conv 3x3 p1, 32->32 on hsw(bn2(y3)) + fused C1 stats.
// ---------------------------------------------------------------------------
__global__ __launch_bounds__(256) void k_clsconv1(const float* __restrict__ y3,
                                                  const float* __restrict__ w1,
                                                  const float* __restrict__ b1,
                                                  const float* __restrict__ sc_in,
                                                  const float* __restrict__ sh_in,
                                                  float* __restrict__ c1,
                                                  float* __restrict__ gsum,
                                                  float* __restrict__ gsq,
                                                  int* __restrict__ counter,
                                                  const float* __restrict__ clg,
                                                  const float* __restrict__ clbe,
                                                  float* __restrict__ sc,
                                                  float* __restrict__ sh) {
  __shared__ float wl[9216];  // [ic][tap][oc]
  __shared__ float scl[32], shl[32];
  __shared__ float cs[32], cq[32];
  __shared__ int lastBlk;
  const int t = threadIdx.x;
  for (int e = t; e < 9216; e += 256) {
    const int oc = e & 31;
    const int tmp = e >> 5;
    const int tap = tmp % 9, ic = tmp / 9;
    wl[e] = w1[(oc * 32 + ic) * 9 + tap];
  }
  if (t < 32) {
    scl[t] = sc_in[t];
    shl[t] = sh_in[t];
  }
  __syncthreads();
  const int px = blockIdx.x * 64 + (t & 63);
  const int ocg = t >> 6;
  const int n = px >> 10, y0 = (px >> 5) & 31, x0 = px & 31;
  float acc[8];
#pragma unroll
  for (int j = 0; j < 8; ++j) acc[j] = 0.f;
  for (int tap = 0; tap < 9; ++tap) {
    const int dy = tap / 3 - 1, dx = tap % 3 - 1;
    const int yy = y0 + dy, xx = x0 + dx;
    if ((unsigned)yy < 32u && (unsigned)xx < 32u) {
      const float* ib = &y3[((n << 10) + yy * 32 + xx) * 32];
      for (int ic = 0; ic < 32; ++ic) {
        const float v = hsw(ib[ic] * scl[ic] + shl[ic]);
        const float* wp = &wl[(ic * 9 + tap) * 32 + ocg * 8];
#pragma unroll
        for (int j = 0; j < 8; ++j) acc[j] += v * wp[j];
      }
    }
  }
  const int lane = t & 63;
#pragma unroll
  for (int j = 0; j < 8; ++j) {
    const float v = acc[j] + b1[ocg * 8 + j];
    c1[px * 32 + ocg * 8 + j] = v;
    float s = v, q = v * v;
#pragma unroll
    for (int off = 1; off < 64; off <<= 1) {
      s += __shfl_xor(s, off, 64);
      q += __shfl_xor(q, off, 64);
    }
    if (lane == 0) {
      cs[ocg * 8 + j] = s;
      cq[ocg * 8 + j] = q;
    }
  }
  __syncthreads();
  if (t < 32) {
    atomicAdd(&gsum[t], cs[t]);
    atomicAdd(&gsq[t], cq[t]);
  }
  __syncthreads();
  if (t == 0) {
    __threadfence();
    lastBlk = (atomicAdd(counter, 1) == (int)gridDim.x - 1) ? 1 : 0;
  }
  __syncthreads();
  if (lastBlk) {
    __threadfence();
    if (t < 32) {
      const float m = gsum[t] * (1.f / 8192.f);
      const float var = gsq[t] * (1.f / 8192.f) - m * m;
      const float inv = rsqrtf(var + 1e-5f);
      const float sg = clg[t] * inv;
      sc[t] = sg;
      sh[t] = clbe[t] - m * sg;
    }
  }
}

// ---------------------------------------------------------------------------
// K4c: c2 = conv3x3(hsw(bn(c1))) 32->1, then cls[n,k] = c2 . dw[k] + db[k]
// ---------------------------------------------------------------------------
__global__ __launch_bounds__(256) void k_cls(const float* __restrict__ c1,
                                             const float* __restrict__ w2,
                                             const float* __restrict__ b2,
                                             const float* __restrict__ dw,
                                             const float* __restrict__ db,
                                             const float* __restrict__ sc,
                                             const float* __restrict__ sh,
                                             float* __restrict__ cls) {
  __shared__ float wl[288];
  __shared__ float scl[32], shl[32];
  __shared__ float red0[256], red1[256];
  const int t = threadIdx.x;
  const int n = blockIdx.x;
  for (int e = t; e < 288; e += 256) wl[e] = w2[e];
  if (t < 32) {
    scl[t] = sc[t];
    shl[t] = sh[t];
  }
  __syncthreads();
  float s0 = 0.f, s1 = 0.f;
  for (int i = 0; i < 4; ++i) {
    const int px = i * 256 + t;
    const int y0 = px >> 5, x0 = px & 31;
    float c2 = b2[0];
    for (int tap = 0; tap < 9; ++tap) {
      const int dy = tap / 3 - 1, dx = tap % 3 - 1;
      const int yy = y0 + dy, xx = x0 + dx;
      if ((unsigned)yy < 32u && (unsigned)xx < 32u) {
        const float* ib = &c1[((n << 10) + yy * 32 + xx) * 32];
        for (int ic = 0; ic < 32; ++ic)
          c2 += hsw(ib[ic] * scl[ic] + shl[ic]) * wl[ic * 9 + tap];
      }
    }
    s0 += c2 * dw[px];
    s1 += c2 * dw[1024 + px];
  }
  red0[t] = s0;
  red1[t] = s1;
  __syncthreads();
  for (int s = 128; s; s >>= 1) {
    if (t < s) {
      red0[t] += red0[t + s];
      red1[t] += red1[t + s];
    }
    __syncthreads();
  }
  if (t == 0) {
    cls[n * 2 + 0] = red0[0] + db[0];
    cls[n * 2 + 1] = red1[0] + db[1];
  }
}

// ---------------------------------------------------------------------------
// K6: reg = conv3x3 p1 (hsw(bn(rr))) 32->2, fp32 NCHW [8,2,256,256]
// ---------------------------------------------------------------------------
__global__ __launch_bounds__(256) void k_regconv(const u16* __restrict__ rr,
                                                 const float* __restrict__ w,
                                                 const float* __restrict__ b,
                                                 const float* __restrict__ sc,
                                                 const float* __restrict__ sh,
                                                 float* __restrict__ reg) {
  __shared__ u16 rl[3 * 258 * 33];
  __shared__ float wl[576];
  __shared__ float scl[32], shl[32];
  const int t = threadIdx.x;
  const int n = blockIdx.x >> 8, oy = blockIdx.x & 255;
  for (int e = t; e < 576; e += 256) wl[e] = w[e];
  if (t < 32) {
    scl[t] = sc[t];
    shl[t] = sh[t];
  }
  if (t < 192) {
    const int ry = t / 64, side = (t >> 5) & 1, ic = t & 31;
    rl[(ry * 258 + side * 257) * 33 + ic] = 0;
  }
  __syncthreads();
  for (int e = t; e < 3072; e += 256) {
    const int icq8 = e & 3;
    const int pxx = (e >> 2) & 255;
    const int ry = e >> 10;
    const int rowi = oy - 1 + ry;
    u16x8 raw = {0, 0, 0, 0, 0, 0, 0, 0};
    bool ok = (unsigned)rowi < 256u;
    if (ok)
      raw = *(const u16x8*)&rr[((size_t)((n * 256 + rowi) * 256 + pxx)) * 32 + icq8 * 8];
#pragma unroll
    for (int j = 0; j < 8; ++j) {
      const int ic = icq8 * 8 + j;
      float v = 0.f;
      if (ok) v = hsw(bf2f(raw[j]) * scl[ic] + shl[ic]);
      rl[(ry * 258 + pxx + 1) * 33 + ic] = f2bf(v);
    }
  }
  __syncthreads();
  const int px = t;
  float a0 = b[0], a1 = b[1];
#pragma unroll
  for (int ry = 0; ry < 3; ++ry)
#pragma unroll
    for (int kx = 0; kx < 3; ++kx) {
      const u16* ib = &rl[(ry * 258 + px + kx) * 33];
      for (int ic = 0; ic < 32; ++ic) {
        const float v = bf2f(ib[ic]);
        a0 += v * wl[ic * 9 + ry * 3 + kx];
        a1 += v * wl[288 + ic * 9 + ry * 3 + kx];
      }
    }
  reg[(n * 2 + 0) * 65536 + oy * 256 + px] = a0;
  reg[(n * 2 + 1) * 65536 + oy * 256 + px] = a1;
}

// ---------------------------------------------------------------------------
// K7: per (n, ch) argmax; last block also decodes -> out [8,2,9]
// ---------------------------------------------------------------------------
__global__ __launch_bounds__(256) void k_argmaxfin(const float* __restrict__ hm,
                                                   int* __restrict__ idx,
                                                   int* __restrict__ counter,
                                                   const float* __restrict__ cls,
                                                   const float* __restrict__ reg,
                                                   float* __restrict__ out) {
  __shared__ float bv[256];
  __shared__ int bi[256];
  __shared__ int lastBlk;
  const int t = threadIdx.x;
  const float* base = &hm[(size_t)blockIdx.x * 65536];
  float best = -3.402823466e38f;
  int bidx = 2147483647;
  for (int i = t; i < 65536; i += 256) {
    const float v = base[i];
    if (v > best) {
      best = v;
      bidx = i;
    }
  }
  bv[t] = best;
  bi[t] = bidx;
  __syncthreads();
  for (int s = 128; s; s >>= 1) {
    if (t < s) {
      if (bv[t + s] > bv[t] || (bv[t + s] == bv[t] && bi[t + s] < bi[t])) {
        bv[t] = bv[t + s];
        bi[t] = bi[t + s];
      }
    }
    __syncthreads();
  }
  if (t == 0) {
    idx[blockIdx.x] = bi[0];
    __threadfence();
    lastBlk = (atomicAdd(counter, 1) == (int)gridDim.x - 1) ? 1 : 0;
  }
  __syncthreads();
  if (lastBlk) {
    __threadfence();
    if (t < 16) {
      const int n = t >> 1, p = t & 1;
      const float cv = cls[n * 2 + p];
      float* o = &out[(n * 2 + p) * 9];
      if (!(cv > 0.6f)) {
        for (int i = 0; i < 9; ++i) o[i] = -1.f;
      } else {
        o[0] = (float)p;
        for (int c = 0; c < 4; ++c) {
          const int id = idx[n * 8 + p * 4 + c];
          const int yi = id >> 8, xi = id & 255;
          const float ox_ = reg[(n * 2 + 0) * 65536 + id];
          const float oy_ = reg[(n * 2 + 1) * 65536 + id];
          o[1 + c] = fminf(fmaxf((ox_ + (float)xi) * (1.f / 256.f), 0.f), 1.f);
          o[5 + c] = fminf(fmaxf((oy_ + (float)yi) * (1.f / 256.f), 0.f), 1.f);
        }
      }
    }
  }
}

// ---------------------------------------------------------------------------
extern "C" void kernel_launch(void* const* d_in, const int* in_sizes, int n_in,
                              void* d_out, int out_size, void* d_ws, size_t ws_size,
                              hipStream_t stream) {
  const float* feature = (const float*)d_in[0];
  const float* ch_w1 = (const float*)d_in[1];
  const float* ch_b1 = (const float*)d_in[2];
  const float* ch_w2 = (const float*)d_in[3];
  const float* ch_b2 = (const float*)d_in[4];
  const float* ch_w3 = (const float*)d_in[5];
  const float* ch_b3 = (const float*)d_in[6];
  const float* ch_g1 = (const float*)d_in[7];
  const float* ch_be1 = (const float*)d_in[8];
  const float* ch_g2 = (const float*)d_in[9];
  const float* ch_be2 = (const float*)d_in[10];
  const float* cl_w1 = (const float*)d_in[11];
  const float* cl_b1 = (const float*)d_in[12];
  const float* cl_w2 = (const float*)d_in[13];
  const float* cl_b2 = (const float*)d_in[14];
  const float* cl_g = (const float*)d_in[15];
  const float* cl_be = (const float*)d_in[16];
  const float* cl_dw = (const float*)d_in[17];
  const float* cl_db = (const float*)d_in[18];
  const float* rg_tw = (const float*)d_in[19];
  const float* rg_tb = (const float*)d_in[20];
  const float* rg_g = (const float*)d_in[21];
  const float* rg_be = (const float*)d_in[22];
  const float* rg_w = (const float*)d_in[23];
  const float* rg_b = (const float*)d_in[24];
  const float* hm_tw = (const float*)d_in[25];
  const float* hm_tb = (const float*)d_in[26];
  float* out = (float*)d_out;

  char* w = (char*)d_ws;
  const size_t OFF_FB = 0;                  // 134217728
  const size_t OFF_BP1 = 134217728;         // 1769472
  const size_t OFF_BP2 = 135987200;         // 663552
  const size_t OFF_BP5 = 136650752;         // 442368
  const size_t OFF_Y1 = 137093120;          // 12582912 (bf16)
  const size_t OFF_Y2 = 149676032;          // 6291456  (fp32)
  const size_t OFF_Y3 = 155967488;          // 1048576
  const size_t OFF_C1 = 157016064;          // 1048576
  const size_t OFF_RR = 158064640;          // 33554432
  const size_t OFF_HM = 191619072;          // 16777216
  const size_t OFF_REG = 208396288;         // 4194304
  const size_t OFF_STATS = 212590592;       // 3840 sums + 64 counters
  const size_t OFF_PARAMS = 212594496;      // 3840
  const size_t OFF_CLS = 212598336;         // 64
  const size_t OFF_IDX = 212598400;         // 256
  const size_t WS_NEED = 212598656;
  if (ws_size < WS_NEED) return;

  u16* FB = (u16*)(w + OFF_FB);
  u16* BP1 = (u16*)(w + OFF_BP1);
  u16* BP2 = (u16*)(w + OFF_BP2);
  u16* BP5 = (u16*)(w + OFF_BP5);
  u16* Y1 = (u16*)(w + OFF_Y1);
  float* Y2 = (float*)(w + OFF_Y2);
  float* Y3 = (float*)(w + OFF_Y3);
  float* C1 = (float*)(w + OFF_C1);
  u16* RR = (u16*)(w + OFF_RR);
  float* HM = (float*)(w + OFF_HM);
  float* REG = (float*)(w + OFF_REG);
  float* GSUM = (float*)(w + OFF_STATS);
  float* GSQ = GSUM + 480;
  int* CNT = (int*)(w + OFF_STATS + 3840);
  float* SC = (float*)(w + OFF_PARAMS);
  float* SH = SC + 480;
  float* CLS = (float*)(w + OFF_CLS);
  int* IDX = (int*)(w + OFF_IDX);

  (void)hipMemsetAsync(w + OFF_STATS, 0, 3904, stream);

  k_tobf<<<16384, 256, 0, stream>>>(feature, FB);
  k_pack_all<<<5616, 256, 0, stream>>>(ch_w1, ch_w2, rg_tw, hm_tw, BP1, BP2, BP5);

  // CommonHead (BN stats fused into every producer epilogue)
  k_conv1<<<512, 256, 0, stream>>>(FB, BP1, ch_b1, Y1, GSUM + 0, GSQ + 0, CNT + 0,
                                   ch_g1, ch_be1, SC + 0, SH + 0);
  k_conv2<<<128, 256, 0, stream>>>(Y1, BP2, ch_b2, SC + 0, SH + 0, Y2, GSUM + 192,
                                   GSQ + 192, CNT + 1, ch_g1, ch_be1, SC + 192,
                                   SH + 192);
  k_conv3<<<32, 256, 0, stream>>>(Y2, ch_w3, ch_b3, SC + 192, SH + 192, Y3,
                                  GSUM + 384, GSQ + 384, CNT + 2, ch_g2, ch_be2,
                                  SC + 384, SH + 384);
  // Classify head
  k_clsconv1<<<128, 256, 0, stream>>>(Y3, cl_w1, cl_b1, SC + 384, SH + 384, C1,
                                      GSUM + 416, GSQ + 416, CNT + 3, cl_g, cl_be,
                                      SC + 416, SH + 416);
  k_cls<<<8, 256, 0, stream>>>(C1, cl_w2, cl_b2, cl_dw, cl_db, SC + 416, SH + 416,
                               CLS);
  // Regression + heatmap
  k_convt<<<1024, 256, 0, stream>>>(FB, BP5, rg_tb, hm_tb, RR, HM, GSUM + 448,
                                    GSQ + 448, CNT + 4, rg_g, rg_be, SC + 448,
                                    SH + 448);
  k_regconv<<<2048, 256, 0, stream>>>(RR, rg_w, rg_b, SC + 448, SH + 448, REG);
  // Decode (argmax + final fused)
  k_argmaxfin<<<64, 256, 0, stream>>>(HM, IDX, CNT + 5, CLS, REG, out);
}